// Round 4
// baseline (712.103 us; speedup 1.0000x reference)
//
#include <hip/hip_runtime.h>
#include <hip/hip_bf16.h>

#define NN 100000   // nodes
#define NE 200000   // edges
#define NG 2500     // graphs
#define FN 16       // node feats
#define FE 8        // edge feats
#define H1C 32
#define H2C 16
#define KH 16       // edge-MLP hidden

typedef __attribute__((ext_vector_type(8))) short short8;
typedef __attribute__((ext_vector_type(4))) float f32x4;

__device__ __forceinline__ float bf2f(unsigned int u){
  union { unsigned int i; float f; } v; v.i = (u & 0xffffu) << 16; return v.f;
}
__device__ __forceinline__ unsigned short f2bf(float f){
  union { float f; unsigned int i; } u; u.f = f;
  unsigned int r = u.i + 0x7fffu + ((u.i >> 16) & 1u);   // RNE, finite data
  return (unsigned short)(r >> 16);
}
__device__ __forceinline__ unsigned int pk2(float a, float b){
  return (unsigned int)f2bf(a) | ((unsigned int)f2bf(b) << 16);
}
__device__ __forceinline__ int lower_bound_i(const int* __restrict__ a, int n, int v){
  int lo = 0, hi = n;
  while(lo < hi){ int mid = (lo + hi) >> 1; if(a[mid] < v) lo = mid + 1; else hi = mid; }
  return lo;
}

// flag=1 if float inputs are bf16, 0 if fp32
__global__ void detect_kernel(const void* __restrict__ x, int* __restrict__ flag){
  int tid = threadIdx.x;
  const unsigned short* u = (const unsigned short*)x;
  float f = bf2f(u[2*tid]);
  float a = fabsf(f);
  int sane = (f == 0.0f) || (a > 1e-4f && a < 1e4f);
  __shared__ int cnt;
  if(tid == 0) cnt = 0;
  __syncthreads();
  if(sane) atomicAdd(&cnt, 1);
  __syncthreads();
  if(tid == 0) *flag = (cnt >= 128) ? 1 : 0;
}

__global__ void cvt_any(const void* __restrict__ in, float* __restrict__ out, int n,
                        const int* __restrict__ flag){
  bool isbf = (*flag) != 0;
  int i = blockIdx.x * blockDim.x + threadIdx.x;
  int stride = gridDim.x * blockDim.x;
  if(isbf){
    const unsigned short* u = (const unsigned short*)in;
    for(; i < n; i += stride) out[i] = bf2f(u[i]);
  } else {
    const float* p = (const float*)in;
    for(; i < n; i += stride) out[i] = p[i];
  }
}

#define NW 20
struct WArgs { const void* p[NW]; };
#define W_TOTAL 19330
enum {
  OW_E1A=0,     OB_E1A=128,   OW_E1B=144,   OB_E1B=8336,  OW_R1=8848,  OB_R1=9360,
  OW_E2A=9392,  OB_E2A=9520,  OW_E2B=9536,  OB_E2B=17728, OW_R2=18240, OB_R2=18752,
  OW_G1=18768,  OB_G1=19024,  OW_G2=19040,  OB_G2=19056,
  OW_L1=19057,  OB_L1=19313,  OW_L2=19321,  OB_L2=19329
};

__global__ void cvt_weights_kernel(WArgs w, float* __restrict__ out, const int* __restrict__ flag){
  const int sz[NW] = {128,16,8192,512,512,32, 128,16,8192,512,512,16, 256,16,16,1, 256,8,8,1};
  bool isbf = (*flag) != 0;
  int i = blockIdx.x * blockDim.x + threadIdx.x;
  if(i >= W_TOTAL) return;
  int seg = 0, base = 0;
  while(i - base >= sz[seg]){ base += sz[seg]; seg++; }
  int off = i - base;
  out[i] = isbf ? bf2f(((const unsigned short*)w.p[seg])[off])
                : ((const float*)w.p[seg])[off];
}

// pack W^T once: wpack[n*KP + k] = bf16(W[k][n]), W=[wb; bb; 0pad]
template<int IN, int OUT>
__global__ void pack_w_kernel(const float* __restrict__ wb, const float* __restrict__ bb,
                              unsigned int* __restrict__ wpacku){
  constexpr int KIN = KH*IN, KTOT = KIN + IN;
  constexpr int KMF = ((KTOT + 31)/32)*32, KP = KMF + 8;
  int j = blockIdx.x*256 + threadIdx.x;
  if(j >= OUT*(KP/2)) return;
  int n = j / (KP/2); int k = (j % (KP/2)) * 2;
  unsigned short v0 = 0, v1 = 0;
  if(k < KIN)          v0 = f2bf(wb[(size_t)k*OUT + n]);
  else if(k < KTOT)    v0 = f2bf(bb[(size_t)(k-KIN)*OUT + n]);
  if(k+1 < KIN)        v1 = f2bf(wb[(size_t)(k+1)*OUT + n]);
  else if(k+1 < KTOT)  v1 = f2bf(bb[(size_t)(k+1-KIN)*OUT + n]);
  wpacku[j] = (unsigned int)v0 | ((unsigned int)v1 << 16);
}

// dense edge-MLP: hpk[e*8+d] = pack(relu(ea@wa+ba)[2d], [2d+1])
__global__ void __launch_bounds__(256) edge_h_kernel(
    const float* __restrict__ ef, const float* __restrict__ wa, const float* __restrict__ ba,
    unsigned int* __restrict__ hpk)
{
  int t = blockIdx.x*256 + threadIdx.x;   // exact grid: NE*8
  int e = t >> 3, d = t & 7;
  const float* ep = ef + (size_t)e*FE;
  float h0 = ba[2*d], h1 = ba[2*d+1];
  #pragma unroll
  for(int j = 0; j < FE; j++){
    float evj = ep[j];
    h0 += evj * wa[j*KH + 2*d];
    h1 += evj * wa[j*KH + 2*d+1];
  }
  h0 = h0 > 0.f ? h0 : 0.f;
  h1 = h1 > 0.f ? h1 : 0.f;
  hpk[t] = pk2(h0, h1);
}

// ---- gate MLP ----
__global__ void __launch_bounds__(256) gate_kernel(
    const float* __restrict__ xf, const float* __restrict__ w1, const float* __restrict__ b1,
    const float* __restrict__ w2, const float* __restrict__ b2, float* __restrict__ gate)
{
  __shared__ float s_w1[FN*FN], s_b1[FN], s_w2[FN], s_b2;
  if(threadIdx.x < FN*FN) s_w1[threadIdx.x] = w1[threadIdx.x];
  if(threadIdx.x < FN){ s_b1[threadIdx.x] = b1[threadIdx.x]; s_w2[threadIdx.x] = w2[threadIdx.x]; }
  if(threadIdx.x == 0) s_b2 = b2[0];
  __syncthreads();
  int n = blockIdx.x * 256 + threadIdx.x;
  if(n >= NN) return;
  float xv[FN];
  const float4* xp = (const float4*)(xf + (size_t)n * FN);
  #pragma unroll
  for(int q = 0; q < 4; q++){ float4 v = xp[q]; xv[q*4+0]=v.x; xv[q*4+1]=v.y; xv[q*4+2]=v.z; xv[q*4+3]=v.w; }
  float g = s_b2;
  #pragma unroll
  for(int j = 0; j < FN; j++){
    float hj = s_b1[j];
    #pragma unroll
    for(int i = 0; i < FN; i++) hj += xv[i] * s_w1[i*FN + j];
    hj = hj > 0.f ? hj : 0.f;
    g += hj * s_w2[j];
  }
  gate[n] = g;
}

// one wave per graph: segment softmax + weighted x sum
__global__ void attn_pool_kernel(const float* __restrict__ gate, const float* __restrict__ xf,
                                 const int* __restrict__ batch, float* __restrict__ x_att)
{
  int g = blockIdx.x;
  int lane = threadIdx.x;
  int start = lower_bound_i(batch, NN, g);
  int end   = lower_bound_i(batch, NN, g + 1);
  float m = -1e30f;
  for(int n = start + lane; n < end; n += 64) m = fmaxf(m, gate[n]);
  #pragma unroll
  for(int o = 32; o >= 1; o >>= 1) m = fmaxf(m, __shfl_xor(m, o));
  float s = 0.f;
  float acc[FN];
  #pragma unroll
  for(int f = 0; f < FN; f++) acc[f] = 0.f;
  for(int n = start + lane; n < end; n += 64){
    float a = __expf(gate[n] - m);
    s += a;
    const float4* xp = (const float4*)(xf + (size_t)n * FN);
    #pragma unroll
    for(int q = 0; q < 4; q++){
      float4 v = xp[q];
      acc[q*4+0] += a*v.x; acc[q*4+1] += a*v.y; acc[q*4+2] += a*v.z; acc[q*4+3] += a*v.w;
    }
  }
  #pragma unroll
  for(int o = 32; o >= 1; o >>= 1){
    s += __shfl_xor(s, o);
    #pragma unroll
    for(int f = 0; f < FN; f++) acc[f] += __shfl_xor(acc[f], o);
  }
  if(lane < FN){
    float v = (end > start && s > 0.f) ? acc[lane] / s : 0.f;
    x_att[g*FN + lane] = v;
  }
}

// ---- CSR build ----
__global__ void histo_kernel(const int* __restrict__ ei, int* __restrict__ deg){
  int e = blockIdx.x*256 + threadIdx.x;
  if(e < NE) atomicAdd(&deg[ei[NE + e]], 1);
}
__global__ void scan1_kernel(const int* __restrict__ deg, int* __restrict__ bsum){
  __shared__ int s[256];
  int i = blockIdx.x*256 + threadIdx.x;
  s[threadIdx.x] = (i < NN) ? deg[i] : 0;
  __syncthreads();
  for(int off=128; off>0; off>>=1){
    if(threadIdx.x < off) s[threadIdx.x] += s[threadIdx.x+off];
    __syncthreads();
  }
  if(threadIdx.x==0) bsum[blockIdx.x] = s[0];
}
__global__ void scan2_kernel(int* __restrict__ bsum, int nb){
  __shared__ int s[512];
  int t = threadIdx.x;
  s[t] = (t < nb) ? bsum[t] : 0;
  __syncthreads();
  for(int off=1; off<512; off<<=1){
    int tv = (t>=off) ? s[t-off] : 0;
    __syncthreads();
    s[t] += tv;
    __syncthreads();
  }
  if(t < nb) bsum[t] = s[t];
}
__global__ void scan3_kernel(const int* __restrict__ deg, const int* __restrict__ bsum,
                             int* __restrict__ rowptr, int* __restrict__ cursor){
  __shared__ int s[256];
  int t = threadIdx.x;
  int i = blockIdx.x*256 + t;
  int v = (i < NN) ? deg[i] : 0;
  s[t] = v;
  __syncthreads();
  for(int off=1; off<256; off<<=1){
    int tv = (t>=off) ? s[t-off] : 0;
    __syncthreads();
    s[t] += tv;
    __syncthreads();
  }
  int bpre = (blockIdx.x==0) ? 0 : bsum[blockIdx.x-1];
  int excl = bpre + s[t] - v;
  if(i < NN){
    rowptr[i] = excl; cursor[i] = excl;
    if(i == NN-1) rowptr[NN] = excl + v;
  }
}
__global__ void fill_kernel(const int* __restrict__ ei, int* __restrict__ cursor, int* __restrict__ csr){
  int e = blockIdx.x*256 + threadIdx.x;
  if(e < NE){ int pos = atomicAdd(&cursor[ei[NE+e]], 1); csr[pos] = e; }
}

// ---- fused NNConv message GEMM via MFMA ----
// P[e,:] = [h(e) (x) x_src(e) | x_src(e) | 0] bf16;  msg = P @ W (W pre-packed bf16 W^T)
template<int IN, int OUT, int EPB>
__global__ void __launch_bounds__(EPB*4) conv_mfma_kernel(
    const float* __restrict__ nodef, const unsigned int* __restrict__ hpk,
    const int* __restrict__ ei, const unsigned int* __restrict__ wpacku,
    unsigned short* __restrict__ msg)
{
  constexpr int KIN  = KH*IN;
  constexpr int KTOT = KIN + IN;
  constexpr int KMF  = ((KTOT + 31)/32)*32;   // conv1: 288, conv2: 544
  constexpr int KP   = KMF + 8;               // stride 20 banks -> 2-way (free)
  constexpr int NT   = OUT/16;
  constexpr int NTHR = EPB*4;
  __shared__ __align__(16) unsigned short sP[EPB*KP];
  __shared__ __align__(16) unsigned short sW[OUT*KP];
  int tid = threadIdx.x;

  // coalesced uint4 copy of pre-packed W^T (KP divisible by 8)
  {
    uint4* sW4 = (uint4*)sW;
    const uint4* wp4 = (const uint4*)wpacku;
    #pragma unroll
    for(int j = tid; j < OUT*KP/8; j += NTHR) sW4[j] = wp4[j];
  }

  int e_loc = tid >> 2, p = tid & 3;
  int e = blockIdx.x*EPB + e_loc;   // exact grids
  int sn = ei[e];
  float xv[IN];
  {
    const float4* xp = (const float4*)(nodef + (size_t)sn*IN);
    #pragma unroll
    for(int q = 0; q < IN/4; q++){ float4 v = xp[q]; xv[q*4+0]=v.x; xv[q*4+1]=v.y; xv[q*4+2]=v.z; xv[q*4+3]=v.w; }
  }
  float hv[KH];
  {
    const unsigned int* hp = hpk + (size_t)e*8;
    #pragma unroll
    for(int d = 0; d < 8; d++){
      unsigned int u = hp[d];
      hv[2*d] = bf2f(u); hv[2*d+1] = bf2f(u >> 16);
    }
  }
  // interleaved P-row write: thread p writes words p, p+4, ... (2-way bank alias = free)
  {
    unsigned int* sPu = (unsigned int*)sP;
    int rb = e_loc*(KP/2);
    #pragma unroll
    for(int w = p; w < KP/2; w += 4){
      int k = 2*w;
      unsigned int u;
      if(k < KIN){
        float hh = hv[k/IN];
        u = pk2(hh*xv[k%IN], hh*xv[k%IN + 1]);
      } else if(k < KTOT){
        u = pk2(xv[k-KIN], xv[k-KIN+1]);
      } else u = 0u;
      sPu[rb + w] = u;
    }
  }
  __syncthreads();

  int lane = tid & 63;
  int w = tid >> 6;
  int m0 = w*16;
  int nrow = lane & 15, quad = lane >> 4;
  f32x4 acc[NT];
  #pragma unroll
  for(int nt = 0; nt < NT; nt++) acc[nt] = (f32x4){0.f,0.f,0.f,0.f};
  #pragma unroll
  for(int ks = 0; ks < KMF/32; ks++){
    short8 a = *(const short8*)&sP[(m0 + nrow)*KP + ks*32 + quad*8];
    #pragma unroll
    for(int nt = 0; nt < NT; nt++){
      short8 b = *(const short8*)&sW[(nt*16 + nrow)*KP + ks*32 + quad*8];
      acc[nt] = __builtin_amdgcn_mfma_f32_16x16x32_bf16(a, b, acc[nt], 0, 0, 0);
    }
  }
  int ebase = blockIdx.x*EPB + m0;
  #pragma unroll
  for(int nt = 0; nt < NT; nt++){
    #pragma unroll
    for(int r = 0; r < 4; r++){
      int m = quad*4 + r;   // C layout: row=(lane>>4)*4+reg, col=lane&15
      msg[(size_t)(ebase + m)*OUT + nt*16 + nrow] = f2bf(acc[nt][r]);
    }
  }
}

// h1 = relu(x@wr1 + br1 + gather(msg1)); 8 threads/node
__global__ void __launch_bounds__(256) gather1_kernel(
    const float* __restrict__ xf, const unsigned short* __restrict__ msg,
    const int* __restrict__ rowptr, const int* __restrict__ csr,
    const float* __restrict__ wr, const float* __restrict__ br, float* __restrict__ h1)
{
  __shared__ float s_w[FN*H1C], s_b[H1C];
  for(int i = threadIdx.x; i < FN*H1C; i += 256) s_w[i] = wr[i];
  if(threadIdx.x < H1C) s_b[threadIdx.x] = br[threadIdx.x];
  __syncthreads();
  int g = blockIdx.x*256 + threadIdx.x;
  int n = g >> 3, q = g & 7;
  if(n >= NN) return;
  float a0 = s_b[q*4+0], a1 = s_b[q*4+1], a2 = s_b[q*4+2], a3 = s_b[q*4+3];
  int jb = rowptr[n], je = rowptr[n+1];
  for(int j = jb; j < je; j++){
    int eid = csr[j];
    const unsigned int* mp = (const unsigned int*)(msg + (size_t)eid*H1C + q*4);
    unsigned int u0 = mp[0], u1 = mp[1];
    a0 += bf2f(u0); a1 += bf2f(u0 >> 16); a2 += bf2f(u1); a3 += bf2f(u1 >> 16);
  }
  const float* xr = xf + (size_t)n*FN;
  #pragma unroll
  for(int i = 0; i < FN; i++){
    float xi = xr[i];
    a0 += xi*s_w[i*H1C + q*4+0]; a1 += xi*s_w[i*H1C + q*4+1];
    a2 += xi*s_w[i*H1C + q*4+2]; a3 += xi*s_w[i*H1C + q*4+3];
  }
  float4 r; r.x = a0>0.f?a0:0.f; r.y = a1>0.f?a1:0.f; r.z = a2>0.f?a2:0.f; r.w = a3>0.f?a3:0.f;
  *(float4*)(h1 + (size_t)n*H1C + q*4) = r;
}

// h2 = relu(h1@wr2 + br2 + gather(msg2)); 4 threads/node
__global__ void __launch_bounds__(256) gather2_kernel(
    const float* __restrict__ h1, const unsigned short* __restrict__ msg,
    const int* __restrict__ rowptr, const int* __restrict__ csr,
    const float* __restrict__ wr, const float* __restrict__ br, float* __restrict__ h2)
{
  __shared__ float s_w[H1C*H2C], s_b[H2C];
  for(int i = threadIdx.x; i < H1C*H2C; i += 256) s_w[i] = wr[i];
  if(threadIdx.x < H2C) s_b[threadIdx.x] = br[threadIdx.x];
  __syncthreads();
  int g = blockIdx.x*256 + threadIdx.x;
  int n = g >> 2, q = g & 3;
  if(n >= NN) return;
  float a0 = s_b[q*4+0], a1 = s_b[q*4+1], a2 = s_b[q*4+2], a3 = s_b[q*4+3];
  int jb = rowptr[n], je = rowptr[n+1];
  for(int j = jb; j < je; j++){
    int eid = csr[j];
    const unsigned int* mp = (const unsigned int*)(msg + (size_t)eid*H2C + q*4);
    unsigned int u0 = mp[0], u1 = mp[1];
    a0 += bf2f(u0); a1 += bf2f(u0 >> 16); a2 += bf2f(u1); a3 += bf2f(u1 >> 16);
  }
  const float* hr = h1 + (size_t)n*H1C;
  #pragma unroll
  for(int i = 0; i < H1C; i++){
    float xi = hr[i];
    a0 += xi*s_w[i*H2C + q*4+0]; a1 += xi*s_w[i*H2C + q*4+1];
    a2 += xi*s_w[i*H2C + q*4+2]; a3 += xi*s_w[i*H2C + q*4+3];
  }
  float4 r; r.x = a0>0.f?a0:0.f; r.y = a1>0.f?a1:0.f; r.z = a2>0.f?a2:0.f; r.w = a3>0.f?a3:0.f;
  *(float4*)(h2 + (size_t)n*H2C + q*4) = r;
}

// one wave per graph: mean-pool h2 + concat x_att + 2-layer head
__global__ void head_kernel(const float* __restrict__ h2, const float* __restrict__ x_att,
    const int* __restrict__ batch,
    const float* __restrict__ wl1, const float* __restrict__ bl1,
    const float* __restrict__ wl2, const float* __restrict__ bl2,
    void* __restrict__ out, const int* __restrict__ flag)
{
  int g = blockIdx.x;
  int lane = threadIdx.x;
  int start = lower_bound_i(batch, NN, g);
  int end   = lower_bound_i(batch, NN, g + 1);
  float acc[H2C];
  #pragma unroll
  for(int f = 0; f < H2C; f++) acc[f] = 0.f;
  for(int n = start + lane; n < end; n += 64){
    const float4* hp = (const float4*)(h2 + (size_t)n*H2C);
    #pragma unroll
    for(int q = 0; q < 4; q++){
      float4 v = hp[q];
      acc[q*4+0] += v.x; acc[q*4+1] += v.y; acc[q*4+2] += v.z; acc[q*4+3] += v.w;
    }
  }
  #pragma unroll
  for(int o = 32; o >= 1; o >>= 1){
    #pragma unroll
    for(int f = 0; f < H2C; f++) acc[f] += __shfl_xor(acc[f], o);
  }
  if(lane == 0){
    float inv = 1.f / fmaxf((float)(end - start), 1.f);
    float z[H2C + FN];
    #pragma unroll
    for(int f = 0; f < H2C; f++) z[f] = acc[f] * inv;
    #pragma unroll
    for(int f = 0; f < FN; f++) z[H2C + f] = x_att[(size_t)g*FN + f];
    float t1[8];
    #pragma unroll
    for(int j = 0; j < 8; j++){
      float t = bl1[j];
      #pragma unroll
      for(int c = 0; c < H2C + FN; c++) t += z[c] * wl1[c*8 + j];
      t1[j] = t;
    }
    float o = bl2[0];
    #pragma unroll
    for(int j = 0; j < 8; j++) o += t1[j] * wl2[j];
    if((*flag) != 0) ((__hip_bfloat16*)out)[g] = __float2bfloat16(o);
    else             ((float*)out)[g] = o;
  }
}

extern "C" void kernel_launch(void* const* d_in, const int* in_sizes, int n_in,
                              void* d_out, int out_size, void* d_ws, size_t ws_size,
                              hipStream_t stream)
{
  const int* ei    = (const int*)d_in[22];
  const int* batch = (const int*)d_in[23];

  float* ws = (float*)d_ws;
  float* xf     = ws;                          // 1,600,000 f
  float* ef     = xf + 1600000;                // 1,600,000 f
  float* gate   = ef + 1600000;                //   100,000 f
  float* x_att  = gate + 100000;               //    40,000 f
  float* wts    = x_att + 40000;               //    19,360 f
  int*   rowptr = (int*)(wts + 19360);         //   100,016 i
  int*   cursor = rowptr + 100016;             //   100,000 i
  int*   deg    = cursor + 100000;             //   100,000 i
  int*   bsum   = deg + 100000;                //       512 i
  int*   csr    = bsum + 512;                  //   200,000 i
  int*   flagp  = csr + 200000;                //        16 i
  unsigned int* wpack1 = (unsigned int*)(flagp + 16);   // 4,736 u32 (32x296 us)
  unsigned int* wpack2 = wpack1 + 4736;                 // 4,416 u32 (16x552 us)
  float* h1     = (float*)(wpack2 + 4416);     // 3,200,000 f
  unsigned short* msg1 = (unsigned short*)(h1 + 3200000);  // 6,400,000 us
  float* h2     = (float*)(msg1 + 6400000);    // 1,600,000 f
  unsigned int* hpk = (unsigned int*)h2;       // alias: 1,600,000 u32 (dead before gather2)
  unsigned short* msg2 = msg1;                 // reuse after gather1

  WArgs wa;
  for(int i = 0; i < NW; i++) wa.p[i] = d_in[2 + i];

  detect_kernel<<<1, 256, 0, stream>>>(d_in[0], flagp);
  cvt_any<<<512, 256, 0, stream>>>(d_in[0], xf, NN*FN, flagp);
  cvt_any<<<512, 256, 0, stream>>>(d_in[1], ef, NE*FE, flagp);
  cvt_weights_kernel<<<(W_TOTAL + 255)/256, 256, 0, stream>>>(wa, wts, flagp);
  hipMemsetAsync(deg, 0, NN*sizeof(int), stream);

  pack_w_kernel<FN, H1C><<<(4736 + 255)/256, 256, 0, stream>>>(wts+OW_E1B, wts+OB_E1B, wpack1);
  pack_w_kernel<H1C, H2C><<<(4416 + 255)/256, 256, 0, stream>>>(wts+OW_E2B, wts+OB_E2B, wpack2);

  gate_kernel<<<(NN + 255)/256, 256, 0, stream>>>(xf, wts+OW_G1, wts+OB_G1, wts+OW_G2, wts+OB_G2, gate);
  attn_pool_kernel<<<NG, 64, 0, stream>>>(gate, xf, batch, x_att);

  const int NB1 = (NN + 255)/256;  // 391
  histo_kernel<<<(NE + 255)/256, 256, 0, stream>>>(ei, deg);
  scan1_kernel<<<NB1, 256, 0, stream>>>(deg, bsum);
  scan2_kernel<<<1, 512, 0, stream>>>(bsum, NB1);
  scan3_kernel<<<NB1, 256, 0, stream>>>(deg, bsum, rowptr, cursor);
  fill_kernel<<<(NE + 255)/256, 256, 0, stream>>>(ei, cursor, csr);

  edge_h_kernel<<<NE*8/256, 256, 0, stream>>>(ef, wts+OW_E1A, wts+OB_E1A, hpk);
  conv_mfma_kernel<FN, H1C, 64><<<NE/64, 256, 0, stream>>>(xf, hpk, ei, wpack1, msg1);
  gather1_kernel<<<(NN*8 + 255)/256, 256, 0, stream>>>(xf, msg1, rowptr, csr, wts+OW_R1, wts+OB_R1, h1);

  edge_h_kernel<<<NE*8/256, 256, 0, stream>>>(ef, wts+OW_E2A, wts+OB_E2A, hpk);
  conv_mfma_kernel<H1C, H2C, 32><<<NE/32, 128, 0, stream>>>(h1, hpk, ei, wpack2, msg2);
  gather2_kernel<<<(NN*4 + 255)/256, 256, 0, stream>>>(h1, msg2, rowptr, csr, wts+OW_R2, wts+OB_R2, h2);

  head_kernel<<<NG, 64, 0, stream>>>(h2, x_att, batch,
      wts+OW_L1, wts+OB_L1, wts+OW_L2, wts+OB_L2, d_out, flagp);
}

// Round 5
// 519.930 us; speedup vs baseline: 1.3696x; 1.3696x over previous
//
#include <hip/hip_runtime.h>
#include <hip/hip_bf16.h>

#define NN 100000   // nodes
#define NE 200000   // edges
#define NG 2500     // graphs
#define FN 16       // node feats
#define FE 8        // edge feats
#define H1C 32
#define H2C 16
#define KH 16       // edge-MLP hidden

typedef __attribute__((ext_vector_type(8))) short short8;
typedef __attribute__((ext_vector_type(4))) float f32x4;

__device__ __forceinline__ float bf2f(unsigned int u){
  union { unsigned int i; float f; } v; v.i = (u & 0xffffu) << 16; return v.f;
}
__device__ __forceinline__ unsigned short f2bf(float f){
  union { float f; unsigned int i; } u; u.f = f;
  unsigned int r = u.i + 0x7fffu + ((u.i >> 16) & 1u);   // RNE, finite data
  return (unsigned short)(r >> 16);
}
__device__ __forceinline__ unsigned int pk2(float a, float b){
  return (unsigned int)f2bf(a) | ((unsigned int)f2bf(b) << 16);
}
__device__ __forceinline__ float rdf(const void* p, long i, bool isbf){
  return isbf ? bf2f(((const unsigned short*)p)[i]) : ((const float*)p)[i];
}
__device__ __forceinline__ int lower_bound_i(const int* __restrict__ a, int n, int v){
  int lo = 0, hi = n;
  while(lo < hi){ int mid = (lo + hi) >> 1; if(a[mid] < v) lo = mid + 1; else hi = mid; }
  return lo;
}

// flag=1 if float inputs are bf16, 0 if fp32
__global__ void detect_kernel(const void* __restrict__ x, int* __restrict__ flag){
  int tid = threadIdx.x;
  const unsigned short* u = (const unsigned short*)x;
  float f = bf2f(u[2*tid]);
  float a = fabsf(f);
  int sane = (f == 0.0f) || (a > 1e-4f && a < 1e4f);
  __shared__ int cnt;
  if(tid == 0) cnt = 0;
  __syncthreads();
  if(sane) atomicAdd(&cnt, 1);
  __syncthreads();
  if(tid == 0) *flag = (cnt >= 128) ? 1 : 0;
}

#define NW 20
struct WArgs { const void* p[NW]; };
#define W_TOTAL 19330
enum {
  OW_E1A=0,     OB_E1A=128,   OW_E1B=144,   OB_E1B=8336,  OW_R1=8848,  OB_R1=9360,
  OW_E2A=9392,  OB_E2A=9520,  OW_E2B=9536,  OB_E2B=17728, OW_R2=18240, OB_R2=18752,
  OW_G1=18768,  OB_G1=19024,  OW_G2=19040,  OB_G2=19056,
  OW_L1=19057,  OB_L1=19313,  OW_L2=19321,  OB_L2=19329
};

// mega-setup: x-cvt | wts-cvt | pack W1^T | pack W2^T | deg=0 | edge-MLP-1
// All regions independent; packs/edge-MLP read raw d_in with inline cvt.
#define SE0 1600000L
#define SE1 (SE0 + 19330L)
#define SE2 (SE1 + 4736L)
#define SE3 (SE2 + 4416L)
#define SE4 (SE3 + 100000L)
#define SE5 (SE4 + 1600000L)
__global__ void __launch_bounds__(256) setup_kernel(
    const void* __restrict__ xin, const void* __restrict__ efin, WArgs w,
    const int* __restrict__ flag, float* __restrict__ xf, float* __restrict__ wts,
    unsigned int* __restrict__ wpack1, unsigned int* __restrict__ wpack2,
    int* __restrict__ deg, unsigned int* __restrict__ hpk1)
{
  bool isbf = (*flag) != 0;
  long t = (long)blockIdx.x*256 + threadIdx.x;
  if(t < SE0){ xf[t] = rdf(xin, t, isbf); return; }
  if(t < SE1){
    const int sz[NW] = {128,16,8192,512,512,32, 128,16,8192,512,512,16, 256,16,16,1, 256,8,8,1};
    long i = t - SE0;
    int seg = 0; long base = 0;
    while(i - base >= sz[seg]){ base += sz[seg]; seg++; }
    wts[i] = rdf(w.p[seg], i - base, isbf);
    return;
  }
  if(t < SE2){   // pack1: 32 rows x 148 u32 (KP=296)
    long j = t - SE1;
    int n = (int)(j / 148); int k = (int)(j % 148) * 2;
    float v0 = 0.f, v1 = 0.f;
    if(k < 256)        v0 = rdf(w.p[2], (long)k*32 + n, isbf);
    else if(k < 272)   v0 = rdf(w.p[3], (long)(k-256)*32 + n, isbf);
    if(k+1 < 256)      v1 = rdf(w.p[2], (long)(k+1)*32 + n, isbf);
    else if(k+1 < 272) v1 = rdf(w.p[3], (long)(k+1-256)*32 + n, isbf);
    wpack1[j] = pk2(v0, v1);
    return;
  }
  if(t < SE3){   // pack2: 16 rows x 276 u32 (KP=552)
    long j = t - SE2;
    int n = (int)(j / 276); int k = (int)(j % 276) * 2;
    float v0 = 0.f, v1 = 0.f;
    if(k < 512)        v0 = rdf(w.p[8], (long)k*16 + n, isbf);
    else if(k < 544)   v0 = rdf(w.p[9], (long)(k-512)*16 + n, isbf);
    if(k+1 < 512)      v1 = rdf(w.p[8], (long)(k+1)*16 + n, isbf);
    else if(k+1 < 544) v1 = rdf(w.p[9], (long)(k+1-512)*16 + n, isbf);
    wpack2[j] = pk2(v0, v1);
    return;
  }
  if(t < SE4){ deg[t - SE3] = 0; return; }
  if(t < SE5){   // edge-MLP for conv1 -> hpk1
    long tt = t - SE4;
    long e = tt >> 3; int d = (int)(tt & 7);
    float h0 = rdf(w.p[1], 2*d, isbf), h1 = rdf(w.p[1], 2*d+1, isbf);
    #pragma unroll
    for(int j = 0; j < FE; j++){
      float ev = rdf(efin, e*FE + j, isbf);
      h0 += ev * rdf(w.p[0], j*KH + 2*d, isbf);
      h1 += ev * rdf(w.p[0], j*KH + 2*d+1, isbf);
    }
    h0 = h0 > 0.f ? h0 : 0.f;
    h1 = h1 > 0.f ? h1 : 0.f;
    hpk1[tt] = pk2(h0, h1);
  }
}

// standalone edge-MLP (conv2): hpk[e*8+d] = pack(relu(ea@wa+ba)[2d],[2d+1])
__global__ void __launch_bounds__(256) edge_h_kernel(
    const void* __restrict__ efin, const void* __restrict__ wa, const void* __restrict__ ba,
    const int* __restrict__ flag, unsigned int* __restrict__ hpk)
{
  bool isbf = (*flag) != 0;
  long t = (long)blockIdx.x*256 + threadIdx.x;   // exact grid NE*8
  long e = t >> 3; int d = (int)(t & 7);
  float h0 = rdf(ba, 2*d, isbf), h1 = rdf(ba, 2*d+1, isbf);
  #pragma unroll
  for(int j = 0; j < FE; j++){
    float ev = rdf(efin, e*FE + j, isbf);
    h0 += ev * rdf(wa, j*KH + 2*d, isbf);
    h1 += ev * rdf(wa, j*KH + 2*d+1, isbf);
  }
  h0 = h0 > 0.f ? h0 : 0.f;
  h1 = h1 > 0.f ? h1 : 0.f;
  hpk[t] = pk2(h0, h1);
}

// one wave per graph: inline gate MLP + segment softmax + weighted x sum
__global__ void attn_pool_kernel(const float* __restrict__ xf, const int* __restrict__ batch,
                                 const float* __restrict__ wts, float* __restrict__ x_att)
{
  __shared__ float s_w1[FN*FN], s_b1[FN], s_w2[FN], s_b2v[1];
  int g = blockIdx.x;
  int lane = threadIdx.x;
  for(int i = lane; i < FN*FN; i += 64) s_w1[i] = wts[OW_G1 + i];
  if(lane < FN){ s_b1[lane] = wts[OB_G1 + lane]; s_w2[lane] = wts[OW_G2 + lane]; }
  if(lane == 0) s_b2v[0] = wts[OB_G2];
  __syncthreads();
  int start = lower_bound_i(batch, NN, g);
  int end   = lower_bound_i(batch, NN, g + 1);

  float m = -1e30f;
  for(int n = start + lane; n < end; n += 64){
    float xv[FN];
    const float4* xp = (const float4*)(xf + (size_t)n * FN);
    #pragma unroll
    for(int q = 0; q < 4; q++){ float4 v = xp[q]; xv[q*4+0]=v.x; xv[q*4+1]=v.y; xv[q*4+2]=v.z; xv[q*4+3]=v.w; }
    float gt = s_b2v[0];
    #pragma unroll
    for(int j = 0; j < FN; j++){
      float hj = s_b1[j];
      #pragma unroll
      for(int i = 0; i < FN; i++) hj += xv[i] * s_w1[i*FN + j];
      hj = hj > 0.f ? hj : 0.f;
      gt += hj * s_w2[j];
    }
    m = fmaxf(m, gt);
  }
  #pragma unroll
  for(int o = 32; o >= 1; o >>= 1) m = fmaxf(m, __shfl_xor(m, o));

  float s = 0.f;
  float acc[FN];
  #pragma unroll
  for(int f = 0; f < FN; f++) acc[f] = 0.f;
  for(int n = start + lane; n < end; n += 64){
    float xv[FN];
    const float4* xp = (const float4*)(xf + (size_t)n * FN);
    #pragma unroll
    for(int q = 0; q < 4; q++){ float4 v = xp[q]; xv[q*4+0]=v.x; xv[q*4+1]=v.y; xv[q*4+2]=v.z; xv[q*4+3]=v.w; }
    float gt = s_b2v[0];
    #pragma unroll
    for(int j = 0; j < FN; j++){
      float hj = s_b1[j];
      #pragma unroll
      for(int i = 0; i < FN; i++) hj += xv[i] * s_w1[i*FN + j];
      hj = hj > 0.f ? hj : 0.f;
      gt += hj * s_w2[j];
    }
    float a = __expf(gt - m);
    s += a;
    #pragma unroll
    for(int f = 0; f < FN; f++) acc[f] += a * xv[f];
  }
  #pragma unroll
  for(int o = 32; o >= 1; o >>= 1){
    s += __shfl_xor(s, o);
    #pragma unroll
    for(int f = 0; f < FN; f++) acc[f] += __shfl_xor(acc[f], o);
  }
  if(lane < FN){
    float v = (end > start && s > 0.f) ? acc[lane] / s : 0.f;
    x_att[g*FN + lane] = v;
  }
}

// ---- CSR build ----
__global__ void histo_kernel(const int* __restrict__ ei, int* __restrict__ deg){
  int e = blockIdx.x*256 + threadIdx.x;
  if(e < NE) atomicAdd(&deg[ei[NE + e]], 1);
}
__global__ void scan1_kernel(const int* __restrict__ deg, int* __restrict__ bsum){
  __shared__ int s[256];
  int i = blockIdx.x*256 + threadIdx.x;
  s[threadIdx.x] = (i < NN) ? deg[i] : 0;
  __syncthreads();
  for(int off=128; off>0; off>>=1){
    if(threadIdx.x < off) s[threadIdx.x] += s[threadIdx.x+off];
    __syncthreads();
  }
  if(threadIdx.x==0) bsum[blockIdx.x] = s[0];
}
__global__ void scan2_kernel(int* __restrict__ bsum, int nb){
  __shared__ int s[512];
  int t = threadIdx.x;
  s[t] = (t < nb) ? bsum[t] : 0;
  __syncthreads();
  for(int off=1; off<512; off<<=1){
    int tv = (t>=off) ? s[t-off] : 0;
    __syncthreads();
    s[t] += tv;
    __syncthreads();
  }
  if(t < nb) bsum[t] = s[t];
}
__global__ void scan3_kernel(const int* __restrict__ deg, const int* __restrict__ bsum,
                             int* __restrict__ rowptr, int* __restrict__ cursor){
  __shared__ int s[256];
  int t = threadIdx.x;
  int i = blockIdx.x*256 + t;
  int v = (i < NN) ? deg[i] : 0;
  s[t] = v;
  __syncthreads();
  for(int off=1; off<256; off<<=1){
    int tv = (t>=off) ? s[t-off] : 0;
    __syncthreads();
    s[t] += tv;
    __syncthreads();
  }
  int bpre = (blockIdx.x==0) ? 0 : bsum[blockIdx.x-1];
  int excl = bpre + s[t] - v;
  if(i < NN){
    rowptr[i] = excl; cursor[i] = excl;
    if(i == NN-1) rowptr[NN] = excl + v;
  }
}
__global__ void fill_kernel(const int* __restrict__ ei, int* __restrict__ cursor, int* __restrict__ csr){
  int e = blockIdx.x*256 + threadIdx.x;
  if(e < NE){ int pos = atomicAdd(&cursor[ei[NE+e]], 1); csr[pos] = e; }
}

// ---- NNConv message GEMM via MFMA ----
// P[e,:] = [h (x) x_src | x_src | 0] bf16 in LDS; B-fragments direct from global wpack.
// NTHR = 2*EPB threads (2 threads build each P row, STATIC indexing only);
// each wave computes 32 edges = 2 M-tiles, reusing register B-frags.
template<int IN, int OUT, int EPB, int NTHR>
__global__ void __launch_bounds__(NTHR) conv_mfma_kernel(
    const float* __restrict__ nodef, const unsigned int* __restrict__ hpk,
    const int* __restrict__ ei, const unsigned short* __restrict__ wpack,
    unsigned short* __restrict__ msg)
{
  constexpr int KIN  = KH*IN;                 // 256 | 512
  constexpr int KTOT = KIN + IN;              // 272 | 544
  constexpr int KMF  = ((KTOT + 31)/32)*32;   // 288 | 544
  constexpr int KP   = KMF + 8;               // 296 | 552 (words stride mod 32 = 20 -> spread)
  constexpr int NT   = OUT/16;                // 2 | 1
  constexpr int KS   = KMF/32;                // 9 | 17
  __shared__ __align__(16) unsigned short sP[EPB*KP];
  int tid = threadIdx.x;
  int lane = tid & 63, nrow = lane & 15, quad = lane >> 4;

  // per-edge inputs (2 threads per edge)
  int e_loc = tid >> 1, q = tid & 1;
  int e = blockIdx.x*EPB + e_loc;   // exact grids
  int sn = ei[e];
  float xv[IN];
  {
    const float4* xp = (const float4*)(nodef + (size_t)sn*IN);
    #pragma unroll
    for(int k = 0; k < IN/4; k++){ float4 v = xp[k]; xv[k*4+0]=v.x; xv[k*4+1]=v.y; xv[k*4+2]=v.z; xv[k*4+3]=v.w; }
  }
  float hh[8];
  {
    const unsigned int* hp = hpk + (size_t)e*8 + q*4;
    #pragma unroll
    for(int d = 0; d < 4; d++){
      unsigned int u = hp[d];
      hh[2*d] = bf2f(u); hh[2*d+1] = bf2f(u >> 16);
    }
  }
  // B-fragments straight from L2-hot packed W^T (independent of LDS/barrier)
  short8 bfr[KS][NT];
  {
    const short8* wp8 = (const short8*)wpack;
    #pragma unroll
    for(int ks = 0; ks < KS; ks++)
      #pragma unroll
      for(int nt = 0; nt < NT; nt++)
        bfr[ks][nt] = wp8[((nt*16 + nrow)*KP + ks*32 + quad*8) >> 3];
  }
  // P-row build: thread q writes h-chunks q*8..q*8+7 (all indices static)
  {
    unsigned int* sPu = (unsigned int*)sP;
    const int rb = e_loc*(KP/2);
    #pragma unroll
    for(int j = 0; j < 8; j++){
      float h = hh[j];
      int cb = rb + (q*8 + j)*(IN/2);
      #pragma unroll
      for(int i2 = 0; i2 < IN/2; i2++) sPu[cb + i2] = pk2(h*xv[2*i2], h*xv[2*i2+1]);
    }
    if(IN == 16){
      if(q == 0){
        int cb = rb + 128;   // x part, k 256..271
        #pragma unroll
        for(int i2 = 0; i2 < 8; i2++) sPu[cb + i2] = pk2(xv[2*i2], xv[2*i2+1]);
      } else {
        int cb = rb + 136;   // zero pad, k 272..287 (read by last k-step)
        #pragma unroll
        for(int i2 = 0; i2 < 8; i2++) sPu[cb + i2] = 0u;
      }
    } else {                 // IN==32: x part k 512..543, split between q
      int cb = rb + 256 + q*8;
      #pragma unroll
      for(int i2 = 0; i2 < 8; i2++) sPu[cb + i2] = pk2(xv[16*q + 2*i2], xv[16*q + 2*i2 + 1]);
    }
  }
  __syncthreads();

  // MFMA: wave handles 32 edges = 2 tiles
  int mwb = (tid >> 6) * 32;
  f32x4 acc[2][NT];
  #pragma unroll
  for(int t2 = 0; t2 < 2; t2++)
    #pragma unroll
    for(int nt = 0; nt < NT; nt++) acc[t2][nt] = (f32x4){0.f,0.f,0.f,0.f};
  #pragma unroll
  for(int ks = 0; ks < KS; ks++){
    short8 a0 = *(const short8*)&sP[(mwb + nrow)*KP + ks*32 + quad*8];
    short8 a1 = *(const short8*)&sP[(mwb + 16 + nrow)*KP + ks*32 + quad*8];
    #pragma unroll
    for(int nt = 0; nt < NT; nt++){
      acc[0][nt] = __builtin_amdgcn_mfma_f32_16x16x32_bf16(a0, bfr[ks][nt], acc[0][nt], 0, 0, 0);
      acc[1][nt] = __builtin_amdgcn_mfma_f32_16x16x32_bf16(a1, bfr[ks][nt], acc[1][nt], 0, 0, 0);
    }
  }
  int ebase = blockIdx.x*EPB + mwb;
  #pragma unroll
  for(int t2 = 0; t2 < 2; t2++)
    #pragma unroll
    for(int nt = 0; nt < NT; nt++)
      #pragma unroll
      for(int r = 0; r < 4; r++){
        int m = t2*16 + quad*4 + r;   // C layout: row=(lane>>4)*4+reg, col=lane&15
        msg[(size_t)(ebase + m)*OUT + nt*16 + nrow] = f2bf(acc[t2][nt][r]);
      }
}

// h1 = relu(x@wr1 + br1 + gather(msg1)); 8 threads/node
__global__ void __launch_bounds__(256) gather1_kernel(
    const float* __restrict__ xf, const unsigned short* __restrict__ msg,
    const int* __restrict__ rowptr, const int* __restrict__ csr,
    const float* __restrict__ wr, const float* __restrict__ br, float* __restrict__ h1)
{
  __shared__ float s_w[FN*H1C], s_b[H1C];
  for(int i = threadIdx.x; i < FN*H1C; i += 256) s_w[i] = wr[i];
  if(threadIdx.x < H1C) s_b[threadIdx.x] = br[threadIdx.x];
  __syncthreads();
  int g = blockIdx.x*256 + threadIdx.x;
  int n = g >> 3, q = g & 7;
  if(n >= NN) return;
  float a0 = s_b[q*4+0], a1 = s_b[q*4+1], a2 = s_b[q*4+2], a3 = s_b[q*4+3];
  int jb = rowptr[n], je = rowptr[n+1];
  for(int j = jb; j < je; j++){
    int eid = csr[j];
    const unsigned int* mp = (const unsigned int*)(msg + (size_t)eid*H1C + q*4);
    unsigned int u0 = mp[0], u1 = mp[1];
    a0 += bf2f(u0); a1 += bf2f(u0 >> 16); a2 += bf2f(u1); a3 += bf2f(u1 >> 16);
  }
  const float* xr = xf + (size_t)n*FN;
  #pragma unroll
  for(int i = 0; i < FN; i++){
    float xi = xr[i];
    a0 += xi*s_w[i*H1C + q*4+0]; a1 += xi*s_w[i*H1C + q*4+1];
    a2 += xi*s_w[i*H1C + q*4+2]; a3 += xi*s_w[i*H1C + q*4+3];
  }
  float4 r; r.x = a0>0.f?a0:0.f; r.y = a1>0.f?a1:0.f; r.z = a2>0.f?a2:0.f; r.w = a3>0.f?a3:0.f;
  *(float4*)(h1 + (size_t)n*H1C + q*4) = r;
}

// h2 = relu(h1@wr2 + br2 + gather(msg2)); 4 threads/node
__global__ void __launch_bounds__(256) gather2_kernel(
    const float* __restrict__ h1, const unsigned short* __restrict__ msg,
    const int* __restrict__ rowptr, const int* __restrict__ csr,
    const float* __restrict__ wr, const float* __restrict__ br, float* __restrict__ h2)
{
  __shared__ float s_w[H1C*H2C], s_b[H2C];
  for(int i = threadIdx.x; i < H1C*H2C; i += 256) s_w[i] = wr[i];
  if(threadIdx.x < H2C) s_b[threadIdx.x] = br[threadIdx.x];
  __syncthreads();
  int g = blockIdx.x*256 + threadIdx.x;
  int n = g >> 2, q = g & 3;
  if(n >= NN) return;
  float a0 = s_b[q*4+0], a1 = s_b[q*4+1], a2 = s_b[q*4+2], a3 = s_b[q*4+3];
  int jb = rowptr[n], je = rowptr[n+1];
  for(int j = jb; j < je; j++){
    int eid = csr[j];
    const unsigned int* mp = (const unsigned int*)(msg + (size_t)eid*H2C + q*4);
    unsigned int u0 = mp[0], u1 = mp[1];
    a0 += bf2f(u0); a1 += bf2f(u0 >> 16); a2 += bf2f(u1); a3 += bf2f(u1 >> 16);
  }
  const float* hr = h1 + (size_t)n*H1C;
  #pragma unroll
  for(int i = 0; i < H1C; i++){
    float xi = hr[i];
    a0 += xi*s_w[i*H2C + q*4+0]; a1 += xi*s_w[i*H2C + q*4+1];
    a2 += xi*s_w[i*H2C + q*4+2]; a3 += xi*s_w[i*H2C + q*4+3];
  }
  float4 r; r.x = a0>0.f?a0:0.f; r.y = a1>0.f?a1:0.f; r.z = a2>0.f?a2:0.f; r.w = a3>0.f?a3:0.f;
  *(float4*)(h2 + (size_t)n*H2C + q*4) = r;
}

// one wave per graph: mean-pool h2 + concat x_att + 2-layer head
__global__ void head_kernel(const float* __restrict__ h2, const float* __restrict__ x_att,
    const int* __restrict__ batch,
    const float* __restrict__ wl1, const float* __restrict__ bl1,
    const float* __restrict__ wl2, const float* __restrict__ bl2,
    void* __restrict__ out, const int* __restrict__ flag)
{
  int g = blockIdx.x;
  int lane = threadIdx.x;
  int start = lower_bound_i(batch, NN, g);
  int end   = lower_bound_i(batch, NN, g + 1);
  float acc[H2C];
  #pragma unroll
  for(int f = 0; f < H2C; f++) acc[f] = 0.f;
  for(int n = start + lane; n < end; n += 64){
    const float4* hp = (const float4*)(h2 + (size_t)n*H2C);
    #pragma unroll
    for(int q = 0; q < 4; q++){
      float4 v = hp[q];
      acc[q*4+0] += v.x; acc[q*4+1] += v.y; acc[q*4+2] += v.z; acc[q*4+3] += v.w;
    }
  }
  #pragma unroll
  for(int o = 32; o >= 1; o >>= 1){
    #pragma unroll
    for(int f = 0; f < H2C; f++) acc[f] += __shfl_xor(acc[f], o);
  }
  if(lane == 0){
    float inv = 1.f / fmaxf((float)(end - start), 1.f);
    float z[H2C + FN];
    #pragma unroll
    for(int f = 0; f < H2C; f++) z[f] = acc[f] * inv;
    #pragma unroll
    for(int f = 0; f < FN; f++) z[H2C + f] = x_att[(size_t)g*FN + f];
    float t1[8];
    #pragma unroll
    for(int j = 0; j < 8; j++){
      float t = bl1[j];
      #pragma unroll
      for(int c = 0; c < H2C + FN; c++) t += z[c] * wl1[c*8 + j];
      t1[j] = t;
    }
    float o = bl2[0];
    #pragma unroll
    for(int j = 0; j < 8; j++) o += t1[j] * wl2[j];
    if((*flag) != 0) ((__hip_bfloat16*)out)[g] = __float2bfloat16(o);
    else             ((float*)out)[g] = o;
  }
}

extern "C" void kernel_launch(void* const* d_in, const int* in_sizes, int n_in,
                              void* d_out, int out_size, void* d_ws, size_t ws_size,
                              hipStream_t stream)
{
  const int* ei    = (const int*)d_in[22];
  const int* batch = (const int*)d_in[23];

  float* ws = (float*)d_ws;
  float* xf     = ws;                          // 1,600,000 f
  float* x_att  = xf + 1600000;                //    40,000 f
  float* wts    = x_att + 40000;               //    19,360 f
  int*   rowptr = (int*)(wts + 19360);         //   100,016 i
  int*   cursor = rowptr + 100016;             //   100,000 i
  int*   deg    = cursor + 100000;             //   100,000 i
  int*   bsum   = deg + 100000;                //       512 i
  int*   csr    = bsum + 512;                  //   200,000 i
  int*   flagp  = csr + 200000;                //        16 i
  unsigned int* wpack1 = (unsigned int*)(flagp + 16);   // 4,736 u32
  unsigned int* wpack2 = wpack1 + 4736;                 // 4,416 u32
  float* h1     = (float*)(wpack2 + 4416);     // 3,200,000 f
  unsigned int* hpk1 = (unsigned int*)h1;      // alias: dead once conv1 done, before gather1 writes h1
  unsigned short* msg1 = (unsigned short*)(h1 + 3200000);  // 6,400,000 u16
  unsigned short* msg2 = msg1;                 // reuse after gather1
  float* h2     = (float*)(msg1 + 6400000);    // 1,600,000 f
  unsigned int* hpk2 = (unsigned int*)h2;      // alias: dead once conv2 done, before gather2 writes h2
  // total ~40.7 MB

  WArgs wa;
  for(int i = 0; i < NW; i++) wa.p[i] = d_in[2 + i];

  detect_kernel<<<1, 256, 0, stream>>>(d_in[0], flagp);
  setup_kernel<<<(int)((SE5 + 255)/256), 256, 0, stream>>>(
      d_in[0], d_in[1], wa, flagp, xf, wts, wpack1, wpack2, deg, hpk1);

  const int NB1 = (NN + 255)/256;  // 391
  histo_kernel<<<(NE + 255)/256, 256, 0, stream>>>(ei, deg);
  scan1_kernel<<<NB1, 256, 0, stream>>>(deg, bsum);
  scan2_kernel<<<1, 512, 0, stream>>>(bsum, NB1);
  scan3_kernel<<<NB1, 256, 0, stream>>>(deg, bsum, rowptr, cursor);
  fill_kernel<<<(NE + 255)/256, 256, 0, stream>>>(ei, cursor, csr);

  attn_pool_kernel<<<NG, 64, 0, stream>>>(xf, batch, wts, x_att);

  conv_mfma_kernel<FN, H1C, 64, 128><<<NE/64, 128, 0, stream>>>(
      xf, hpk1, ei, (const unsigned short*)wpack1, msg1);
  gather1_kernel<<<(NN*8 + 255)/256, 256, 0, stream>>>(xf, msg1, rowptr, csr, wts+OW_R1, wts+OB_R1, h1);

  edge_h_kernel<<<NE*8/256, 256, 0, stream>>>(d_in[1], d_in[8], d_in[9], flagp, hpk2);
  conv_mfma_kernel<H1C, H2C, 32, 64><<<NE/32, 64, 0, stream>>>(
      h1, hpk2, ei, (const unsigned short*)wpack2, msg2);
  gather2_kernel<<<(NN*4 + 255)/256, 256, 0, stream>>>(h1, msg2, rowptr, csr, wts+OW_R2, wts+OB_R2, h2);

  head_kernel<<<NG, 64, 0, stream>>>(h2, x_att, batch,
      wts+OW_L1, wts+OB_L1, wts+OW_L2, wts+OB_L2, d_out, flagp);
}

// Round 6
// 344.479 us; speedup vs baseline: 2.0672x; 1.5093x over previous
//
#include <hip/hip_runtime.h>
#include <hip/hip_bf16.h>

#define NN 100000   // nodes
#define NE 200000   // edges
#define NG 2500     // graphs
#define FN 16       // node feats
#define FE 8        // edge feats
#define H1C 32
#define H2C 16
#define KH 16       // edge-MLP hidden

typedef __attribute__((ext_vector_type(8))) short short8;
typedef __attribute__((ext_vector_type(4))) float f32x4;

__device__ __forceinline__ float bf2f(unsigned int u){
  union { unsigned int i; float f; } v; v.i = (u & 0xffffu) << 16; return v.f;
}
__device__ __forceinline__ unsigned short f2bf(float f){
  union { float f; unsigned int i; } u; u.f = f;
  unsigned int r = u.i + 0x7fffu + ((u.i >> 16) & 1u);   // RNE, finite data
  return (unsigned short)(r >> 16);
}
__device__ __forceinline__ unsigned int pk2(float a, float b){
  return (unsigned int)f2bf(a) | ((unsigned int)f2bf(b) << 16);
}
__device__ __forceinline__ float rdf(const void* p, long i, bool isbf){
  return isbf ? bf2f(((const unsigned short*)p)[i]) : ((const float*)p)[i];
}
__device__ __forceinline__ int lower_bound_i(const int* __restrict__ a, int n, int v){
  int lo = 0, hi = n;
  while(lo < hi){ int mid = (lo + hi) >> 1; if(a[mid] < v) lo = mid + 1; else hi = mid; }
  return lo;
}

// flag=1 if float inputs are bf16, 0 if fp32
__global__ void detect_kernel(const void* __restrict__ x, int* __restrict__ flag){
  int tid = threadIdx.x;
  const unsigned short* u = (const unsigned short*)x;
  float f = bf2f(u[2*tid]);
  float a = fabsf(f);
  int sane = (f == 0.0f) || (a > 1e-4f && a < 1e4f);
  __shared__ int cnt;
  if(tid == 0) cnt = 0;
  __syncthreads();
  if(sane) atomicAdd(&cnt, 1);
  __syncthreads();
  if(tid == 0) *flag = (cnt >= 128) ? 1 : 0;
}

#define NW 20
struct WArgs { const void* p[NW]; };
#define W_TOTAL 19330
enum {
  OW_E1A=0,     OB_E1A=128,   OW_E1B=144,   OB_E1B=8336,  OW_R1=8848,  OB_R1=9360,
  OW_E2A=9392,  OB_E2A=9520,  OW_E2B=9536,  OB_E2B=17728, OW_R2=18240, OB_R2=18752,
  OW_G1=18768,  OB_G1=19024,  OW_G2=19040,  OB_G2=19056,
  OW_L1=19057,  OB_L1=19313,  OW_L2=19321,  OB_L2=19329
};

// mega-setup: x-cvt | wts-cvt | pack W1^T | pack W2^T | deg=0 | edge-MLP-1 | gate MLP
// All regions independent; reads raw d_in with inline cvt (no cross-segment deps).
#define SE0 1600000L
#define SE1 (SE0 + 19330L)
#define SE2 (SE1 + 4736L)
#define SE3 (SE2 + 4416L)
#define SE4 (SE3 + 100000L)
#define SE5 (SE4 + 1600000L)
#define SE6 (SE5 + 100000L)
__global__ void __launch_bounds__(256) setup_kernel(
    const void* __restrict__ xin, const void* __restrict__ efin, WArgs w,
    const int* __restrict__ flag, float* __restrict__ xf, float* __restrict__ wts,
    unsigned int* __restrict__ wpack1, unsigned int* __restrict__ wpack2,
    int* __restrict__ deg, unsigned int* __restrict__ hpk1, float* __restrict__ gate)
{
  bool isbf = (*flag) != 0;
  long t = (long)blockIdx.x*256 + threadIdx.x;
  if(t < SE0){ xf[t] = rdf(xin, t, isbf); return; }
  if(t < SE1){
    const int sz[NW] = {128,16,8192,512,512,32, 128,16,8192,512,512,16, 256,16,16,1, 256,8,8,1};
    long i = t - SE0;
    int seg = 0; long base = 0;
    while(i - base >= sz[seg]){ base += sz[seg]; seg++; }
    wts[i] = rdf(w.p[seg], i - base, isbf);
    return;
  }
  if(t < SE2){   // pack1: 32 rows x 148 u32 (KP=296)
    long j = t - SE1;
    int n = (int)(j / 148); int k = (int)(j % 148) * 2;
    float v0 = 0.f, v1 = 0.f;
    if(k < 256)        v0 = rdf(w.p[2], (long)k*32 + n, isbf);
    else if(k < 272)   v0 = rdf(w.p[3], (long)(k-256)*32 + n, isbf);
    if(k+1 < 256)      v1 = rdf(w.p[2], (long)(k+1)*32 + n, isbf);
    else if(k+1 < 272) v1 = rdf(w.p[3], (long)(k+1-256)*32 + n, isbf);
    wpack1[j] = pk2(v0, v1);
    return;
  }
  if(t < SE3){   // pack2: 16 rows x 276 u32 (KP=552)
    long j = t - SE2;
    int n = (int)(j / 276); int k = (int)(j % 276) * 2;
    float v0 = 0.f, v1 = 0.f;
    if(k < 512)        v0 = rdf(w.p[8], (long)k*16 + n, isbf);
    else if(k < 544)   v0 = rdf(w.p[9], (long)(k-512)*16 + n, isbf);
    if(k+1 < 512)      v1 = rdf(w.p[8], (long)(k+1)*16 + n, isbf);
    else if(k+1 < 544) v1 = rdf(w.p[9], (long)(k+1-512)*16 + n, isbf);
    wpack2[j] = pk2(v0, v1);
    return;
  }
  if(t < SE4){ deg[t - SE3] = 0; return; }
  if(t < SE5){   // edge-MLP for conv1 -> hpk1
    long tt = t - SE4;
    long e = tt >> 3; int d = (int)(tt & 7);
    float h0 = rdf(w.p[1], 2*d, isbf), h1 = rdf(w.p[1], 2*d+1, isbf);
    #pragma unroll
    for(int j = 0; j < FE; j++){
      float ev = rdf(efin, e*FE + j, isbf);
      h0 += ev * rdf(w.p[0], j*KH + 2*d, isbf);
      h1 += ev * rdf(w.p[0], j*KH + 2*d+1, isbf);
    }
    h0 = h0 > 0.f ? h0 : 0.f;
    h1 = h1 > 0.f ? h1 : 0.f;
    hpk1[tt] = pk2(h0, h1);
    return;
  }
  if(t < SE6){   // gate MLP: gate[n] = relu(x@wg1+bg1)@wg2+bg2 (reads raw xin)
    long n = t - SE5;
    float xv[FN];
    #pragma unroll
    for(int i = 0; i < FN; i++) xv[i] = rdf(xin, n*FN + i, isbf);
    float g = rdf(w.p[15], 0, isbf);
    #pragma unroll
    for(int j = 0; j < FN; j++){
      float hj = rdf(w.p[13], j, isbf);
      #pragma unroll
      for(int i = 0; i < FN; i++) hj += xv[i] * rdf(w.p[12], i*FN + j, isbf);
      hj = hj > 0.f ? hj : 0.f;
      g += hj * rdf(w.p[14], j, isbf);
    }
    gate[n] = g;
  }
}

// standalone edge-MLP (conv2): hpk[e*8+d] = pack(relu(ea@wa+ba)[2d],[2d+1])
__global__ void __launch_bounds__(256) edge_h_kernel(
    const void* __restrict__ efin, const void* __restrict__ wa, const void* __restrict__ ba,
    const int* __restrict__ flag, unsigned int* __restrict__ hpk)
{
  bool isbf = (*flag) != 0;
  long t = (long)blockIdx.x*256 + threadIdx.x;   // exact grid NE*8
  long e = t >> 3; int d = (int)(t & 7);
  float h0 = rdf(ba, 2*d, isbf), h1 = rdf(ba, 2*d+1, isbf);
  #pragma unroll
  for(int j = 0; j < FE; j++){
    float ev = rdf(efin, e*FE + j, isbf);
    h0 += ev * rdf(wa, j*KH + 2*d, isbf);
    h1 += ev * rdf(wa, j*KH + 2*d+1, isbf);
  }
  h0 = h0 > 0.f ? h0 : 0.f;
  h1 = h1 > 0.f ? h1 : 0.f;
  hpk[t] = pk2(h0, h1);
}

// one wave per graph: segment softmax over precomputed gate + weighted x sum
__global__ void attn_pool_kernel(const float* __restrict__ gate, const float* __restrict__ xf,
                                 const int* __restrict__ batch, float* __restrict__ x_att)
{
  int g = blockIdx.x;
  int lane = threadIdx.x;
  int start = lower_bound_i(batch, NN, g);
  int end   = lower_bound_i(batch, NN, g + 1);
  float m = -1e30f;
  for(int n = start + lane; n < end; n += 64) m = fmaxf(m, gate[n]);
  #pragma unroll
  for(int o = 32; o >= 1; o >>= 1) m = fmaxf(m, __shfl_xor(m, o));
  float s = 0.f;
  float acc[FN];
  #pragma unroll
  for(int f = 0; f < FN; f++) acc[f] = 0.f;
  for(int n = start + lane; n < end; n += 64){
    float a = __expf(gate[n] - m);
    s += a;
    const float4* xp = (const float4*)(xf + (size_t)n * FN);
    #pragma unroll
    for(int q = 0; q < 4; q++){
      float4 v = xp[q];
      acc[q*4+0] += a*v.x; acc[q*4+1] += a*v.y; acc[q*4+2] += a*v.z; acc[q*4+3] += a*v.w;
    }
  }
  #pragma unroll
  for(int o = 32; o >= 1; o >>= 1){
    s += __shfl_xor(s, o);
    #pragma unroll
    for(int f = 0; f < FN; f++) acc[f] += __shfl_xor(acc[f], o);
  }
  if(lane < FN){
    float v = (end > start && s > 0.f) ? acc[lane] / s : 0.f;
    x_att[g*FN + lane] = v;
  }
}

// ---- CSR build ----
__global__ void histo_kernel(const int* __restrict__ ei, int* __restrict__ deg){
  int e = blockIdx.x*256 + threadIdx.x;
  if(e < NE) atomicAdd(&deg[ei[NE + e]], 1);
}
__global__ void scan1_kernel(const int* __restrict__ deg, int* __restrict__ bsum){
  __shared__ int s[256];
  int i = blockIdx.x*256 + threadIdx.x;
  s[threadIdx.x] = (i < NN) ? deg[i] : 0;
  __syncthreads();
  for(int off=128; off>0; off>>=1){
    if(threadIdx.x < off) s[threadIdx.x] += s[threadIdx.x+off];
    __syncthreads();
  }
  if(threadIdx.x==0) bsum[blockIdx.x] = s[0];
}
__global__ void scan2_kernel(int* __restrict__ bsum, int nb){
  __shared__ int s[512];
  int t = threadIdx.x;
  s[t] = (t < nb) ? bsum[t] : 0;
  __syncthreads();
  for(int off=1; off<512; off<<=1){
    int tv = (t>=off) ? s[t-off] : 0;
    __syncthreads();
    s[t] += tv;
    __syncthreads();
  }
  if(t < nb) bsum[t] = s[t];
}
__global__ void scan3_kernel(const int* __restrict__ deg, const int* __restrict__ bsum,
                             int* __restrict__ rowptr, int* __restrict__ cursor){
  __shared__ int s[256];
  int t = threadIdx.x;
  int i = blockIdx.x*256 + t;
  int v = (i < NN) ? deg[i] : 0;
  s[t] = v;
  __syncthreads();
  for(int off=1; off<256; off<<=1){
    int tv = (t>=off) ? s[t-off] : 0;
    __syncthreads();
    s[t] += tv;
    __syncthreads();
  }
  int bpre = (blockIdx.x==0) ? 0 : bsum[blockIdx.x-1];
  int excl = bpre + s[t] - v;
  if(i < NN){
    rowptr[i] = excl; cursor[i] = excl;
    if(i == NN-1) rowptr[NN] = excl + v;
  }
}
__global__ void fill_kernel(const int* __restrict__ ei, int* __restrict__ cursor, int* __restrict__ csr){
  int e = blockIdx.x*256 + threadIdx.x;
  if(e < NE){ int pos = atomicAdd(&cursor[ei[NE+e]], 1); csr[pos] = e; }
}

// ---- NNConv message GEMM via MFMA ----
// P[e,:] = [h (x) x_src | x_src | 0] bf16 in LDS; B-fragments direct from global wpack.
// NTHR = 2*EPB threads (2 threads build each P row, STATIC indexing only);
// each wave computes 32 edges = 2 M-tiles, reusing register B-frags.
template<int IN, int OUT, int EPB, int NTHR>
__global__ void __launch_bounds__(NTHR) conv_mfma_kernel(
    const float* __restrict__ nodef, const unsigned int* __restrict__ hpk,
    const int* __restrict__ ei, const unsigned short* __restrict__ wpack,
    unsigned short* __restrict__ msg)
{
  constexpr int KIN  = KH*IN;                 // 256 | 512
  constexpr int KTOT = KIN + IN;              // 272 | 544
  constexpr int KMF  = ((KTOT + 31)/32)*32;   // 288 | 544
  constexpr int KP   = KMF + 8;               // 296 | 552
  constexpr int NT   = OUT/16;                // 2 | 1
  constexpr int KS   = KMF/32;                // 9 | 17
  __shared__ __align__(16) unsigned short sP[EPB*KP];
  int tid = threadIdx.x;
  int lane = tid & 63, nrow = lane & 15, quad = lane >> 4;

  // per-edge inputs (2 threads per edge)
  int e_loc = tid >> 1, q = tid & 1;
  int e = blockIdx.x*EPB + e_loc;   // exact grids
  int sn = ei[e];
  float xv[IN];
  {
    const float4* xp = (const float4*)(nodef + (size_t)sn*IN);
    #pragma unroll
    for(int k = 0; k < IN/4; k++){ float4 v = xp[k]; xv[k*4+0]=v.x; xv[k*4+1]=v.y; xv[k*4+2]=v.z; xv[k*4+3]=v.w; }
  }
  float hh[8];
  {
    const unsigned int* hp = hpk + (size_t)e*8 + q*4;
    #pragma unroll
    for(int d = 0; d < 4; d++){
      unsigned int u = hp[d];
      hh[2*d] = bf2f(u); hh[2*d+1] = bf2f(u >> 16);
    }
  }
  // B-fragments straight from L2-hot packed W^T (independent of LDS/barrier)
  short8 bfr[KS][NT];
  {
    const short8* wp8 = (const short8*)wpack;
    #pragma unroll
    for(int ks = 0; ks < KS; ks++)
      #pragma unroll
      for(int nt = 0; nt < NT; nt++)
        bfr[ks][nt] = wp8[((nt*16 + nrow)*KP + ks*32 + quad*8) >> 3];
  }
  // P-row build: thread q writes h-chunks q*8..q*8+7 (all indices static)
  {
    unsigned int* sPu = (unsigned int*)sP;
    const int rb = e_loc*(KP/2);
    #pragma unroll
    for(int j = 0; j < 8; j++){
      float h = hh[j];
      int cb = rb + (q*8 + j)*(IN/2);
      #pragma unroll
      for(int i2 = 0; i2 < IN/2; i2++) sPu[cb + i2] = pk2(h*xv[2*i2], h*xv[2*i2+1]);
    }
    if(IN == 16){
      if(q == 0){
        int cb = rb + 128;   // x part, k 256..271
        #pragma unroll
        for(int i2 = 0; i2 < 8; i2++) sPu[cb + i2] = pk2(xv[2*i2], xv[2*i2+1]);
      } else {
        int cb = rb + 136;   // zero pad, k 272..287
        #pragma unroll
        for(int i2 = 0; i2 < 8; i2++) sPu[cb + i2] = 0u;
      }
    } else {                 // IN==32: x part k 512..543, split between q
      int cb = rb + 256 + q*8;
      #pragma unroll
      for(int i2 = 0; i2 < 8; i2++) sPu[cb + i2] = pk2(xv[16*q + 2*i2], xv[16*q + 2*i2 + 1]);
    }
  }
  __syncthreads();

  // MFMA: wave handles 32 edges = 2 tiles
  int mwb = (tid >> 6) * 32;
  f32x4 acc[2][NT];
  #pragma unroll
  for(int t2 = 0; t2 < 2; t2++)
    #pragma unroll
    for(int nt = 0; nt < NT; nt++) acc[t2][nt] = (f32x4){0.f,0.f,0.f,0.f};
  #pragma unroll
  for(int ks = 0; ks < KS; ks++){
    short8 a0 = *(const short8*)&sP[(mwb + nrow)*KP + ks*32 + quad*8];
    short8 a1 = *(const short8*)&sP[(mwb + 16 + nrow)*KP + ks*32 + quad*8];
    #pragma unroll
    for(int nt = 0; nt < NT; nt++){
      acc[0][nt] = __builtin_amdgcn_mfma_f32_16x16x32_bf16(a0, bfr[ks][nt], acc[0][nt], 0, 0, 0);
      acc[1][nt] = __builtin_amdgcn_mfma_f32_16x16x32_bf16(a1, bfr[ks][nt], acc[1][nt], 0, 0, 0);
    }
  }
  int ebase = blockIdx.x*EPB + mwb;
  #pragma unroll
  for(int t2 = 0; t2 < 2; t2++)
    #pragma unroll
    for(int nt = 0; nt < NT; nt++)
      #pragma unroll
      for(int r = 0; r < 4; r++){
        int m = t2*16 + quad*4 + r;   // C layout: row=(lane>>4)*4+reg, col=lane&15
        msg[(size_t)(ebase + m)*OUT + nt*16 + nrow] = f2bf(acc[t2][nt][r]);
      }
}

// h1 = relu(x@wr1 + br1 + gather(msg1)); 8 threads/node
__global__ void __launch_bounds__(256) gather1_kernel(
    const float* __restrict__ xf, const unsigned short* __restrict__ msg,
    const int* __restrict__ rowptr, const int* __restrict__ csr,
    const float* __restrict__ wr, const float* __restrict__ br, float* __restrict__ h1)
{
  __shared__ float s_w[FN*H1C], s_b[H1C];
  for(int i = threadIdx.x; i < FN*H1C; i += 256) s_w[i] = wr[i];
  if(threadIdx.x < H1C) s_b[threadIdx.x] = br[threadIdx.x];
  __syncthreads();
  int g = blockIdx.x*256 + threadIdx.x;
  int n = g >> 3, q = g & 7;
  if(n >= NN) return;
  float a0 = s_b[q*4+0], a1 = s_b[q*4+1], a2 = s_b[q*4+2], a3 = s_b[q*4+3];
  int jb = rowptr[n], je = rowptr[n+1];
  for(int j = jb; j < je; j++){
    int eid = csr[j];
    const unsigned int* mp = (const unsigned int*)(msg + (size_t)eid*H1C + q*4);
    unsigned int u0 = mp[0], u1 = mp[1];
    a0 += bf2f(u0); a1 += bf2f(u0 >> 16); a2 += bf2f(u1); a3 += bf2f(u1 >> 16);
  }
  const float* xr = xf + (size_t)n*FN;
  #pragma unroll
  for(int i = 0; i < FN; i++){
    float xi = xr[i];
    a0 += xi*s_w[i*H1C + q*4+0]; a1 += xi*s_w[i*H1C + q*4+1];
    a2 += xi*s_w[i*H1C + q*4+2]; a3 += xi*s_w[i*H1C + q*4+3];
  }
  float4 r; r.x = a0>0.f?a0:0.f; r.y = a1>0.f?a1:0.f; r.z = a2>0.f?a2:0.f; r.w = a3>0.f?a3:0.f;
  *(float4*)(h1 + (size_t)n*H1C + q*4) = r;
}

// h2 = relu(h1@wr2 + br2 + gather(msg2)); 4 threads/node
__global__ void __launch_bounds__(256) gather2_kernel(
    const float* __restrict__ h1, const unsigned short* __restrict__ msg,
    const int* __restrict__ rowptr, const int* __restrict__ csr,
    const float* __restrict__ wr, const float* __restrict__ br, float* __restrict__ h2)
{
  __shared__ float s_w[H1C*H2C], s_b[H2C];
  for(int i = threadIdx.x; i < H1C*H2C; i += 256) s_w[i] = wr[i];
  if(threadIdx.x < H2C) s_b[threadIdx.x] = br[threadIdx.x];
  __syncthreads();
  int g = blockIdx.x*256 + threadIdx.x;
  int n = g >> 2, q = g & 3;
  if(n >= NN) return;
  float a0 = s_b[q*4+0], a1 = s_b[q*4+1], a2 = s_b[q*4+2], a3 = s_b[q*4+3];
  int jb = rowptr[n], je = rowptr[n+1];
  for(int j = jb; j < je; j++){
    int eid = csr[j];
    const unsigned int* mp = (const unsigned int*)(msg + (size_t)eid*H2C + q*4);
    unsigned int u0 = mp[0], u1 = mp[1];
    a0 += bf2f(u0); a1 += bf2f(u0 >> 16); a2 += bf2f(u1); a3 += bf2f(u1 >> 16);
  }
  const float* hr = h1 + (size_t)n*H1C;
  #pragma unroll
  for(int i = 0; i < H1C; i++){
    float xi = hr[i];
    a0 += xi*s_w[i*H2C + q*4+0]; a1 += xi*s_w[i*H2C + q*4+1];
    a2 += xi*s_w[i*H2C + q*4+2]; a3 += xi*s_w[i*H2C + q*4+3];
  }
  float4 r; r.x = a0>0.f?a0:0.f; r.y = a1>0.f?a1:0.f; r.z = a2>0.f?a2:0.f; r.w = a3>0.f?a3:0.f;
  *(float4*)(h2 + (size_t)n*H2C + q*4) = r;
}

// one wave per graph: mean-pool h2 + concat x_att + 2-layer head
__global__ void head_kernel(const float* __restrict__ h2, const float* __restrict__ x_att,
    const int* __restrict__ batch,
    const float* __restrict__ wl1, const float* __restrict__ bl1,
    const float* __restrict__ wl2, const float* __restrict__ bl2,
    void* __restrict__ out, const int* __restrict__ flag)
{
  int g = blockIdx.x;
  int lane = threadIdx.x;
  int start = lower_bound_i(batch, NN, g);
  int end   = lower_bound_i(batch, NN, g + 1);
  float acc[H2C];
  #pragma unroll
  for(int f = 0; f < H2C; f++) acc[f] = 0.f;
  for(int n = start + lane; n < end; n += 64){
    const float4* hp = (const float4*)(h2 + (size_t)n*H2C);
    #pragma unroll
    for(int q = 0; q < 4; q++){
      float4 v = hp[q];
      acc[q*4+0] += v.x; acc[q*4+1] += v.y; acc[q*4+2] += v.z; acc[q*4+3] += v.w;
    }
  }
  #pragma unroll
  for(int o = 32; o >= 1; o >>= 1){
    #pragma unroll
    for(int f = 0; f < H2C; f++) acc[f] += __shfl_xor(acc[f], o);
  }
  if(lane == 0){
    float inv = 1.f / fmaxf((float)(end - start), 1.f);
    float z[H2C + FN];
    #pragma unroll
    for(int f = 0; f < H2C; f++) z[f] = acc[f] * inv;
    #pragma unroll
    for(int f = 0; f < FN; f++) z[H2C + f] = x_att[(size_t)g*FN + f];
    float t1[8];
    #pragma unroll
    for(int j = 0; j < 8; j++){
      float t = bl1[j];
      #pragma unroll
      for(int c = 0; c < H2C + FN; c++) t += z[c] * wl1[c*8 + j];
      t1[j] = t;
    }
    float o = bl2[0];
    #pragma unroll
    for(int j = 0; j < 8; j++) o += t1[j] * wl2[j];
    if((*flag) != 0) ((__hip_bfloat16*)out)[g] = __float2bfloat16(o);
    else             ((float*)out)[g] = o;
  }
}

extern "C" void kernel_launch(void* const* d_in, const int* in_sizes, int n_in,
                              void* d_out, int out_size, void* d_ws, size_t ws_size,
                              hipStream_t stream)
{
  const int* ei    = (const int*)d_in[22];
  const int* batch = (const int*)d_in[23];

  float* ws = (float*)d_ws;
  float* xf     = ws;                          // 1,600,000 f
  float* x_att  = xf + 1600000;                //    40,000 f
  float* gate   = x_att + 40000;               //   100,000 f
  float* wts    = gate + 100000;               //    19,360 f
  int*   rowptr = (int*)(wts + 19360);         //   100,016 i
  int*   cursor = rowptr + 100016;             //   100,000 i
  int*   deg    = cursor + 100000;             //   100,000 i
  int*   bsum   = deg + 100000;                //       512 i
  int*   csr    = bsum + 512;                  //   200,000 i
  int*   flagp  = csr + 200000;                //        16 i
  unsigned int* wpack1 = (unsigned int*)(flagp + 16);   // 4,736 u32
  unsigned int* wpack2 = wpack1 + 4736;                 // 4,416 u32
  float* h1     = (float*)(wpack2 + 4416);     // 3,200,000 f
  unsigned int* hpk1 = (unsigned int*)h1;      // alias: dead once conv1 done
  unsigned short* msg1 = (unsigned short*)(h1 + 3200000);  // 6,400,000 u16
  unsigned short* msg2 = msg1;                 // reuse after gather1
  float* h2     = (float*)(msg1 + 6400000);    // 1,600,000 f
  unsigned int* hpk2 = (unsigned int*)h2;      // alias: dead once conv2 done
  // total ~41 MB

  WArgs wa;
  for(int i = 0; i < NW; i++) wa.p[i] = d_in[2 + i];

  detect_kernel<<<1, 256, 0, stream>>>(d_in[0], flagp);
  setup_kernel<<<(int)((SE6 + 255)/256), 256, 0, stream>>>(
      d_in[0], d_in[1], wa, flagp, xf, wts, wpack1, wpack2, deg, hpk1, gate);

  const int NB1 = (NN + 255)/256;  // 391
  histo_kernel<<<(NE + 255)/256, 256, 0, stream>>>(ei, deg);
  scan1_kernel<<<NB1, 256, 0, stream>>>(deg, bsum);
  scan2_kernel<<<1, 512, 0, stream>>>(bsum, NB1);
  scan3_kernel<<<NB1, 256, 0, stream>>>(deg, bsum, rowptr, cursor);
  fill_kernel<<<(NE + 255)/256, 256, 0, stream>>>(ei, cursor, csr);

  attn_pool_kernel<<<NG, 64, 0, stream>>>(gate, xf, batch, x_att);

  conv_mfma_kernel<FN, H1C, 64, 128><<<NE/64, 128, 0, stream>>>(
      xf, hpk1, ei, (const unsigned short*)wpack1, msg1);
  gather1_kernel<<<(NN*8 + 255)/256, 256, 0, stream>>>(xf, msg1, rowptr, csr, wts+OW_R1, wts+OB_R1, h1);

  edge_h_kernel<<<NE*8/256, 256, 0, stream>>>(d_in[1], d_in[8], d_in[9], flagp, hpk2);
  conv_mfma_kernel<H1C, H2C, 32, 64><<<NE/32, 64, 0, stream>>>(
      h1, hpk2, ei, (const unsigned short*)wpack2, msg2);
  gather2_kernel<<<(NN*4 + 255)/256, 256, 0, stream>>>(h1, msg2, rowptr, csr, wts+OW_R2, wts+OB_R2, h2);

  head_kernel<<<NG, 64, 0, stream>>>(h2, x_att, batch,
      wts+OW_L1, wts+OB_L1, wts+OW_L2, wts+OB_L2, d_out, flagp);
}

// Round 7
// 273.087 us; speedup vs baseline: 2.6076x; 1.2614x over previous
//
#include <hip/hip_runtime.h>
#include <hip/hip_bf16.h>

#define NN 100000   // nodes
#define NE 200000   // edges
#define NG 2500     // graphs
#define FN 16       // node feats
#define FE 8        // edge feats
#define H1C 32
#define H2C 16
#define KH 16       // edge-MLP hidden

typedef __attribute__((ext_vector_type(8))) short short8;
typedef __attribute__((ext_vector_type(4))) float f32x4;

__device__ __forceinline__ float bf2f(unsigned int u){
  union { unsigned int i; float f; } v; v.i = (u & 0xffffu) << 16; return v.f;
}
__device__ __forceinline__ unsigned short f2bf(float f){
  union { float f; unsigned int i; } u; u.f = f;
  unsigned int r = u.i + 0x7fffu + ((u.i >> 16) & 1u);   // RNE, finite data
  return (unsigned short)(r >> 16);
}
__device__ __forceinline__ unsigned int pk2(float a, float b){
  return (unsigned int)f2bf(a) | ((unsigned int)f2bf(b) << 16);
}
__device__ __forceinline__ float rdf(const void* p, long i, bool isbf){
  return isbf ? bf2f(((const unsigned short*)p)[i]) : ((const float*)p)[i];
}
__device__ __forceinline__ int lower_bound_i(const int* __restrict__ a, int n, int v){
  int lo = 0, hi = n;
  while(lo < hi){ int mid = (lo + hi) >> 1; if(a[mid] < v) lo = mid + 1; else hi = mid; }
  return lo;
}

// flag=1 if float inputs are bf16, 0 if fp32
__global__ void detect_kernel(const void* __restrict__ x, int* __restrict__ flag){
  int tid = threadIdx.x;
  const unsigned short* u = (const unsigned short*)x;
  float f = bf2f(u[2*tid]);
  float a = fabsf(f);
  int sane = (f == 0.0f) || (a > 1e-4f && a < 1e4f);
  __shared__ int cnt;
  if(tid == 0) cnt = 0;
  __syncthreads();
  if(sane) atomicAdd(&cnt, 1);
  __syncthreads();
  if(tid == 0) *flag = (cnt >= 128) ? 1 : 0;
}

#define NW 20
struct WArgs { const void* p[NW]; };
#define W_TOTAL 19330
enum {
  OW_E1A=0,     OB_E1A=128,   OW_E1B=144,   OB_E1B=8336,  OW_R1=8848,  OB_R1=9360,
  OW_E2A=9392,  OB_E2A=9520,  OW_E2B=9536,  OB_E2B=17728, OW_R2=18240, OB_R2=18752,
  OW_G1=18768,  OB_G1=19024,  OW_G2=19040,  OB_G2=19056,
  OW_L1=19057,  OB_L1=19313,  OW_L2=19321,  OB_L2=19329
};

// vectorized x conversion: 8 elems/thread
__global__ void __launch_bounds__(256) cvt_x_kernel(
    const void* __restrict__ xin, float* __restrict__ xf, const int* __restrict__ flag)
{
  bool isbf = (*flag) != 0;
  int t = blockIdx.x*256 + threadIdx.x;
  if((long)t*8 >= 1600000L) return;
  float4 a, b;
  if(isbf){
    uint4 u = ((const uint4*)xin)[t];
    a.x = bf2f(u.x); a.y = bf2f(u.x >> 16); a.z = bf2f(u.y); a.w = bf2f(u.y >> 16);
    b.x = bf2f(u.z); b.y = bf2f(u.z >> 16); b.z = bf2f(u.w); b.w = bf2f(u.w >> 16);
  } else {
    a = ((const float4*)xin)[2*t]; b = ((const float4*)xin)[2*t+1];
  }
  ((float4*)xf)[2*t] = a; ((float4*)xf)[2*t+1] = b;
}

// small setup: wts-cvt | pack W1^T | pack W2^T | deg=0
#define SS0 19330L
#define SS1 (SS0 + 4736L)
#define SS2 (SS1 + 4416L)
#define SS3 (SS2 + 100000L)
__global__ void __launch_bounds__(256) setup_small_kernel(
    WArgs w, const int* __restrict__ flag, float* __restrict__ wts,
    unsigned int* __restrict__ wpack1, unsigned int* __restrict__ wpack2,
    int* __restrict__ deg)
{
  bool isbf = (*flag) != 0;
  long t = (long)blockIdx.x*256 + threadIdx.x;
  if(t < SS0){
    const int sz[NW] = {128,16,8192,512,512,32, 128,16,8192,512,512,16, 256,16,16,1, 256,8,8,1};
    long i = t;
    int seg = 0; long base = 0;
    while(i - base >= sz[seg]){ base += sz[seg]; seg++; }
    wts[i] = rdf(w.p[seg], i - base, isbf);
    return;
  }
  if(t < SS1){   // pack1: 32 rows x 148 u32 (KP=296)
    long j = t - SS0;
    int n = (int)(j / 148); int k = (int)(j % 148) * 2;
    float v0 = 0.f, v1 = 0.f;
    if(k < 256)        v0 = rdf(w.p[2], (long)k*32 + n, isbf);
    else if(k < 272)   v0 = rdf(w.p[3], (long)(k-256)*32 + n, isbf);
    if(k+1 < 256)      v1 = rdf(w.p[2], (long)(k+1)*32 + n, isbf);
    else if(k+1 < 272) v1 = rdf(w.p[3], (long)(k+1-256)*32 + n, isbf);
    wpack1[j] = pk2(v0, v1);
    return;
  }
  if(t < SS2){   // pack2: 16 rows x 276 u32 (KP=552)
    long j = t - SS1;
    int n = (int)(j / 276); int k = (int)(j % 276) * 2;
    float v0 = 0.f, v1 = 0.f;
    if(k < 512)        v0 = rdf(w.p[8], (long)k*16 + n, isbf);
    else if(k < 544)   v0 = rdf(w.p[9], (long)(k-512)*16 + n, isbf);
    if(k+1 < 512)      v1 = rdf(w.p[8], (long)(k+1)*16 + n, isbf);
    else if(k+1 < 544) v1 = rdf(w.p[9], (long)(k+1-512)*16 + n, isbf);
    wpack2[j] = pk2(v0, v1);
    return;
  }
  if(t < SS3) deg[t - SS2] = 0;
}

// edge-MLP: weights staged to LDS, edge row read as one vector. 8 threads/edge.
__global__ void __launch_bounds__(256) edge_h_kernel(
    const void* __restrict__ efin, const void* __restrict__ wa, const void* __restrict__ ba,
    const int* __restrict__ flag, unsigned int* __restrict__ hpk)
{
  __shared__ float s_wa[FE*KH], s_ba[KH];
  bool isbf = (*flag) != 0;
  if(threadIdx.x < FE*KH) s_wa[threadIdx.x] = rdf(wa, threadIdx.x, isbf);
  if(threadIdx.x < KH)    s_ba[threadIdx.x] = rdf(ba, threadIdx.x, isbf);
  __syncthreads();
  long t = (long)blockIdx.x*256 + threadIdx.x;
  if(t >= (long)NE*8) return;
  long e = t >> 3; int d = (int)(t & 7);
  float ev[FE];
  if(isbf){
    uint4 u = ((const uint4*)efin)[e];   // 8 bf16 = 16B
    ev[0]=bf2f(u.x); ev[1]=bf2f(u.x>>16); ev[2]=bf2f(u.y); ev[3]=bf2f(u.y>>16);
    ev[4]=bf2f(u.z); ev[5]=bf2f(u.z>>16); ev[6]=bf2f(u.w); ev[7]=bf2f(u.w>>16);
  } else {
    float4 a = ((const float4*)efin)[2*e], b = ((const float4*)efin)[2*e+1];
    ev[0]=a.x; ev[1]=a.y; ev[2]=a.z; ev[3]=a.w; ev[4]=b.x; ev[5]=b.y; ev[6]=b.z; ev[7]=b.w;
  }
  float h0 = s_ba[2*d], h1 = s_ba[2*d+1];
  #pragma unroll
  for(int j = 0; j < FE; j++){
    h0 += ev[j] * s_wa[j*KH + 2*d];
    h1 += ev[j] * s_wa[j*KH + 2*d+1];
  }
  h0 = h0 > 0.f ? h0 : 0.f;
  h1 = h1 > 0.f ? h1 : 0.f;
  hpk[t] = pk2(h0, h1);
}

// gate MLP: weights in LDS, x row as 2x uint4 from raw input
__global__ void __launch_bounds__(256) gate_kernel(
    const void* __restrict__ xin, const void* __restrict__ wg1, const void* __restrict__ bg1,
    const void* __restrict__ wg2, const void* __restrict__ bg2,
    const int* __restrict__ flag, float* __restrict__ gate)
{
  __shared__ float s_w1[FN*FN], s_b1[FN], s_w2[FN], s_b2v[1];
  bool isbf = (*flag) != 0;
  if(threadIdx.x < FN*FN) s_w1[threadIdx.x] = rdf(wg1, threadIdx.x, isbf);
  if(threadIdx.x < FN){ s_b1[threadIdx.x] = rdf(bg1, threadIdx.x, isbf); s_w2[threadIdx.x] = rdf(wg2, threadIdx.x, isbf); }
  if(threadIdx.x == 0) s_b2v[0] = rdf(bg2, 0, isbf);
  __syncthreads();
  int n = blockIdx.x*256 + threadIdx.x;
  if(n >= NN) return;
  float xv[FN];
  if(isbf){
    uint4 u0 = ((const uint4*)xin)[2*n], u1 = ((const uint4*)xin)[2*n+1];
    xv[0]=bf2f(u0.x); xv[1]=bf2f(u0.x>>16); xv[2]=bf2f(u0.y); xv[3]=bf2f(u0.y>>16);
    xv[4]=bf2f(u0.z); xv[5]=bf2f(u0.z>>16); xv[6]=bf2f(u0.w); xv[7]=bf2f(u0.w>>16);
    xv[8]=bf2f(u1.x); xv[9]=bf2f(u1.x>>16); xv[10]=bf2f(u1.y); xv[11]=bf2f(u1.y>>16);
    xv[12]=bf2f(u1.z); xv[13]=bf2f(u1.z>>16); xv[14]=bf2f(u1.w); xv[15]=bf2f(u1.w>>16);
  } else {
    #pragma unroll
    for(int q = 0; q < 4; q++){
      float4 v = ((const float4*)xin)[4*n + q];
      xv[q*4+0]=v.x; xv[q*4+1]=v.y; xv[q*4+2]=v.z; xv[q*4+3]=v.w;
    }
  }
  float g = s_b2v[0];
  #pragma unroll
  for(int j = 0; j < FN; j++){
    float hj = s_b1[j];
    #pragma unroll
    for(int i = 0; i < FN; i++) hj += xv[i] * s_w1[i*FN + j];
    hj = hj > 0.f ? hj : 0.f;
    g += hj * s_w2[j];
  }
  gate[n] = g;
}

// one wave per graph: segment softmax over precomputed gate + weighted x sum
__global__ void attn_pool_kernel(const float* __restrict__ gate, const float* __restrict__ xf,
                                 const int* __restrict__ batch, float* __restrict__ x_att)
{
  int g = blockIdx.x;
  int lane = threadIdx.x;
  int start = lower_bound_i(batch, NN, g);
  int end   = lower_bound_i(batch, NN, g + 1);
  float m = -1e30f;
  for(int n = start + lane; n < end; n += 64) m = fmaxf(m, gate[n]);
  #pragma unroll
  for(int o = 32; o >= 1; o >>= 1) m = fmaxf(m, __shfl_xor(m, o));
  float s = 0.f;
  float acc[FN];
  #pragma unroll
  for(int f = 0; f < FN; f++) acc[f] = 0.f;
  for(int n = start + lane; n < end; n += 64){
    float a = __expf(gate[n] - m);
    s += a;
    const float4* xp = (const float4*)(xf + (size_t)n * FN);
    #pragma unroll
    for(int q = 0; q < 4; q++){
      float4 v = xp[q];
      acc[q*4+0] += a*v.x; acc[q*4+1] += a*v.y; acc[q*4+2] += a*v.z; acc[q*4+3] += a*v.w;
    }
  }
  #pragma unroll
  for(int o = 32; o >= 1; o >>= 1){
    s += __shfl_xor(s, o);
    #pragma unroll
    for(int f = 0; f < FN; f++) acc[f] += __shfl_xor(acc[f], o);
  }
  if(lane < FN){
    float v = (end > start && s > 0.f) ? acc[lane] / s : 0.f;
    x_att[g*FN + lane] = v;
  }
}

// ---- CSR build ----
__global__ void histo_kernel(const int* __restrict__ ei, int* __restrict__ deg){
  int e = blockIdx.x*256 + threadIdx.x;
  if(e < NE) atomicAdd(&deg[ei[NE + e]], 1);
}
__global__ void scan1_kernel(const int* __restrict__ deg, int* __restrict__ bsum){
  __shared__ int s[256];
  int i = blockIdx.x*256 + threadIdx.x;
  s[threadIdx.x] = (i < NN) ? deg[i] : 0;
  __syncthreads();
  for(int off=128; off>0; off>>=1){
    if(threadIdx.x < off) s[threadIdx.x] += s[threadIdx.x+off];
    __syncthreads();
  }
  if(threadIdx.x==0) bsum[blockIdx.x] = s[0];
}
__global__ void scan2_kernel(int* __restrict__ bsum, int nb){
  __shared__ int s[512];
  int t = threadIdx.x;
  s[t] = (t < nb) ? bsum[t] : 0;
  __syncthreads();
  for(int off=1; off<512; off<<=1){
    int tv = (t>=off) ? s[t-off] : 0;
    __syncthreads();
    s[t] += tv;
    __syncthreads();
  }
  if(t < nb) bsum[t] = s[t];
}
__global__ void scan3_kernel(const int* __restrict__ deg, const int* __restrict__ bsum,
                             int* __restrict__ rowptr, int* __restrict__ cursor){
  __shared__ int s[256];
  int t = threadIdx.x;
  int i = blockIdx.x*256 + t;
  int v = (i < NN) ? deg[i] : 0;
  s[t] = v;
  __syncthreads();
  for(int off=1; off<256; off<<=1){
    int tv = (t>=off) ? s[t-off] : 0;
    __syncthreads();
    s[t] += tv;
    __syncthreads();
  }
  int bpre = (blockIdx.x==0) ? 0 : bsum[blockIdx.x-1];
  int excl = bpre + s[t] - v;
  if(i < NN){
    rowptr[i] = excl; cursor[i] = excl;
    if(i == NN-1) rowptr[NN] = excl + v;
  }
}
__global__ void fill_kernel(const int* __restrict__ ei, int* __restrict__ cursor, int* __restrict__ csr){
  int e = blockIdx.x*256 + threadIdx.x;
  if(e < NE){ int pos = atomicAdd(&cursor[ei[NE+e]], 1); csr[pos] = e; }
}

// ---- NNConv message GEMM via MFMA ----
// P[e,:] = [h (x) x_src | x_src | 0] bf16 in LDS; B-fragments direct from global wpack.
template<int IN, int OUT, int EPB, int NTHR>
__global__ void __launch_bounds__(NTHR) conv_mfma_kernel(
    const float* __restrict__ nodef, const unsigned int* __restrict__ hpk,
    const int* __restrict__ ei, const unsigned short* __restrict__ wpack,
    unsigned short* __restrict__ msg)
{
  constexpr int KIN  = KH*IN;                 // 256 | 512
  constexpr int KTOT = KIN + IN;              // 272 | 544
  constexpr int KMF  = ((KTOT + 31)/32)*32;   // 288 | 544
  constexpr int KP   = KMF + 8;               // 296 | 552
  constexpr int NT   = OUT/16;                // 2 | 1
  constexpr int KS   = KMF/32;                // 9 | 17
  __shared__ __align__(16) unsigned short sP[EPB*KP];
  int tid = threadIdx.x;
  int lane = tid & 63, nrow = lane & 15, quad = lane >> 4;

  int e_loc = tid >> 1, q = tid & 1;
  int e = blockIdx.x*EPB + e_loc;   // exact grids
  int sn = ei[e];
  float xv[IN];
  {
    const float4* xp = (const float4*)(nodef + (size_t)sn*IN);
    #pragma unroll
    for(int k = 0; k < IN/4; k++){ float4 v = xp[k]; xv[k*4+0]=v.x; xv[k*4+1]=v.y; xv[k*4+2]=v.z; xv[k*4+3]=v.w; }
  }
  float hh[8];
  {
    const unsigned int* hp = hpk + (size_t)e*8 + q*4;
    #pragma unroll
    for(int d = 0; d < 4; d++){
      unsigned int u = hp[d];
      hh[2*d] = bf2f(u); hh[2*d+1] = bf2f(u >> 16);
    }
  }
  short8 bfr[KS][NT];
  {
    const short8* wp8 = (const short8*)wpack;
    #pragma unroll
    for(int ks = 0; ks < KS; ks++)
      #pragma unroll
      for(int nt = 0; nt < NT; nt++)
        bfr[ks][nt] = wp8[((nt*16 + nrow)*KP + ks*32 + quad*8) >> 3];
  }
  {
    unsigned int* sPu = (unsigned int*)sP;
    const int rb = e_loc*(KP/2);
    #pragma unroll
    for(int j = 0; j < 8; j++){
      float h = hh[j];
      int cb = rb + (q*8 + j)*(IN/2);
      #pragma unroll
      for(int i2 = 0; i2 < IN/2; i2++) sPu[cb + i2] = pk2(h*xv[2*i2], h*xv[2*i2+1]);
    }
    if(IN == 16){
      if(q == 0){
        int cb = rb + 128;
        #pragma unroll
        for(int i2 = 0; i2 < 8; i2++) sPu[cb + i2] = pk2(xv[2*i2], xv[2*i2+1]);
      } else {
        int cb = rb + 136;
        #pragma unroll
        for(int i2 = 0; i2 < 8; i2++) sPu[cb + i2] = 0u;
      }
    } else {
      int cb = rb + 256 + q*8;
      #pragma unroll
      for(int i2 = 0; i2 < 8; i2++) sPu[cb + i2] = pk2(xv[16*q + 2*i2], xv[16*q + 2*i2 + 1]);
    }
  }
  __syncthreads();

  int mwb = (tid >> 6) * 32;
  f32x4 acc[2][NT];
  #pragma unroll
  for(int t2 = 0; t2 < 2; t2++)
    #pragma unroll
    for(int nt = 0; nt < NT; nt++) acc[t2][nt] = (f32x4){0.f,0.f,0.f,0.f};
  #pragma unroll
  for(int ks = 0; ks < KS; ks++){
    short8 a0 = *(const short8*)&sP[(mwb + nrow)*KP + ks*32 + quad*8];
    short8 a1 = *(const short8*)&sP[(mwb + 16 + nrow)*KP + ks*32 + quad*8];
    #pragma unroll
    for(int nt = 0; nt < NT; nt++){
      acc[0][nt] = __builtin_amdgcn_mfma_f32_16x16x32_bf16(a0, bfr[ks][nt], acc[0][nt], 0, 0, 0);
      acc[1][nt] = __builtin_amdgcn_mfma_f32_16x16x32_bf16(a1, bfr[ks][nt], acc[1][nt], 0, 0, 0);
    }
  }
  int ebase = blockIdx.x*EPB + mwb;
  #pragma unroll
  for(int t2 = 0; t2 < 2; t2++)
    #pragma unroll
    for(int nt = 0; nt < NT; nt++)
      #pragma unroll
      for(int r = 0; r < 4; r++){
        int m = t2*16 + quad*4 + r;   // C layout: row=(lane>>4)*4+reg, col=lane&15
        msg[(size_t)(ebase + m)*OUT + nt*16 + nrow] = f2bf(acc[t2][nt][r]);
      }
}

// h1 = relu(x@wr1 + br1 + gather(msg1)); 8 threads/node
__global__ void __launch_bounds__(256) gather1_kernel(
    const float* __restrict__ xf, const unsigned short* __restrict__ msg,
    const int* __restrict__ rowptr, const int* __restrict__ csr,
    const float* __restrict__ wr, const float* __restrict__ br, float* __restrict__ h1)
{
  __shared__ float s_w[FN*H1C], s_b[H1C];
  for(int i = threadIdx.x; i < FN*H1C; i += 256) s_w[i] = wr[i];
  if(threadIdx.x < H1C) s_b[threadIdx.x] = br[threadIdx.x];
  __syncthreads();
  int g = blockIdx.x*256 + threadIdx.x;
  int n = g >> 3, q = g & 7;
  if(n >= NN) return;
  float a0 = s_b[q*4+0], a1 = s_b[q*4+1], a2 = s_b[q*4+2], a3 = s_b[q*4+3];
  int jb = rowptr[n], je = rowptr[n+1];
  for(int j = jb; j < je; j++){
    int eid = csr[j];
    const unsigned int* mp = (const unsigned int*)(msg + (size_t)eid*H1C + q*4);
    unsigned int u0 = mp[0], u1 = mp[1];
    a0 += bf2f(u0); a1 += bf2f(u0 >> 16); a2 += bf2f(u1); a3 += bf2f(u1 >> 16);
  }
  const float* xr = xf + (size_t)n*FN;
  #pragma unroll
  for(int i = 0; i < FN; i++){
    float xi = xr[i];
    a0 += xi*s_w[i*H1C + q*4+0]; a1 += xi*s_w[i*H1C + q*4+1];
    a2 += xi*s_w[i*H1C + q*4+2]; a3 += xi*s_w[i*H1C + q*4+3];
  }
  float4 r; r.x = a0>0.f?a0:0.f; r.y = a1>0.f?a1:0.f; r.z = a2>0.f?a2:0.f; r.w = a3>0.f?a3:0.f;
  *(float4*)(h1 + (size_t)n*H1C + q*4) = r;
}

// h2 = relu(h1@wr2 + br2 + gather(msg2)); 4 threads/node
__global__ void __launch_bounds__(256) gather2_kernel(
    const float* __restrict__ h1, const unsigned short* __restrict__ msg,
    const int* __restrict__ rowptr, const int* __restrict__ csr,
    const float* __restrict__ wr, const float* __restrict__ br, float* __restrict__ h2)
{
  __shared__ float s_w[H1C*H2C], s_b[H2C];
  for(int i = threadIdx.x; i < H1C*H2C; i += 256) s_w[i] = wr[i];
  if(threadIdx.x < H2C) s_b[threadIdx.x] = br[threadIdx.x];
  __syncthreads();
  int g = blockIdx.x*256 + threadIdx.x;
  int n = g >> 2, q = g & 3;
  if(n >= NN) return;
  float a0 = s_b[q*4+0], a1 = s_b[q*4+1], a2 = s_b[q*4+2], a3 = s_b[q*4+3];
  int jb = rowptr[n], je = rowptr[n+1];
  for(int j = jb; j < je; j++){
    int eid = csr[j];
    const unsigned int* mp = (const unsigned int*)(msg + (size_t)eid*H2C + q*4);
    unsigned int u0 = mp[0], u1 = mp[1];
    a0 += bf2f(u0); a1 += bf2f(u0 >> 16); a2 += bf2f(u1); a3 += bf2f(u1 >> 16);
  }
  const float* hr = h1 + (size_t)n*H1C;
  #pragma unroll
  for(int i = 0; i < H1C; i++){
    float xi = hr[i];
    a0 += xi*s_w[i*H2C + q*4+0]; a1 += xi*s_w[i*H2C + q*4+1];
    a2 += xi*s_w[i*H2C + q*4+2]; a3 += xi*s_w[i*H2C + q*4+3];
  }
  float4 r; r.x = a0>0.f?a0:0.f; r.y = a1>0.f?a1:0.f; r.z = a2>0.f?a2:0.f; r.w = a3>0.f?a3:0.f;
  *(float4*)(h2 + (size_t)n*H2C + q*4) = r;
}

// one wave per graph: mean-pool h2 + concat x_att + 2-layer head
__global__ void head_kernel(const float* __restrict__ h2, const float* __restrict__ x_att,
    const int* __restrict__ batch,
    const float* __restrict__ wl1, const float* __restrict__ bl1,
    const float* __restrict__ wl2, const float* __restrict__ bl2,
    void* __restrict__ out, const int* __restrict__ flag)
{
  int g = blockIdx.x;
  int lane = threadIdx.x;
  int start = lower_bound_i(batch, NN, g);
  int end   = lower_bound_i(batch, NN, g + 1);
  float acc[H2C];
  #pragma unroll
  for(int f = 0; f < H2C; f++) acc[f] = 0.f;
  for(int n = start + lane; n < end; n += 64){
    const float4* hp = (const float4*)(h2 + (size_t)n*H2C);
    #pragma unroll
    for(int q = 0; q < 4; q++){
      float4 v = hp[q];
      acc[q*4+0] += v.x; acc[q*4+1] += v.y; acc[q*4+2] += v.z; acc[q*4+3] += v.w;
    }
  }
  #pragma unroll
  for(int o = 32; o >= 1; o >>= 1){
    #pragma unroll
    for(int f = 0; f < H2C; f++) acc[f] += __shfl_xor(acc[f], o);
  }
  if(lane == 0){
    float inv = 1.f / fmaxf((float)(end - start), 1.f);
    float z[H2C + FN];
    #pragma unroll
    for(int f = 0; f < H2C; f++) z[f] = acc[f] * inv;
    #pragma unroll
    for(int f = 0; f < FN; f++) z[H2C + f] = x_att[(size_t)g*FN + f];
    float t1[8];
    #pragma unroll
    for(int j = 0; j < 8; j++){
      float t = bl1[j];
      #pragma unroll
      for(int c = 0; c < H2C + FN; c++) t += z[c] * wl1[c*8 + j];
      t1[j] = t;
    }
    float o = bl2[0];
    #pragma unroll
    for(int j = 0; j < 8; j++) o += t1[j] * wl2[j];
    if((*flag) != 0) ((__hip_bfloat16*)out)[g] = __float2bfloat16(o);
    else             ((float*)out)[g] = o;
  }
}

extern "C" void kernel_launch(void* const* d_in, const int* in_sizes, int n_in,
                              void* d_out, int out_size, void* d_ws, size_t ws_size,
                              hipStream_t stream)
{
  const int* ei    = (const int*)d_in[22];
  const int* batch = (const int*)d_in[23];

  float* ws = (float*)d_ws;
  float* xf     = ws;                          // 1,600,000 f
  float* x_att  = xf + 1600000;                //    40,000 f
  float* gate   = x_att + 40000;               //   100,000 f
  float* wts    = gate + 100000;               //    19,360 f
  int*   rowptr = (int*)(wts + 19360);         //   100,016 i
  int*   cursor = rowptr + 100016;             //   100,000 i
  int*   deg    = cursor + 100000;             //   100,000 i
  int*   bsum   = deg + 100000;                //       512 i
  int*   csr    = bsum + 512;                  //   200,000 i
  int*   flagp  = csr + 200000;                //        16 i
  unsigned int* wpack1 = (unsigned int*)(flagp + 16);   // 4,736 u32
  unsigned int* wpack2 = wpack1 + 4736;                 // 4,416 u32
  float* h1     = (float*)(wpack2 + 4416);     // 3,200,000 f
  unsigned int* hpk1 = (unsigned int*)h1;      // alias: dead once conv1 done
  unsigned short* msg1 = (unsigned short*)(h1 + 3200000);  // 6,400,000 u16
  unsigned short* msg2 = msg1;                 // reuse after gather1
  float* h2     = (float*)(msg1 + 6400000);    // 1,600,000 f
  unsigned int* hpk2 = (unsigned int*)h2;      // alias: dead once conv2 done
  // total ~41 MB

  WArgs wa;
  for(int i = 0; i < NW; i++) wa.p[i] = d_in[2 + i];

  detect_kernel<<<1, 256, 0, stream>>>(d_in[0], flagp);
  setup_small_kernel<<<(int)((SS3 + 255)/256), 256, 0, stream>>>(wa, flagp, wts, wpack1, wpack2, deg);
  cvt_x_kernel<<<(200000 + 255)/256, 256, 0, stream>>>(d_in[0], xf, flagp);
  gate_kernel<<<(NN + 255)/256, 256, 0, stream>>>(d_in[0], d_in[14], d_in[15], d_in[16], d_in[17], flagp, gate);

  const int NB1 = (NN + 255)/256;  // 391
  histo_kernel<<<(NE + 255)/256, 256, 0, stream>>>(ei, deg);
  scan1_kernel<<<NB1, 256, 0, stream>>>(deg, bsum);
  scan2_kernel<<<1, 512, 0, stream>>>(bsum, NB1);
  scan3_kernel<<<NB1, 256, 0, stream>>>(deg, bsum, rowptr, cursor);
  fill_kernel<<<(NE + 255)/256, 256, 0, stream>>>(ei, cursor, csr);

  attn_pool_kernel<<<NG, 64, 0, stream>>>(gate, xf, batch, x_att);

  edge_h_kernel<<<(int)(((long)NE*8 + 255)/256), 256, 0, stream>>>(d_in[1], d_in[2], d_in[3], flagp, hpk1);
  conv_mfma_kernel<FN, H1C, 64, 128><<<NE/64, 128, 0, stream>>>(
      xf, hpk1, ei, (const unsigned short*)wpack1, msg1);
  gather1_kernel<<<(NN*8 + 255)/256, 256, 0, stream>>>(xf, msg1, rowptr, csr, wts+OW_R1, wts+OB_R1, h1);

  edge_h_kernel<<<(int)(((long)NE*8 + 255)/256), 256, 0, stream>>>(d_in[1], d_in[8], d_in[9], flagp, hpk2);
  conv_mfma_kernel<H1C, H2C, 32, 64><<<NE/32, 64, 0, stream>>>(
      h1, hpk2, ei, (const unsigned short*)wpack2, msg2);
  gather2_kernel<<<(NN*4 + 255)/256, 256, 0, stream>>>(h1, msg2, rowptr, csr, wts+OW_R2, wts+OB_R2, h2);

  head_kernel<<<NG, 64, 0, stream>>>(h2, x_att, batch,
      wts+OW_L1, wts+OB_L1, wts+OW_L2, wts+OB_L2, d_out, flagp);
}

// Round 9
// 247.571 us; speedup vs baseline: 2.8764x; 1.1031x over previous
//
#include <hip/hip_runtime.h>
#include <hip/hip_bf16.h>

#define NN 100000   // nodes
#define NE 200000   // edges
#define NG 2500     // graphs
#define FN 16       // node feats
#define FE 8        // edge feats
#define H1C 32
#define H2C 16
#define KH 16       // edge-MLP hidden

typedef __attribute__((ext_vector_type(8))) short short8;
typedef __attribute__((ext_vector_type(4))) float f32x4;

__device__ __forceinline__ float bf2f(unsigned int u){
  union { unsigned int i; float f; } v; v.i = (u & 0xffffu) << 16; return v.f;
}
__device__ __forceinline__ unsigned short f2bf(float f){
  union { float f; unsigned int i; } u; u.f = f;
  unsigned int r = u.i + 0x7fffu + ((u.i >> 16) & 1u);   // RNE, finite data
  return (unsigned short)(r >> 16);
}
__device__ __forceinline__ unsigned int pk2(float a, float b){
  return (unsigned int)f2bf(a) | ((unsigned int)f2bf(b) << 16);
}
__device__ __forceinline__ float rdf(const void* p, long i, bool isbf){
  return isbf ? bf2f(((const unsigned short*)p)[i]) : ((const float*)p)[i];
}
__device__ __forceinline__ int lower_bound_i(const int* __restrict__ a, int n, int v){
  int lo = 0, hi = n;
  while(lo < hi){ int mid = (lo + hi) >> 1; if(a[mid] < v) lo = mid + 1; else hi = mid; }
  return lo;
}

// flag=1 if float inputs are bf16, 0 if fp32
__global__ void detect_kernel(const void* __restrict__ x, int* __restrict__ flag){
  int tid = threadIdx.x;
  const unsigned short* u = (const unsigned short*)x;
  float f = bf2f(u[2*tid]);
  float a = fabsf(f);
  int sane = (f == 0.0f) || (a > 1e-4f && a < 1e4f);
  __shared__ int cnt;
  if(tid == 0) cnt = 0;
  __syncthreads();
  if(sane) atomicAdd(&cnt, 1);
  __syncthreads();
  if(tid == 0) *flag = (cnt >= 128) ? 1 : 0;
}

#define NW 20
struct WArgs { const void* p[NW]; };
#define W_TOTAL 19330
enum {
  OW_E1A=0,     OB_E1A=128,   OW_E1B=144,   OB_E1B=8336,  OW_R1=8848,  OB_R1=9360,
  OW_E2A=9392,  OB_E2A=9520,  OW_E2B=9536,  OB_E2B=17728, OW_R2=18240, OB_R2=18752,
  OW_G1=18768,  OB_G1=19024,  OW_G2=19040,  OB_G2=19056,
  OW_L1=19057,  OB_L1=19313,  OW_L2=19321,  OB_L2=19329
};

// vectorized x conversion: 8 elems/thread
__global__ void __launch_bounds__(256) cvt_x_kernel(
    const void* __restrict__ xin, float* __restrict__ xf, const int* __restrict__ flag)
{
  bool isbf = (*flag) != 0;
  int t = blockIdx.x*256 + threadIdx.x;
  if((long)t*8 >= 1600000L) return;
  float4 a, b;
  if(isbf){
    uint4 u = ((const uint4*)xin)[t];
    a.x = bf2f(u.x); a.y = bf2f(u.x >> 16); a.z = bf2f(u.y); a.w = bf2f(u.y >> 16);
    b.x = bf2f(u.z); b.y = bf2f(u.z >> 16); b.z = bf2f(u.w); b.w = bf2f(u.w >> 16);
  } else {
    a = ((const float4*)xin)[2*t]; b = ((const float4*)xin)[2*t+1];
  }
  ((float4*)xf)[2*t] = a; ((float4*)xf)[2*t+1] = b;
}

// small setup: wts-cvt | pack W1^T | pack W2^T | deg=0  (round-7-verified wpack layout)
#define SS0 19330L
#define SS1 (SS0 + 4736L)
#define SS2 (SS1 + 4416L)
#define SS3 (SS2 + 100000L)
__global__ void __launch_bounds__(256) setup_small_kernel(
    WArgs w, const int* __restrict__ flag, float* __restrict__ wts,
    unsigned int* __restrict__ wpack1, unsigned int* __restrict__ wpack2,
    int* __restrict__ deg)
{
  bool isbf = (*flag) != 0;
  long t = (long)blockIdx.x*256 + threadIdx.x;
  if(t < SS0){
    const int sz[NW] = {128,16,8192,512,512,32, 128,16,8192,512,512,16, 256,16,16,1, 256,8,8,1};
    long i = t;
    int seg = 0; long base = 0;
    while(i - base >= sz[seg]){ base += sz[seg]; seg++; }
    wts[i] = rdf(w.p[seg], i - base, isbf);
    return;
  }
  if(t < SS1){   // wpack1: 32 rows x 148 u32 (KP=296)
    long j = t - SS0;
    int n = (int)(j / 148); int k = (int)(j % 148) * 2;
    float v0 = 0.f, v1 = 0.f;
    if(k < 256)        v0 = rdf(w.p[2], (long)k*32 + n, isbf);
    else if(k < 272)   v0 = rdf(w.p[3], (long)(k-256)*32 + n, isbf);
    if(k+1 < 256)      v1 = rdf(w.p[2], (long)(k+1)*32 + n, isbf);
    else if(k+1 < 272) v1 = rdf(w.p[3], (long)(k+1-256)*32 + n, isbf);
    wpack1[j] = pk2(v0, v1);
    return;
  }
  if(t < SS2){   // wpack2: 16 rows x 276 u32 (KP=552)
    long j = t - SS1;
    int n = (int)(j / 276); int k = (int)(j % 276) * 2;
    float v0 = 0.f, v1 = 0.f;
    if(k < 512)        v0 = rdf(w.p[8], (long)k*16 + n, isbf);
    else if(k < 544)   v0 = rdf(w.p[9], (long)(k-512)*16 + n, isbf);
    if(k+1 < 512)      v1 = rdf(w.p[8], (long)(k+1)*16 + n, isbf);
    else if(k+1 < 544) v1 = rdf(w.p[9], (long)(k+1-512)*16 + n, isbf);
    wpack2[j] = pk2(v0, v1);
    return;
  }
  if(t < SS3) deg[t - SS2] = 0;
}

// edge-MLP: weights staged to LDS. 8 threads/edge -> hpk[e*8+d] = pack(h[2d], h[2d+1])
__global__ void __launch_bounds__(256) edge_h_kernel(
    const void* __restrict__ efin, const void* __restrict__ wa, const void* __restrict__ ba,
    const int* __restrict__ flag, unsigned int* __restrict__ hpk)
{
  __shared__ float s_wa[FE*KH], s_ba[KH];
  bool isbf = (*flag) != 0;
  if(threadIdx.x < FE*KH) s_wa[threadIdx.x] = rdf(wa, threadIdx.x, isbf);
  if(threadIdx.x < KH)    s_ba[threadIdx.x] = rdf(ba, threadIdx.x, isbf);
  __syncthreads();
  long t = (long)blockIdx.x*256 + threadIdx.x;   // exact grid NE*8
  if(t >= (long)NE*8) return;
  long e = t >> 3; int d = (int)(t & 7);
  float ev[FE];
  if(isbf){
    uint4 u = ((const uint4*)efin)[e];
    ev[0]=bf2f(u.x); ev[1]=bf2f(u.x>>16); ev[2]=bf2f(u.y); ev[3]=bf2f(u.y>>16);
    ev[4]=bf2f(u.z); ev[5]=bf2f(u.z>>16); ev[6]=bf2f(u.w); ev[7]=bf2f(u.w>>16);
  } else {
    float4 a = ((const float4*)efin)[2*e], b = ((const float4*)efin)[2*e+1];
    ev[0]=a.x; ev[1]=a.y; ev[2]=a.z; ev[3]=a.w; ev[4]=b.x; ev[5]=b.y; ev[6]=b.z; ev[7]=b.w;
  }
  float h0 = s_ba[2*d], h1 = s_ba[2*d+1];
  #pragma unroll
  for(int j = 0; j < FE; j++){
    h0 += ev[j] * s_wa[j*KH + 2*d];
    h1 += ev[j] * s_wa[j*KH + 2*d+1];
  }
  h0 = h0 > 0.f ? h0 : 0.f;
  h1 = h1 > 0.f ? h1 : 0.f;
  hpk[t] = pk2(h0, h1);
}

// gate MLP: weights in LDS, x row from raw input
__global__ void __launch_bounds__(256) gate_kernel(
    const void* __restrict__ xin, const void* __restrict__ wg1, const void* __restrict__ bg1,
    const void* __restrict__ wg2, const void* __restrict__ bg2,
    const int* __restrict__ flag, float* __restrict__ gate)
{
  __shared__ float s_w1[FN*FN], s_b1[FN], s_w2[FN], s_b2v[1];
  bool isbf = (*flag) != 0;
  if(threadIdx.x < FN*FN) s_w1[threadIdx.x] = rdf(wg1, threadIdx.x, isbf);
  if(threadIdx.x < FN){ s_b1[threadIdx.x] = rdf(bg1, threadIdx.x, isbf); s_w2[threadIdx.x] = rdf(wg2, threadIdx.x, isbf); }
  if(threadIdx.x == 0) s_b2v[0] = rdf(bg2, 0, isbf);
  __syncthreads();
  int n = blockIdx.x*256 + threadIdx.x;
  if(n >= NN) return;
  float xv[FN];
  if(isbf){
    uint4 u0 = ((const uint4*)xin)[2*n], u1 = ((const uint4*)xin)[2*n+1];
    xv[0]=bf2f(u0.x); xv[1]=bf2f(u0.x>>16); xv[2]=bf2f(u0.y); xv[3]=bf2f(u0.y>>16);
    xv[4]=bf2f(u0.z); xv[5]=bf2f(u0.z>>16); xv[6]=bf2f(u0.w); xv[7]=bf2f(u0.w>>16);
    xv[8]=bf2f(u1.x); xv[9]=bf2f(u1.x>>16); xv[10]=bf2f(u1.y); xv[11]=bf2f(u1.y>>16);
    xv[12]=bf2f(u1.z); xv[13]=bf2f(u1.z>>16); xv[14]=bf2f(u1.w); xv[15]=bf2f(u1.w>>16);
  } else {
    #pragma unroll
    for(int q = 0; q < 4; q++){
      float4 v = ((const float4*)xin)[4*n + q];
      xv[q*4+0]=v.x; xv[q*4+1]=v.y; xv[q*4+2]=v.z; xv[q*4+3]=v.w;
    }
  }
  float g = s_b2v[0];
  #pragma unroll
  for(int j = 0; j < FN; j++){
    float hj = s_b1[j];
    #pragma unroll
    for(int i = 0; i < FN; i++) hj += xv[i] * s_w1[i*FN + j];
    hj = hj > 0.f ? hj : 0.f;
    g += hj * s_w2[j];
  }
  gate[n] = g;
}

// one wave per graph: segment softmax over precomputed gate + weighted x sum
__global__ void attn_pool_kernel(const float* __restrict__ gate, const float* __restrict__ xf,
                                 const int* __restrict__ batch, float* __restrict__ x_att)
{
  int g = blockIdx.x;
  int lane = threadIdx.x;
  int start = lower_bound_i(batch, NN, g);
  int end   = lower_bound_i(batch, NN, g + 1);
  float m = -1e30f;
  for(int n = start + lane; n < end; n += 64) m = fmaxf(m, gate[n]);
  #pragma unroll
  for(int o = 32; o >= 1; o >>= 1) m = fmaxf(m, __shfl_xor(m, o));
  float s = 0.f;
  float acc[FN];
  #pragma unroll
  for(int f = 0; f < FN; f++) acc[f] = 0.f;
  for(int n = start + lane; n < end; n += 64){
    float a = __expf(gate[n] - m);
    s += a;
    const float4* xp = (const float4*)(xf + (size_t)n * FN);
    #pragma unroll
    for(int q = 0; q < 4; q++){
      float4 v = xp[q];
      acc[q*4+0] += a*v.x; acc[q*4+1] += a*v.y; acc[q*4+2] += a*v.z; acc[q*4+3] += a*v.w;
    }
  }
  #pragma unroll
  for(int o = 32; o >= 1; o >>= 1){
    s += __shfl_xor(s, o);
    #pragma unroll
    for(int f = 0; f < FN; f++) acc[f] += __shfl_xor(acc[f], o);
  }
  if(lane < FN){
    float v = (end > start && s > 0.f) ? acc[lane] / s : 0.f;
    x_att[g*FN + lane] = v;
  }
}

// ---- CSR build ----
__global__ void histo_kernel(const int* __restrict__ ei, int* __restrict__ deg){
  int e = blockIdx.x*256 + threadIdx.x;
  if(e < NE) atomicAdd(&deg[ei[NE + e]], 1);
}
__global__ void scan1_kernel(const int* __restrict__ deg, int* __restrict__ bsum){
  __shared__ int s[256];
  int i = blockIdx.x*256 + threadIdx.x;
  s[threadIdx.x] = (i < NN) ? deg[i] : 0;
  __syncthreads();
  for(int off=128; off>0; off>>=1){
    if(threadIdx.x < off) s[threadIdx.x] += s[threadIdx.x+off];
    __syncthreads();
  }
  if(threadIdx.x==0) bsum[blockIdx.x] = s[0];
}
__global__ void scan2_kernel(int* __restrict__ bsum, int nb){
  __shared__ int s[512];
  int t = threadIdx.x;
  s[t] = (t < nb) ? bsum[t] : 0;
  __syncthreads();
  for(int off=1; off<512; off<<=1){
    int tv = (t>=off) ? s[t-off] : 0;
    __syncthreads();
    s[t] += tv;
    __syncthreads();
  }
  if(t < nb) bsum[t] = s[t];
}
__global__ void scan3_kernel(const int* __restrict__ deg, const int* __restrict__ bsum,
                             int* __restrict__ rowptr, int* __restrict__ cursor){
  __shared__ int s[256];
  int t = threadIdx.x;
  int i = blockIdx.x*256 + t;
  int v = (i < NN) ? deg[i] : 0;
  s[t] = v;
  __syncthreads();
  for(int off=1; off<256; off<<=1){
    int tv = (t>=off) ? s[t-off] : 0;
    __syncthreads();
    s[t] += tv;
    __syncthreads();
  }
  int bpre = (blockIdx.x==0) ? 0 : bsum[blockIdx.x-1];
  int excl = bpre + s[t] - v;
  if(i < NN){
    rowptr[i] = excl; cursor[i] = excl;
    if(i == NN-1) rowptr[NN] = excl + v;
  }
}
__global__ void fill_kernel(const int* __restrict__ ei, int* __restrict__ cursor, int* __restrict__ csr){
  int e = blockIdx.x*256 + threadIdx.x;
  if(e < NE){ int pos = atomicAdd(&cursor[ei[NE+e]], 1); csr[pos] = e; }
}

// ---- NNConv message GEMM, register-built A-fragments (no LDS, no barrier) ----
// P[e, k] = h[e, k/IN]*x[e, k%IN] for k<KH*IN, x[e, k-KH*IN] after; msg = P @ W.
// Lane (m=lane&15, quad) holds A[m][ks*32+quad*8+j]: per k-step one h value times a
// fixed x8 slice -> 8 muls + pack. W^T rows read from L1-hot global wpack (round-7 layout).
template<int IN, int OUT>
__global__ void __launch_bounds__(256) conv_mfma_kernel(
    const float* __restrict__ nodef, const unsigned int* __restrict__ hpk,
    const int* __restrict__ ei, const unsigned short* __restrict__ wpack,
    unsigned short* __restrict__ msg)
{
  constexpr int KIN  = KH*IN;                 // 256 | 512
  constexpr int KTOT = KIN + IN;              // 272 | 544
  constexpr int KMF  = ((KTOT + 31)/32)*32;   // 288 | 544
  constexpr int KP   = KMF + 8;               // 296 | 552 (wpack row stride)
  constexpr int NT   = OUT/16;                // 2 | 1
  constexpr int KS   = KMF/32;                // 9 | 17
  int tid = threadIdx.x;
  int lane = tid & 63, m = lane & 15, quad = lane >> 4;
  int wid = tid >> 6;
  int ebase = blockIdx.x*64 + wid*16;         // 16 edges per wave, grid = NE/64
  int em = ebase + m;
  int sn = ei[em];
  int q1 = quad >> 1;
  int xoff = (IN == 16) ? ((quad & 1)*8) : (quad*8);
  float x8[8];
  {
    const float4* xp = (const float4*)(nodef + (size_t)sn*IN + xoff);
    float4 v0 = xp[0], v1 = xp[1];
    x8[0]=v0.x; x8[1]=v0.y; x8[2]=v0.z; x8[3]=v0.w;
    x8[4]=v1.x; x8[5]=v1.y; x8[6]=v1.z; x8[7]=v1.w;
  }
  unsigned int hu[8];
  {
    const uint4* hp = (const uint4*)(hpk + (size_t)em*8);
    uint4 u0 = hp[0], u1 = hp[1];
    hu[0]=u0.x; hu[1]=u0.y; hu[2]=u0.z; hu[3]=u0.w;
    hu[4]=u1.x; hu[5]=u1.y; hu[6]=u1.z; hu[7]=u1.w;
  }
  short8 xb;   // bf16(x8) for the trailing x-part k-step
  {
    unsigned int* xbp = (unsigned int*)&xb;
    #pragma unroll
    for(int j = 0; j < 4; j++) xbp[j] = pk2(x8[2*j], x8[2*j+1]);
  }

  f32x4 acc[NT];
  #pragma unroll
  for(int nt = 0; nt < NT; nt++) acc[nt] = (f32x4){0.f,0.f,0.f,0.f};

  #pragma unroll
  for(int ks = 0; ks < KS; ks++){
    short8 a;
    if(ks < KS-1){
      // k = ks*32 + quad*8 + j < KIN: kh = IN==16 ? 2*ks+q1 : ks; x-idx = xoff+j
      float hv = (IN == 16) ? bf2f(hu[ks] >> (16*q1))
                            : bf2f(hu[ks >> 1] >> (16*(ks & 1)));
      unsigned int* ap = (unsigned int*)&a;
      #pragma unroll
      for(int j = 0; j < 4; j++) ap[j] = pk2(hv*x8[2*j], hv*x8[2*j+1]);
    } else {
      // x-part: conv1 k in [256,288): quads 0,1 real, 2,3 zero; conv2 k in [512,544): all real
      if(IN == 16) a = (quad < 2) ? xb : (short8){0,0,0,0,0,0,0,0};
      else         a = xb;
    }
    #pragma unroll
    for(int nt = 0; nt < NT; nt++){
      short8 b = *(const short8*)(wpack + (size_t)(nt*16 + m)*KP + ks*32 + quad*8);
      acc[nt] = __builtin_amdgcn_mfma_f32_16x16x32_bf16(a, b, acc[nt], 0, 0, 0);
    }
  }
  #pragma unroll
  for(int nt = 0; nt < NT; nt++)
    #pragma unroll
    for(int r = 0; r < 4; r++)   // C layout: row=(lane>>4)*4+reg (edge), col=lane&15
      msg[(size_t)(ebase + quad*4 + r)*OUT + nt*16 + m] = f2bf(acc[nt][r]);
}

// h1 = relu(x@wr1 + br1 + gather(msg1)); 8 threads/node
__global__ void __launch_bounds__(256) gather1_kernel(
    const float* __restrict__ xf, const unsigned short* __restrict__ msg,
    const int* __restrict__ rowptr, const int* __restrict__ csr,
    const float* __restrict__ wr, const float* __restrict__ br, float* __restrict__ h1)
{
  __shared__ float s_w[FN*H1C], s_b[H1C];
  for(int i = threadIdx.x; i < FN*H1C; i += 256) s_w[i] = wr[i];
  if(threadIdx.x < H1C) s_b[threadIdx.x] = br[threadIdx.x];
  __syncthreads();
  int g = blockIdx.x*256 + threadIdx.x;
  int n = g >> 3, q = g & 7;
  if(n >= NN) return;
  float a0 = s_b[q*4+0], a1 = s_b[q*4+1], a2 = s_b[q*4+2], a3 = s_b[q*4+3];
  int jb = rowptr[n], je = rowptr[n+1];
  for(int j = jb; j < je; j++){
    int eid = csr[j];
    const unsigned int* mp = (const unsigned int*)(msg + (size_t)eid*H1C + q*4);
    unsigned int u0 = mp[0], u1 = mp[1];
    a0 += bf2f(u0); a1 += bf2f(u0 >> 16); a2 += bf2f(u1); a3 += bf2f(u1 >> 16);
  }
  const float* xr = xf + (size_t)n*FN;
  #pragma unroll
  for(int i = 0; i < FN; i++){
    float xi = xr[i];
    a0 += xi*s_w[i*H1C + q*4+0]; a1 += xi*s_w[i*H1C + q*4+1];
    a2 += xi*s_w[i*H1C + q*4+2]; a3 += xi*s_w[i*H1C + q*4+3];
  }
  float4 r; r.x = a0>0.f?a0:0.f; r.y = a1>0.f?a1:0.f; r.z = a2>0.f?a2:0.f; r.w = a3>0.f?a3:0.f;
  *(float4*)(h1 + (size_t)n*H1C + q*4) = r;
}

// h2 = relu(h1@wr2 + br2 + gather(msg2)); 4 threads/node
__global__ void __launch_bounds__(256) gather2_kernel(
    const float* __restrict__ h1, const unsigned short* __restrict__ msg,
    const int* __restrict__ rowptr, const int* __restrict__ csr,
    const float* __restrict__ wr, const float* __restrict__ br, float* __restrict__ h2)
{
  __shared__ float s_w[H1C*H2C], s_b[H2C];
  for(int i = threadIdx.x; i < H1C*H2C; i += 256) s_w[i] = wr[i];
  if(threadIdx.x < H2C) s_b[threadIdx.x] = br[threadIdx.x];
  __syncthreads();
  int g = blockIdx.x*256 + threadIdx.x;
  int n = g >> 2, q = g & 3;
  if(n >= NN) return;
  float a0 = s_b[q*4+0], a1 = s_b[q*4+1], a2 = s_b[q*4+2], a3 = s_b[q*4+3];
  int jb = rowptr[n], je = rowptr[n+1];
  for(int j = jb; j < je; j++){
    int eid = csr[j];
    const unsigned int* mp = (const unsigned int*)(msg + (size_t)eid*H2C + q*4);
    unsigned int u0 = mp[0], u1 = mp[1];
    a0 += bf2f(u0); a1 += bf2f(u0 >> 16); a2 += bf2f(u1); a3 += bf2f(u1 >> 16);
  }
  const float* hr = h1 + (size_t)n*H1C;
  #pragma unroll
  for(int i = 0; i < H1C; i++){
    float xi = hr[i];
    a0 += xi*s_w[i*H2C + q*4+0]; a1 += xi*s_w[i*H2C + q*4+1];
    a2 += xi*s_w[i*H2C + q*4+2]; a3 += xi*s_w[i*H2C + q*4+3];
  }
  float4 r; r.x = a0>0.f?a0:0.f; r.y = a1>0.f?a1:0.f; r.z = a2>0.f?a2:0.f; r.w = a3>0.f?a3:0.f;
  *(float4*)(h2 + (size_t)n*H2C + q*4) = r;
}

// one wave per graph: mean-pool h2 + concat x_att + 2-layer head
__global__ void head_kernel(const float* __restrict__ h2, const float* __restrict__ x_att,
    const int* __restrict__ batch,
    const float* __restrict__ wl1, const float* __restrict__ bl1,
    const float* __restrict__ wl2, const float* __restrict__ bl2,
    void* __restrict__ out, const int* __restrict__ flag)
{
  int g = blockIdx.x;
  int lane = threadIdx.x;
  int start = lower_bound_i(batch, NN, g);
  int end   = lower_bound_i(batch, NN, g + 1);
  float acc[H2C];
  #pragma unroll
  for(int f = 0; f < H2C; f++) acc[f] = 0.f;
  for(int n = start + lane; n < end; n += 64){
    const float4* hp = (const float4*)(h2 + (size_t)n*H2C);
    #pragma unroll
    for(int q = 0; q < 4; q++){
      float4 v = hp[q];
      acc[q*4+0] += v.x; acc[q*4+1] += v.y; acc[q*4+2] += v.z; acc[q*4+3] += v.w;
    }
  }
  #pragma unroll
  for(int o = 32; o >= 1; o >>= 1){
    #pragma unroll
    for(int f = 0; f < H2C; f++) acc[f] += __shfl_xor(acc[f], o);
  }
  if(lane == 0){
    float inv = 1.f / fmaxf((float)(end - start), 1.f);
    float z[H2C + FN];
    #pragma unroll
    for(int f = 0; f < H2C; f++) z[f] = acc[f] * inv;
    #pragma unroll
    for(int f = 0; f < FN; f++) z[H2C + f] = x_att[(size_t)g*FN + f];
    float t1[8];
    #pragma unroll
    for(int j = 0; j < 8; j++){
      float t = bl1[j];
      #pragma unroll
      for(int c = 0; c < H2C + FN; c++) t += z[c] * wl1[c*8 + j];
      t1[j] = t;
    }
    float o = bl2[0];
    #pragma unroll
    for(int j = 0; j < 8; j++) o += t1[j] * wl2[j];
    if((*flag) != 0) ((__hip_bfloat16*)out)[g] = __float2bfloat16(o);
    else             ((float*)out)[g] = o;
  }
}

extern "C" void kernel_launch(void* const* d_in, const int* in_sizes, int n_in,
                              void* d_out, int out_size, void* d_ws, size_t ws_size,
                              hipStream_t stream)
{
  const int* ei    = (const int*)d_in[22];
  const int* batch = (const int*)d_in[23];

  float* ws = (float*)d_ws;
  float* xf     = ws;                          // 1,600,000 f
  float* x_att  = xf + 1600000;                //    40,000 f
  float* gate   = x_att + 40000;               //   100,000 f
  float* wts    = gate + 100000;               //    19,360 f
  int*   rowptr = (int*)(wts + 19360);         //   100,016 i
  int*   cursor = rowptr + 100016;             //   100,000 i
  int*   deg    = cursor + 100000;             //   100,000 i
  int*   bsum   = deg + 100000;                //       512 i
  int*   csr    = bsum + 512;                  //   200,000 i
  int*   flagp  = csr + 200000;                //        16 i
  unsigned int* wpack1 = (unsigned int*)(flagp + 16);   // 4,736 u32
  unsigned int* wpack2 = wpack1 + 4736;                 // 4,416 u32
  float* h1     = (float*)(wpack2 + 4416);     // 3,200,000 f
  unsigned int* hpk1 = (unsigned int*)h1;      // alias: [NE][8] u32, dead before gather1
  unsigned short* msg1 = (unsigned short*)(h1 + 3200000);  // 6,400,000 u16
  unsigned short* msg2 = msg1;                 // reuse after gather1
  float* h2     = (float*)(msg1 + 6400000);    // 1,600,000 f
  unsigned int* hpk2 = (unsigned int*)h2;      // alias: dead before gather2
  // total ~41 MB (round-7 layout)

  WArgs wa;
  for(int i = 0; i < NW; i++) wa.p[i] = d_in[2 + i];

  detect_kernel<<<1, 256, 0, stream>>>(d_in[0], flagp);
  setup_small_kernel<<<(int)((SS3 + 255)/256), 256, 0, stream>>>(wa, flagp, wts, wpack1, wpack2, deg);
  cvt_x_kernel<<<(200000 + 255)/256, 256, 0, stream>>>(d_in[0], xf, flagp);
  gate_kernel<<<(NN + 255)/256, 256, 0, stream>>>(d_in[0], d_in[14], d_in[15], d_in[16], d_in[17], flagp, gate);

  const int NB1 = (NN + 255)/256;  // 391
  histo_kernel<<<(NE + 255)/256, 256, 0, stream>>>(ei, deg);
  scan1_kernel<<<NB1, 256, 0, stream>>>(deg, bsum);
  scan2_kernel<<<1, 512, 0, stream>>>(bsum, NB1);
  scan3_kernel<<<NB1, 256, 0, stream>>>(deg, bsum, rowptr, cursor);
  fill_kernel<<<(NE + 255)/256, 256, 0, stream>>>(ei, cursor, csr);

  attn_pool_kernel<<<NG, 64, 0, stream>>>(gate, xf, batch, x_att);

  edge_h_kernel<<<(int)(((long)NE*8 + 255)/256), 256, 0, stream>>>(d_in[1], d_in[2], d_in[3], flagp, hpk1);
  conv_mfma_kernel<FN, H1C><<<NE/64, 256, 0, stream>>>(
      xf, hpk1, ei, (const unsigned short*)wpack1, msg1);
  gather1_kernel<<<(NN*8 + 255)/256, 256, 0, stream>>>(xf, msg1, rowptr, csr, wts+OW_R1, wts+OB_R1, h1);

  edge_h_kernel<<<(int)(((long)NE*8 + 255)/256), 256, 0, stream>>>(d_in[1], d_in[8], d_in[9], flagp, hpk2);
  conv_mfma_kernel<H1C, H2C><<<NE/64, 256, 0, stream>>>(
      h1, hpk2, ei, (const unsigned short*)wpack2, msg2);
  gather2_kernel<<<(NN*4 + 255)/256, 256, 0, stream>>>(h1, msg2, rowptr, csr, wts+OW_R2, wts+OB_R2, h2);

  head_kernel<<<NG, 64, 0, stream>>>(h2, x_att, batch,
      wts+OW_L1, wts+OB_L1, wts+OW_L2, wts+OB_L2, d_out, flagp);
}

// Round 10
// 231.386 us; speedup vs baseline: 3.0776x; 1.0699x over previous
//
#include <hip/hip_runtime.h>
#include <hip/hip_bf16.h>

#define NN 100000   // nodes
#define NE 200000   // edges
#define NG 2500     // graphs
#define FN 16       // node feats
#define FE 8        // edge feats
#define H1C 32
#define H2C 16
#define KH 16       // edge-MLP hidden

typedef __attribute__((ext_vector_type(8))) short short8;
typedef __attribute__((ext_vector_type(4))) float f32x4;

__device__ __forceinline__ float bf2f(unsigned int u){
  union { unsigned int i; float f; } v; v.i = (u & 0xffffu) << 16; return v.f;
}
__device__ __forceinline__ unsigned short f2bf(float f){
  union { float f; unsigned int i; } u; u.f = f;
  unsigned int r = u.i + 0x7fffu + ((u.i >> 16) & 1u);   // RNE, finite data
  return (unsigned short)(r >> 16);
}
__device__ __forceinline__ unsigned int pk2(float a, float b){
  return (unsigned int)f2bf(a) | ((unsigned int)f2bf(b) << 16);
}
__device__ __forceinline__ float rdf(const void* p, long i, bool isbf){
  return isbf ? bf2f(((const unsigned short*)p)[i]) : ((const float*)p)[i];
}
__device__ __forceinline__ int lower_bound_i(const int* __restrict__ a, int n, int v){
  int lo = 0, hi = n;
  while(lo < hi){ int mid = (lo + hi) >> 1; if(a[mid] < v) lo = mid + 1; else hi = mid; }
  return lo;
}

// flag=1 if float inputs are bf16, 0 if fp32
__global__ void detect_kernel(const void* __restrict__ x, int* __restrict__ flag){
  int tid = threadIdx.x;
  const unsigned short* u = (const unsigned short*)x;
  float f = bf2f(u[2*tid]);
  float a = fabsf(f);
  int sane = (f == 0.0f) || (a > 1e-4f && a < 1e4f);
  __shared__ int cnt;
  if(tid == 0) cnt = 0;
  __syncthreads();
  if(sane) atomicAdd(&cnt, 1);
  __syncthreads();
  if(tid == 0) *flag = (cnt >= 128) ? 1 : 0;
}

#define NW 20
struct WArgs { const void* p[NW]; };
#define W_TOTAL 19330
enum {
  OW_E1A=0,     OB_E1A=128,   OW_E1B=144,   OB_E1B=8336,  OW_R1=8848,  OB_R1=9360,
  OW_E2A=9392,  OB_E2A=9520,  OW_E2B=9536,  OB_E2B=17728, OW_R2=18240, OB_R2=18752,
  OW_G1=18768,  OB_G1=19024,  OW_G2=19040,  OB_G2=19056,
  OW_L1=19057,  OB_L1=19313,  OW_L2=19321,  OB_L2=19329
};

// small setup: wts-cvt | pack W1^T | pack W2^T | deg=0  (round-7-verified wpack layout)
#define SS0 19330L
#define SS1 (SS0 + 4736L)
#define SS2 (SS1 + 4416L)
#define SS3 (SS2 + 100000L)
__global__ void __launch_bounds__(256) setup_small_kernel(
    WArgs w, const int* __restrict__ flag, float* __restrict__ wts,
    unsigned int* __restrict__ wpack1, unsigned int* __restrict__ wpack2,
    int* __restrict__ deg)
{
  bool isbf = (*flag) != 0;
  long t = (long)blockIdx.x*256 + threadIdx.x;
  if(t < SS0){
    const int sz[NW] = {128,16,8192,512,512,32, 128,16,8192,512,512,16, 256,16,16,1, 256,8,8,1};
    long i = t;
    int seg = 0; long base = 0;
    while(i - base >= sz[seg]){ base += sz[seg]; seg++; }
    wts[i] = rdf(w.p[seg], i - base, isbf);
    return;
  }
  if(t < SS1){   // wpack1: 32 rows x 148 u32 (KP=296)
    long j = t - SS0;
    int n = (int)(j / 148); int k = (int)(j % 148) * 2;
    float v0 = 0.f, v1 = 0.f;
    if(k < 256)        v0 = rdf(w.p[2], (long)k*32 + n, isbf);
    else if(k < 272)   v0 = rdf(w.p[3], (long)(k-256)*32 + n, isbf);
    if(k+1 < 256)      v1 = rdf(w.p[2], (long)(k+1)*32 + n, isbf);
    else if(k+1 < 272) v1 = rdf(w.p[3], (long)(k+1-256)*32 + n, isbf);
    wpack1[j] = pk2(v0, v1);
    return;
  }
  if(t < SS2){   // wpack2: 16 rows x 276 u32 (KP=552)
    long j = t - SS1;
    int n = (int)(j / 276); int k = (int)(j % 276) * 2;
    float v0 = 0.f, v1 = 0.f;
    if(k < 512)        v0 = rdf(w.p[8], (long)k*16 + n, isbf);
    else if(k < 544)   v0 = rdf(w.p[9], (long)(k-512)*16 + n, isbf);
    if(k+1 < 512)      v1 = rdf(w.p[8], (long)(k+1)*16 + n, isbf);
    else if(k+1 < 544) v1 = rdf(w.p[9], (long)(k+1-544+32)*16 + n, isbf);
    // note: (k+1-512); keep explicit to avoid typo
    if(k+1 >= 512 && k+1 < 544) v1 = rdf(w.p[9], (long)(k+1-512)*16 + n, isbf);
    wpack2[j] = pk2(v0, v1);
    return;
  }
  if(t < SS3) deg[t - SS2] = 0;
}

// gate MLP + x conversion fused: one pass over raw x
__global__ void __launch_bounds__(256) gate_cvt_kernel(
    const void* __restrict__ xin, const void* __restrict__ wg1, const void* __restrict__ bg1,
    const void* __restrict__ wg2, const void* __restrict__ bg2,
    const int* __restrict__ flag, float* __restrict__ gate, float* __restrict__ xf)
{
  __shared__ float s_w1[FN*FN], s_b1[FN], s_w2[FN], s_b2v[1];
  bool isbf = (*flag) != 0;
  if(threadIdx.x < FN*FN) s_w1[threadIdx.x] = rdf(wg1, threadIdx.x, isbf);
  if(threadIdx.x < FN){ s_b1[threadIdx.x] = rdf(bg1, threadIdx.x, isbf); s_w2[threadIdx.x] = rdf(wg2, threadIdx.x, isbf); }
  if(threadIdx.x == 0) s_b2v[0] = rdf(bg2, 0, isbf);
  __syncthreads();
  int n = blockIdx.x*256 + threadIdx.x;
  if(n >= NN) return;
  float xv[FN];
  if(isbf){
    uint4 u0 = ((const uint4*)xin)[2*n], u1 = ((const uint4*)xin)[2*n+1];
    xv[0]=bf2f(u0.x); xv[1]=bf2f(u0.x>>16); xv[2]=bf2f(u0.y); xv[3]=bf2f(u0.y>>16);
    xv[4]=bf2f(u0.z); xv[5]=bf2f(u0.z>>16); xv[6]=bf2f(u0.w); xv[7]=bf2f(u0.w>>16);
    xv[8]=bf2f(u1.x); xv[9]=bf2f(u1.x>>16); xv[10]=bf2f(u1.y); xv[11]=bf2f(u1.y>>16);
    xv[12]=bf2f(u1.z); xv[13]=bf2f(u1.z>>16); xv[14]=bf2f(u1.w); xv[15]=bf2f(u1.w>>16);
  } else {
    #pragma unroll
    for(int q = 0; q < 4; q++){
      float4 v = ((const float4*)xin)[4*n + q];
      xv[q*4+0]=v.x; xv[q*4+1]=v.y; xv[q*4+2]=v.z; xv[q*4+3]=v.w;
    }
  }
  float4* xo = (float4*)(xf + (size_t)n*FN);
  #pragma unroll
  for(int q = 0; q < 4; q++) xo[q] = make_float4(xv[q*4+0], xv[q*4+1], xv[q*4+2], xv[q*4+3]);
  float g = s_b2v[0];
  #pragma unroll
  for(int j = 0; j < FN; j++){
    float hj = s_b1[j];
    #pragma unroll
    for(int i = 0; i < FN; i++) hj += xv[i] * s_w1[i*FN + j];
    hj = hj > 0.f ? hj : 0.f;
    g += hj * s_w2[j];
  }
  gate[n] = g;
}

// ---- CSR build ----
__global__ void histo_kernel(const int* __restrict__ ei, int* __restrict__ deg){
  int e = blockIdx.x*256 + threadIdx.x;
  if(e < NE) atomicAdd(&deg[ei[NE + e]], 1);
}
__global__ void scan1_kernel(const int* __restrict__ deg, int* __restrict__ bsum){
  __shared__ int s[256];
  int i = blockIdx.x*256 + threadIdx.x;
  s[threadIdx.x] = (i < NN) ? deg[i] : 0;
  __syncthreads();
  for(int off=128; off>0; off>>=1){
    if(threadIdx.x < off) s[threadIdx.x] += s[threadIdx.x+off];
    __syncthreads();
  }
  if(threadIdx.x==0) bsum[blockIdx.x] = s[0];
}
__global__ void scan2_kernel(int* __restrict__ bsum, int nb){
  __shared__ int s[512];
  int t = threadIdx.x;
  s[t] = (t < nb) ? bsum[t] : 0;
  __syncthreads();
  for(int off=1; off<512; off<<=1){
    int tv = (t>=off) ? s[t-off] : 0;
    __syncthreads();
    s[t] += tv;
    __syncthreads();
  }
  if(t < nb) bsum[t] = s[t];
}
__global__ void scan3_kernel(const int* __restrict__ deg, const int* __restrict__ bsum,
                             int* __restrict__ rowptr, int* __restrict__ cursor){
  __shared__ int s[256];
  int t = threadIdx.x;
  int i = blockIdx.x*256 + t;
  int v = (i < NN) ? deg[i] : 0;
  s[t] = v;
  __syncthreads();
  for(int off=1; off<256; off<<=1){
    int tv = (t>=off) ? s[t-off] : 0;
    __syncthreads();
    s[t] += tv;
    __syncthreads();
  }
  int bpre = (blockIdx.x==0) ? 0 : bsum[blockIdx.x-1];
  int excl = bpre + s[t] - v;
  if(i < NN){
    rowptr[i] = excl; cursor[i] = excl;
    if(i == NN-1) rowptr[NN] = excl + v;
  }
}
// counting sort fill: csr[pos]=edge id, srcp[pos]=src node (so convs never re-read edge_index)
__global__ void fill_kernel(const int* __restrict__ ei, int* __restrict__ cursor,
                            int* __restrict__ csr, int* __restrict__ srcp){
  int e = blockIdx.x*256 + threadIdx.x;
  if(e < NE){
    int pos = atomicAdd(&cursor[ei[NE+e]], 1);
    csr[pos] = e;
    srcp[pos] = ei[e];
  }
}

// edge-MLP for BOTH convs, CSR-ordered output: hpk{1,2}[j*8+d] for edge csr[j]
__global__ void __launch_bounds__(256) edge_all_kernel(
    const void* __restrict__ efin, const float* __restrict__ wts,
    const int* __restrict__ flag, const int* __restrict__ csr,
    unsigned int* __restrict__ hpk1, unsigned int* __restrict__ hpk2)
{
  __shared__ float s_w1[FE*KH], s_b1[KH], s_w2[FE*KH], s_b2[KH];
  if(threadIdx.x < FE*KH){ s_w1[threadIdx.x] = wts[OW_E1A + threadIdx.x]; s_w2[threadIdx.x] = wts[OW_E2A + threadIdx.x]; }
  if(threadIdx.x < KH){ s_b1[threadIdx.x] = wts[OB_E1A + threadIdx.x]; s_b2[threadIdx.x] = wts[OB_E2A + threadIdx.x]; }
  bool isbf = (*flag) != 0;
  __syncthreads();
  int j = blockIdx.x*256 + threadIdx.x;
  if(j >= NE) return;
  int e = csr[j];
  float ev[FE];
  if(isbf){
    uint4 u = ((const uint4*)efin)[e];
    ev[0]=bf2f(u.x); ev[1]=bf2f(u.x>>16); ev[2]=bf2f(u.y); ev[3]=bf2f(u.y>>16);
    ev[4]=bf2f(u.z); ev[5]=bf2f(u.z>>16); ev[6]=bf2f(u.w); ev[7]=bf2f(u.w>>16);
  } else {
    float4 a = ((const float4*)efin)[2*e], b = ((const float4*)efin)[2*e+1];
    ev[0]=a.x; ev[1]=a.y; ev[2]=a.z; ev[3]=a.w; ev[4]=b.x; ev[5]=b.y; ev[6]=b.z; ev[7]=b.w;
  }
  unsigned int o[8];
  #pragma unroll
  for(int d = 0; d < 8; d++){
    float h0 = s_b1[2*d], h1 = s_b1[2*d+1];
    #pragma unroll
    for(int k = 0; k < FE; k++){
      h0 += ev[k] * s_w1[k*KH + 2*d];
      h1 += ev[k] * s_w1[k*KH + 2*d+1];
    }
    h0 = h0 > 0.f ? h0 : 0.f; h1 = h1 > 0.f ? h1 : 0.f;
    o[d] = pk2(h0, h1);
  }
  uint4* p1 = (uint4*)(hpk1 + (size_t)j*8);
  p1[0] = make_uint4(o[0],o[1],o[2],o[3]); p1[1] = make_uint4(o[4],o[5],o[6],o[7]);
  #pragma unroll
  for(int d = 0; d < 8; d++){
    float h0 = s_b2[2*d], h1 = s_b2[2*d+1];
    #pragma unroll
    for(int k = 0; k < FE; k++){
      h0 += ev[k] * s_w2[k*KH + 2*d];
      h1 += ev[k] * s_w2[k*KH + 2*d+1];
    }
    h0 = h0 > 0.f ? h0 : 0.f; h1 = h1 > 0.f ? h1 : 0.f;
    o[d] = pk2(h0, h1);
  }
  uint4* p2 = (uint4*)(hpk2 + (size_t)j*8);
  p2[0] = make_uint4(o[0],o[1],o[2],o[3]); p2[1] = make_uint4(o[4],o[5],o[6],o[7]);
}

// ---- NNConv message GEMM, register-built A-fragments (round-9-verified math) ----
// All inputs CSR-ordered: srcp[j], hpk[j], msg[j]. ABF: node features are bf16.
template<int IN, int OUT, bool ABF>
__global__ void __launch_bounds__(256) conv_mfma_kernel(
    const void* __restrict__ nodef, const unsigned int* __restrict__ hpk,
    const int* __restrict__ srcp, const unsigned short* __restrict__ wpack,
    unsigned short* __restrict__ msg)
{
  constexpr int KMF  = ((KH*IN + IN + 31)/32)*32;   // 288 | 544
  constexpr int KP   = KMF + 8;                     // 296 | 552
  constexpr int NT   = OUT/16;                      // 2 | 1
  constexpr int KS   = KMF/32;                      // 9 | 17
  int tid = threadIdx.x;
  int lane = tid & 63, m = lane & 15, quad = lane >> 4;
  int wid = tid >> 6;
  int ebase = blockIdx.x*64 + wid*16;               // grid = NE/64 exactly
  int em = ebase + m;
  int sn = srcp[em];
  int q1 = quad >> 1;
  int xoff = (IN == 16) ? ((quad & 1)*8) : (quad*8);
  float x8[8];
  short8 xb;
  if(ABF){
    uint4 u = *(const uint4*)((const unsigned short*)nodef + (size_t)sn*IN + xoff);
    unsigned int uu[4] = {u.x, u.y, u.z, u.w};
    #pragma unroll
    for(int k = 0; k < 4; k++){ x8[2*k] = bf2f(uu[k]); x8[2*k+1] = bf2f(uu[k] >> 16); }
    xb = *(short8*)&u;
  } else {
    const float4* xp = (const float4*)((const float*)nodef + (size_t)sn*IN + xoff);
    float4 v0 = xp[0], v1 = xp[1];
    x8[0]=v0.x; x8[1]=v0.y; x8[2]=v0.z; x8[3]=v0.w;
    x8[4]=v1.x; x8[5]=v1.y; x8[6]=v1.z; x8[7]=v1.w;
    unsigned int* xbp = (unsigned int*)&xb;
    #pragma unroll
    for(int k = 0; k < 4; k++) xbp[k] = pk2(x8[2*k], x8[2*k+1]);
  }
  unsigned int hu[8];
  {
    const uint4* hp = (const uint4*)(hpk + (size_t)em*8);
    uint4 u0 = hp[0], u1 = hp[1];
    hu[0]=u0.x; hu[1]=u0.y; hu[2]=u0.z; hu[3]=u0.w;
    hu[4]=u1.x; hu[5]=u1.y; hu[6]=u1.z; hu[7]=u1.w;
  }

  f32x4 acc[NT];
  #pragma unroll
  for(int nt = 0; nt < NT; nt++) acc[nt] = (f32x4){0.f,0.f,0.f,0.f};

  #pragma unroll
  for(int ks = 0; ks < KS; ks++){
    short8 a;
    if(ks < KS-1){
      float hv = (IN == 16) ? bf2f(hu[ks] >> (16*q1))
                            : bf2f(hu[ks >> 1] >> (16*(ks & 1)));
      unsigned int* ap = (unsigned int*)&a;
      #pragma unroll
      for(int k = 0; k < 4; k++) ap[k] = pk2(hv*x8[2*k], hv*x8[2*k+1]);
    } else {
      if(IN == 16) a = (quad < 2) ? xb : (short8){0,0,0,0,0,0,0,0};
      else         a = xb;
    }
    #pragma unroll
    for(int nt = 0; nt < NT; nt++){
      short8 b = *(const short8*)(wpack + (size_t)(nt*16 + m)*KP + ks*32 + quad*8);
      acc[nt] = __builtin_amdgcn_mfma_f32_16x16x32_bf16(a, b, acc[nt], 0, 0, 0);
    }
  }
  #pragma unroll
  for(int nt = 0; nt < NT; nt++)
    #pragma unroll
    for(int r = 0; r < 4; r++)   // C layout: row=(lane>>4)*4+reg (edge), col=lane&15
      msg[(size_t)(ebase + quad*4 + r)*OUT + nt*16 + m] = f2bf(acc[nt][r]);
}

// h1 = relu(x@wr1 + br1 + sum msg rows rowptr[n]..) -> bf16 h1b. 8 threads/node; msg streaming.
__global__ void __launch_bounds__(256) gather1_kernel(
    const float* __restrict__ xf, const unsigned short* __restrict__ msg,
    const int* __restrict__ rowptr,
    const float* __restrict__ wr, const float* __restrict__ br,
    unsigned short* __restrict__ h1b)
{
  __shared__ float s_w[FN*H1C], s_b[H1C];
  for(int i = threadIdx.x; i < FN*H1C; i += 256) s_w[i] = wr[i];
  if(threadIdx.x < H1C) s_b[threadIdx.x] = br[threadIdx.x];
  __syncthreads();
  int g = blockIdx.x*256 + threadIdx.x;
  int n = g >> 3, q = g & 7;
  if(n >= NN) return;
  float a0 = s_b[q*4+0], a1 = s_b[q*4+1], a2 = s_b[q*4+2], a3 = s_b[q*4+3];
  int jb = rowptr[n], je = rowptr[n+1];
  for(int j = jb; j < je; j++){
    const unsigned int* mp = (const unsigned int*)(msg + (size_t)j*H1C + q*4);
    unsigned int u0 = mp[0], u1 = mp[1];
    a0 += bf2f(u0); a1 += bf2f(u0 >> 16); a2 += bf2f(u1); a3 += bf2f(u1 >> 16);
  }
  const float* xr = xf + (size_t)n*FN;
  #pragma unroll
  for(int i = 0; i < FN; i++){
    float xi = xr[i];
    a0 += xi*s_w[i*H1C + q*4+0]; a1 += xi*s_w[i*H1C + q*4+1];
    a2 += xi*s_w[i*H1C + q*4+2]; a3 += xi*s_w[i*H1C + q*4+3];
  }
  a0 = a0>0.f?a0:0.f; a1 = a1>0.f?a1:0.f; a2 = a2>0.f?a2:0.f; a3 = a3>0.f?a3:0.f;
  uint2 hb; hb.x = pk2(a0, a1); hb.y = pk2(a2, a3);
  *(uint2*)(h1b + (size_t)n*H1C + q*4) = hb;
}

// h2 = relu(h1@wr2 + br2 + sum msg2 rows); 4 threads/node; h1 read as bf16
__global__ void __launch_bounds__(256) gather2_kernel(
    const unsigned short* __restrict__ h1b, const unsigned short* __restrict__ msg,
    const int* __restrict__ rowptr,
    const float* __restrict__ wr, const float* __restrict__ br, float* __restrict__ h2)
{
  __shared__ float s_w[H1C*H2C], s_b[H2C];
  for(int i = threadIdx.x; i < H1C*H2C; i += 256) s_w[i] = wr[i];
  if(threadIdx.x < H2C) s_b[threadIdx.x] = br[threadIdx.x];
  __syncthreads();
  int g = blockIdx.x*256 + threadIdx.x;
  int n = g >> 2, q = g & 3;
  if(n >= NN) return;
  float a0 = s_b[q*4+0], a1 = s_b[q*4+1], a2 = s_b[q*4+2], a3 = s_b[q*4+3];
  int jb = rowptr[n], je = rowptr[n+1];
  for(int j = jb; j < je; j++){
    const unsigned int* mp = (const unsigned int*)(msg + (size_t)j*H2C + q*4);
    unsigned int u0 = mp[0], u1 = mp[1];
    a0 += bf2f(u0); a1 += bf2f(u0 >> 16); a2 += bf2f(u1); a3 += bf2f(u1 >> 16);
  }
  const unsigned int* hb = (const unsigned int*)(h1b + (size_t)n*H1C);
  #pragma unroll
  for(int i2 = 0; i2 < H1C/2; i2++){
    unsigned int u = hb[i2];
    float x0 = bf2f(u), x1 = bf2f(u >> 16);
    int i = 2*i2;
    a0 += x0*s_w[i*H2C + q*4+0] + x1*s_w[(i+1)*H2C + q*4+0];
    a1 += x0*s_w[i*H2C + q*4+1] + x1*s_w[(i+1)*H2C + q*4+1];
    a2 += x0*s_w[i*H2C + q*4+2] + x1*s_w[(i+1)*H2C + q*4+2];
    a3 += x0*s_w[i*H2C + q*4+3] + x1*s_w[(i+1)*H2C + q*4+3];
  }
  float4 r; r.x = a0>0.f?a0:0.f; r.y = a1>0.f?a1:0.f; r.z = a2>0.f?a2:0.f; r.w = a3>0.f?a3:0.f;
  *(float4*)(h2 + (size_t)n*H2C + q*4) = r;
}

// one wave per graph: attention pool (gate softmax + weighted x) + mean-pool h2 + head MLP
__global__ void head_kernel(const float* __restrict__ gate, const float* __restrict__ xf,
    const float* __restrict__ h2, const int* __restrict__ batch,
    const float* __restrict__ wl1, const float* __restrict__ bl1,
    const float* __restrict__ wl2, const float* __restrict__ bl2,
    void* __restrict__ out, const int* __restrict__ flag)
{
  __shared__ float sz[H2C + FN];
  int g = blockIdx.x;
  int lane = threadIdx.x;
  int start = lower_bound_i(batch, NN, g);
  int end   = lower_bound_i(batch, NN, g + 1);
  // attention pool
  float m = -1e30f;
  for(int n = start + lane; n < end; n += 64) m = fmaxf(m, gate[n]);
  #pragma unroll
  for(int o = 32; o >= 1; o >>= 1) m = fmaxf(m, __shfl_xor(m, o));
  float s = 0.f;
  float acc[FN];
  #pragma unroll
  for(int f = 0; f < FN; f++) acc[f] = 0.f;
  for(int n = start + lane; n < end; n += 64){
    float a = __expf(gate[n] - m);
    s += a;
    const float4* xp = (const float4*)(xf + (size_t)n * FN);
    #pragma unroll
    for(int q = 0; q < 4; q++){
      float4 v = xp[q];
      acc[q*4+0] += a*v.x; acc[q*4+1] += a*v.y; acc[q*4+2] += a*v.z; acc[q*4+3] += a*v.w;
    }
  }
  #pragma unroll
  for(int o = 32; o >= 1; o >>= 1){
    s += __shfl_xor(s, o);
    #pragma unroll
    for(int f = 0; f < FN; f++) acc[f] += __shfl_xor(acc[f], o);
  }
  if(lane < FN) sz[H2C + lane] = (end > start && s > 0.f) ? acc[lane] / s : 0.f;
  // mean pool of h2 (reuse acc)
  #pragma unroll
  for(int f = 0; f < H2C; f++) acc[f] = 0.f;
  for(int n = start + lane; n < end; n += 64){
    const float4* hp = (const float4*)(h2 + (size_t)n*H2C);
    #pragma unroll
    for(int q = 0; q < 4; q++){
      float4 v = hp[q];
      acc[q*4+0] += v.x; acc[q*4+1] += v.y; acc[q*4+2] += v.z; acc[q*4+3] += v.w;
    }
  }
  #pragma unroll
  for(int o = 32; o >= 1; o >>= 1){
    #pragma unroll
    for(int f = 0; f < H2C; f++) acc[f] += __shfl_xor(acc[f], o);
  }
  float inv = 1.f / fmaxf((float)(end - start), 1.f);
  if(lane < H2C) sz[lane] = acc[lane] * inv;
  __syncthreads();
  if(lane == 0){
    float t1[8];
    #pragma unroll
    for(int j = 0; j < 8; j++){
      float t = bl1[j];
      #pragma unroll
      for(int c = 0; c < H2C + FN; c++) t += sz[c] * wl1[c*8 + j];
      t1[j] = t;
    }
    float o = bl2[0];
    #pragma unroll
    for(int j = 0; j < 8; j++) o += t1[j] * wl2[j];
    if((*flag) != 0) ((__hip_bfloat16*)out)[g] = __float2bfloat16(o);
    else             ((float*)out)[g] = o;
  }
}

extern "C" void kernel_launch(void* const* d_in, const int* in_sizes, int n_in,
                              void* d_out, int out_size, void* d_ws, size_t ws_size,
                              hipStream_t stream)
{
  const int* ei    = (const int*)d_in[22];
  const int* batch = (const int*)d_in[23];

  float* ws = (float*)d_ws;
  float* xf     = ws;                          // 1,600,000 f
  float* gate   = xf + 1600000;                //   100,000 f
  float* wts    = gate + 100000;               //    19,360 f
  int*   rowptr = (int*)(wts + 19360);         //   100,016 i
  int*   cursor = rowptr + 100016;             //   100,000 i
  int*   deg    = cursor + 100000;             //   100,000 i
  int*   bsum   = deg + 100000;                //       512 i
  int*   csr    = bsum + 512;                  //   200,000 i
  int*   srcp   = csr + 200000;                //   200,000 i
  int*   flagp  = srcp + 200000;               //        16 i
  unsigned int* wpack1 = (unsigned int*)(flagp + 16);   // 4,736 u32
  unsigned int* wpack2 = wpack1 + 4736;                 // 4,416 u32
  unsigned short* h1b  = (unsigned short*)(wpack2 + 4416);  // 3,200,000 u16 (6.4 MB)
  unsigned int* hpk1   = (unsigned int*)h1b;   // alias: [NE][8] u32, dead before gather1 writes h1b
  unsigned short* msg1 = h1b + 3200000;        // 6,400,000 u16 (12.8 MB)
  unsigned short* msg2 = msg1;                 // reuse after gather1
  float* h2     = (float*)(msg1 + 6400000);    // 1,600,000 f (6.4 MB)
  unsigned int* hpk2   = (unsigned int*)h2;    // alias: dead before gather2 writes h2
  // total ~35.4 MB

  WArgs wa;
  for(int i = 0; i < NW; i++) wa.p[i] = d_in[2 + i];

  detect_kernel<<<1, 256, 0, stream>>>(d_in[0], flagp);
  setup_small_kernel<<<(int)((SS3 + 255)/256), 256, 0, stream>>>(wa, flagp, wts, wpack1, wpack2, deg);
  gate_cvt_kernel<<<(NN + 255)/256, 256, 0, stream>>>(
      d_in[0], d_in[14], d_in[15], d_in[16], d_in[17], flagp, gate, xf);

  const int NB1 = (NN + 255)/256;  // 391
  histo_kernel<<<(NE + 255)/256, 256, 0, stream>>>(ei, deg);
  scan1_kernel<<<NB1, 256, 0, stream>>>(deg, bsum);
  scan2_kernel<<<1, 512, 0, stream>>>(bsum, NB1);
  scan3_kernel<<<NB1, 256, 0, stream>>>(deg, bsum, rowptr, cursor);
  fill_kernel<<<(NE + 255)/256, 256, 0, stream>>>(ei, cursor, csr, srcp);

  edge_all_kernel<<<(NE + 255)/256, 256, 0, stream>>>(d_in[1], wts, flagp, csr, hpk1, hpk2);

  conv_mfma_kernel<FN, H1C, false><<<NE/64, 256, 0, stream>>>(
      xf, hpk1, srcp, (const unsigned short*)wpack1, msg1);
  gather1_kernel<<<(NN*8 + 255)/256, 256, 0, stream>>>(xf, msg1, rowptr, wts+OW_R1, wts+OB_R1, h1b);

  conv_mfma_kernel<H1C, H2C, true><<<NE/64, 256, 0, stream>>>(
      h1b, hpk2, srcp, (const unsigned short*)wpack2, msg2);
  gather2_kernel<<<(NN*4 + 255)/256, 256, 0, stream>>>(h1b, msg2, rowptr, wts+OW_R2, wts+OB_R2, h2);

  head_kernel<<<NG, 64, 0, stream>>>(gate, xf, h2, batch,
      wts+OW_L1, wts+OB_L1, wts+OW_L2, wts+OB_L2, d_out, flagp);
}

// Round 11
// 218.677 us; speedup vs baseline: 3.2564x; 1.0581x over previous
//
#include <hip/hip_runtime.h>
#include <hip/hip_bf16.h>

#define NN 100000   // nodes
#define NE 200000   // edges
#define NG 2500     // graphs
#define FN 16       // node feats
#define FE 8        // edge feats
#define H1C 32
#define H2C 16
#define KH 16       // edge-MLP hidden

typedef __attribute__((ext_vector_type(8))) short short8;
typedef __attribute__((ext_vector_type(4))) float f32x4;

__device__ __forceinline__ float bf2f(unsigned int u){
  union { unsigned int i; float f; } v; v.i = (u & 0xffffu) << 16; return v.f;
}
__device__ __forceinline__ unsigned short f2bf(float f){
  union { float f; unsigned int i; } u; u.f = f;
  unsigned int r = u.i + 0x7fffu + ((u.i >> 16) & 1u);   // RNE, finite data
  return (unsigned short)(r >> 16);
}
__device__ __forceinline__ unsigned int pk2(float a, float b){
  return (unsigned int)f2bf(a) | ((unsigned int)f2bf(b) << 16);
}
__device__ __forceinline__ float rdf(const void* p, long i, bool isbf){
  return isbf ? bf2f(((const unsigned short*)p)[i]) : ((const float*)p)[i];
}
__device__ __forceinline__ int lower_bound_i(const int* __restrict__ a, int n, int v){
  int lo = 0, hi = n;
  while(lo < hi){ int mid = (lo + hi) >> 1; if(a[mid] < v) lo = mid + 1; else hi = mid; }
  return lo;
}
// inline dtype detection: wave-ballot over 64 sampled halfwords of x (deterministic,
// wave-uniform, identical decision across all kernels). bf16 N(0,1): ~64/64 sane;
// fp32 mantissa halfwords: ~7/64 sane -> threshold 32 is decisive.
__device__ __forceinline__ bool detect_isbf(const void* __restrict__ x){
  const unsigned short* u = (const unsigned short*)x;
  int lane = threadIdx.x & 63;
  float f = bf2f(u[2*lane]);
  float a = fabsf(f);
  bool sane = (f == 0.0f) || (a > 1e-4f && a < 1e4f);
  unsigned long long b = __ballot(sane);
  return __popcll(b) >= 32;
}

#define NW 20
struct WArgs { const void* p[NW]; };
enum {
  OW_E1A=0,     OB_E1A=128,   OW_E1B=144,   OB_E1B=8336,  OW_R1=8848,  OB_R1=9360,
  OW_E2A=9392,  OB_E2A=9520,  OW_E2B=9536,  OB_E2B=17728, OW_R2=18240, OB_R2=18752,
  OW_G1=18768,  OB_G1=19024,  OW_G2=19040,  OB_G2=19056,
  OW_L1=19057,  OB_L1=19313,  OW_L2=19321,  OB_L2=19329
};

// ---- mega setup: wts-cvt | wpack1 | wpack2 | gate+cvt | histo (block-segmented) ----
#define MB_A 76               // wts cvt: 19330 elems
#define MB_B (MB_A + 19)      // wpack1: 4736
#define MB_C (MB_B + 18)      // wpack2: 4416
#define MB_D (MB_C + 391)     // gate_cvt: NN
#define MB_E (MB_D + 782)     // histo: NE
__global__ void __launch_bounds__(256) mega1_kernel(
    const void* __restrict__ xin, const void* __restrict__ efin, WArgs w,
    const int* __restrict__ ei,
    float* __restrict__ wts, unsigned int* __restrict__ wpack1, unsigned int* __restrict__ wpack2,
    float* __restrict__ gate, float* __restrict__ xf, int* __restrict__ deg)
{
  int b = blockIdx.x, tid = threadIdx.x;
  if(b < MB_A){
    bool isbf = detect_isbf(xin);
    int i = b*256 + tid;
    if(i >= 19330) return;
    const int sz[NW] = {128,16,8192,512,512,32, 128,16,8192,512,512,16, 256,16,16,1, 256,8,8,1};
    int seg = 0; long base = 0;
    while(i - base >= sz[seg]){ base += sz[seg]; seg++; }
    wts[i] = rdf(w.p[seg], i - base, isbf);
    return;
  }
  if(b < MB_B){   // wpack1: 32 rows x 148 u32 (KP=296), round-7-verified layout
    bool isbf = detect_isbf(xin);
    int j = (b - MB_A)*256 + tid;
    if(j >= 4736) return;
    int n = j / 148; int k = (j % 148) * 2;
    float v0 = 0.f, v1 = 0.f;
    if(k < 256)        v0 = rdf(w.p[2], (long)k*32 + n, isbf);
    else if(k < 272)   v0 = rdf(w.p[3], (long)(k-256)*32 + n, isbf);
    if(k+1 < 256)      v1 = rdf(w.p[2], (long)(k+1)*32 + n, isbf);
    else if(k+1 < 272) v1 = rdf(w.p[3], (long)(k+1-256)*32 + n, isbf);
    wpack1[j] = pk2(v0, v1);
    return;
  }
  if(b < MB_C){   // wpack2: 16 rows x 276 u32 (KP=552)
    bool isbf = detect_isbf(xin);
    int j = (b - MB_B)*256 + tid;
    if(j >= 4416) return;
    int n = j / 276; int k = (j % 276) * 2;
    float v0 = 0.f, v1 = 0.f;
    if(k < 512)        v0 = rdf(w.p[8], (long)k*16 + n, isbf);
    else if(k < 544)   v0 = rdf(w.p[9], (long)(k-512)*16 + n, isbf);
    if(k+1 < 512)      v1 = rdf(w.p[8], (long)(k+1)*16 + n, isbf);
    else if(k+1 < 544) v1 = rdf(w.p[9], (long)(k+1-512)*16 + n, isbf);
    wpack2[j] = pk2(v0, v1);
    return;
  }
  if(b < MB_D){   // gate MLP + x conversion (one pass over raw x)
    __shared__ float s_w1[FN*FN], s_b1[FN], s_w2[FN], s_b2v[1];
    bool isbf = detect_isbf(xin);
    if(tid < FN*FN) s_w1[tid] = rdf(w.p[12], tid, isbf);
    if(tid < FN){ s_b1[tid] = rdf(w.p[13], tid, isbf); s_w2[tid] = rdf(w.p[14], tid, isbf); }
    if(tid == 0) s_b2v[0] = rdf(w.p[15], 0, isbf);
    __syncthreads();
    int n = (b - MB_C)*256 + tid;
    if(n >= NN) return;
    float xv[FN];
    if(isbf){
      uint4 u0 = ((const uint4*)xin)[2*n], u1 = ((const uint4*)xin)[2*n+1];
      xv[0]=bf2f(u0.x); xv[1]=bf2f(u0.x>>16); xv[2]=bf2f(u0.y); xv[3]=bf2f(u0.y>>16);
      xv[4]=bf2f(u0.z); xv[5]=bf2f(u0.z>>16); xv[6]=bf2f(u0.w); xv[7]=bf2f(u0.w>>16);
      xv[8]=bf2f(u1.x); xv[9]=bf2f(u1.x>>16); xv[10]=bf2f(u1.y); xv[11]=bf2f(u1.y>>16);
      xv[12]=bf2f(u1.z); xv[13]=bf2f(u1.z>>16); xv[14]=bf2f(u1.w); xv[15]=bf2f(u1.w>>16);
    } else {
      #pragma unroll
      for(int q = 0; q < 4; q++){
        float4 v = ((const float4*)xin)[4*n + q];
        xv[q*4+0]=v.x; xv[q*4+1]=v.y; xv[q*4+2]=v.z; xv[q*4+3]=v.w;
      }
    }
    float4* xo = (float4*)(xf + (size_t)n*FN);
    #pragma unroll
    for(int q = 0; q < 4; q++) xo[q] = make_float4(xv[q*4+0], xv[q*4+1], xv[q*4+2], xv[q*4+3]);
    float g = s_b2v[0];
    #pragma unroll
    for(int j = 0; j < FN; j++){
      float hj = s_b1[j];
      #pragma unroll
      for(int i = 0; i < FN; i++) hj += xv[i] * s_w1[i*FN + j];
      hj = hj > 0.f ? hj : 0.f;
      g += hj * s_w2[j];
    }
    gate[n] = g;
    return;
  }
  {   // histogram of edge targets (deg pre-zeroed by memset)
    int e = (b - MB_D)*256 + tid;
    if(e < NE) atomicAdd(&deg[ei[NE + e]], 1);
  }
}

// ---- single-launch exclusive scan (decoupled lookback; 98 blocks all co-resident) ----
// pub[b] = (value<<2)|state; state 1=aggregate, 2=inclusive prefix. Device-scope atomics.
__global__ void __launch_bounds__(256) scan_kernel(
    const int* __restrict__ deg, int* __restrict__ rowptr, int* __restrict__ cursor,
    unsigned long long* __restrict__ pub)
{
  __shared__ int s_thr[256];
  __shared__ int s_bcast;
  int tid = threadIdx.x, bid = blockIdx.x;
  int base = bid*1024 + tid*4;
  int v0=0, v1=0, v2=0, v3=0;
  if(base + 3 < NN){
    int4 t4 = *(const int4*)(deg + base);
    v0=t4.x; v1=t4.y; v2=t4.z; v3=t4.w;
  } else {
    if(base+0 < NN) v0 = deg[base+0];
    if(base+1 < NN) v1 = deg[base+1];
    if(base+2 < NN) v2 = deg[base+2];
  }
  int e1 = v0, e2 = v0+v1, e3 = v0+v1+v2, tot = v0+v1+v2+v3;
  s_thr[tid] = tot;
  __syncthreads();
  for(int off = 1; off < 256; off <<= 1){
    int t = (tid >= off) ? s_thr[tid-off] : 0;
    __syncthreads();
    s_thr[tid] += t;
    __syncthreads();
  }
  int thr_excl = s_thr[tid] - tot;
  int agg = s_thr[255];
  if(tid == 0){
    if(bid == 0){
      atomicExch(&pub[0], ((unsigned long long)agg << 2) | 2ULL);
      s_bcast = 0;
    } else {
      atomicExch(&pub[bid], ((unsigned long long)agg << 2) | 1ULL);
      int acc = 0, p = bid - 1;
      while(true){
        unsigned long long got;
        do { got = atomicAdd(&pub[p], 0ULL); } while((got & 3ULL) == 0ULL);
        acc += (int)(got >> 2);
        if((got & 3ULL) == 2ULL) break;
        p--;
      }
      atomicExch(&pub[bid], ((unsigned long long)(acc + agg) << 2) | 2ULL);
      s_bcast = acc;
    }
  }
  __syncthreads();
  int ex = s_bcast + thr_excl;
  if(base + 3 < NN){
    int4 r = make_int4(ex, ex+e1, ex+e2, ex+e3);
    *(int4*)(rowptr + base) = r;
    *(int4*)(cursor + base) = r;
  } else {
    if(base+0 < NN){ rowptr[base+0]=ex;    cursor[base+0]=ex;    }
    if(base+1 < NN){ rowptr[base+1]=ex+e1; cursor[base+1]=ex+e1; }
    if(base+2 < NN){ rowptr[base+2]=ex+e2; cursor[base+2]=ex+e2; }
  }
  if(bid == 0 && tid == 0) rowptr[NN] = NE;
}

// ---- fill + edge-MLP fused: counting-sort placement computes both conv MLPs in-place ----
// reads ef COALESCED (by edge id), writes srcp/hpk1/hpk2 at CSR position (scattered writes).
__global__ void __launch_bounds__(256) fill_edge_kernel(
    const int* __restrict__ ei, int* __restrict__ cursor,
    const void* __restrict__ efin, const float* __restrict__ wts, const void* __restrict__ xin,
    int* __restrict__ srcp, unsigned int* __restrict__ hpk1, unsigned int* __restrict__ hpk2)
{
  __shared__ float s_w1[FE*KH], s_b1[KH], s_w2[FE*KH], s_b2[KH];
  int tid = threadIdx.x;
  if(tid < FE*KH){ s_w1[tid] = wts[OW_E1A + tid]; s_w2[tid] = wts[OW_E2A + tid]; }
  if(tid < KH){ s_b1[tid] = wts[OB_E1A + tid]; s_b2[tid] = wts[OB_E2A + tid]; }
  bool isbf = detect_isbf(xin);
  __syncthreads();
  int e = blockIdx.x*256 + tid;
  if(e >= NE) return;
  int pos = atomicAdd(&cursor[ei[NE + e]], 1);
  srcp[pos] = ei[e];
  float ev[FE];
  if(isbf){
    uint4 u = ((const uint4*)efin)[e];
    ev[0]=bf2f(u.x); ev[1]=bf2f(u.x>>16); ev[2]=bf2f(u.y); ev[3]=bf2f(u.y>>16);
    ev[4]=bf2f(u.z); ev[5]=bf2f(u.z>>16); ev[6]=bf2f(u.w); ev[7]=bf2f(u.w>>16);
  } else {
    float4 a = ((const float4*)efin)[2*e], b = ((const float4*)efin)[2*e+1];
    ev[0]=a.x; ev[1]=a.y; ev[2]=a.z; ev[3]=a.w; ev[4]=b.x; ev[5]=b.y; ev[6]=b.z; ev[7]=b.w;
  }
  unsigned int o[8];
  #pragma unroll
  for(int d = 0; d < 8; d++){
    float h0 = s_b1[2*d], h1 = s_b1[2*d+1];
    #pragma unroll
    for(int k = 0; k < FE; k++){
      h0 += ev[k] * s_w1[k*KH + 2*d];
      h1 += ev[k] * s_w1[k*KH + 2*d+1];
    }
    h0 = h0 > 0.f ? h0 : 0.f; h1 = h1 > 0.f ? h1 : 0.f;
    o[d] = pk2(h0, h1);
  }
  uint4* p1 = (uint4*)(hpk1 + (size_t)pos*8);
  p1[0] = make_uint4(o[0],o[1],o[2],o[3]); p1[1] = make_uint4(o[4],o[5],o[6],o[7]);
  #pragma unroll
  for(int d = 0; d < 8; d++){
    float h0 = s_b2[2*d], h1 = s_b2[2*d+1];
    #pragma unroll
    for(int k = 0; k < FE; k++){
      h0 += ev[k] * s_w2[k*KH + 2*d];
      h1 += ev[k] * s_w2[k*KH + 2*d+1];
    }
    h0 = h0 > 0.f ? h0 : 0.f; h1 = h1 > 0.f ? h1 : 0.f;
    o[d] = pk2(h0, h1);
  }
  uint4* p2 = (uint4*)(hpk2 + (size_t)pos*8);
  p2[0] = make_uint4(o[0],o[1],o[2],o[3]); p2[1] = make_uint4(o[4],o[5],o[6],o[7]);
}

// ---- NNConv message GEMM, register-built A-fragments (round-9-verified math) ----
template<int IN, int OUT, bool ABF>
__global__ void __launch_bounds__(256) conv_mfma_kernel(
    const void* __restrict__ nodef, const unsigned int* __restrict__ hpk,
    const int* __restrict__ srcp, const unsigned short* __restrict__ wpack,
    unsigned short* __restrict__ msg)
{
  constexpr int KMF  = ((KH*IN + IN + 31)/32)*32;   // 288 | 544
  constexpr int KP   = KMF + 8;                     // 296 | 552
  constexpr int NT   = OUT/16;                      // 2 | 1
  constexpr int KS   = KMF/32;                      // 9 | 17
  int tid = threadIdx.x;
  int lane = tid & 63, m = lane & 15, quad = lane >> 4;
  int wid = tid >> 6;
  int ebase = blockIdx.x*64 + wid*16;               // grid = NE/64 exactly
  int em = ebase + m;
  int sn = srcp[em];
  int q1 = quad >> 1;
  int xoff = (IN == 16) ? ((quad & 1)*8) : (quad*8);
  float x8[8];
  short8 xb;
  if(ABF){
    uint4 u = *(const uint4*)((const unsigned short*)nodef + (size_t)sn*IN + xoff);
    unsigned int uu[4] = {u.x, u.y, u.z, u.w};
    #pragma unroll
    for(int k = 0; k < 4; k++){ x8[2*k] = bf2f(uu[k]); x8[2*k+1] = bf2f(uu[k] >> 16); }
    xb = *(short8*)&u;
  } else {
    const float4* xp = (const float4*)((const float*)nodef + (size_t)sn*IN + xoff);
    float4 v0 = xp[0], v1 = xp[1];
    x8[0]=v0.x; x8[1]=v0.y; x8[2]=v0.z; x8[3]=v0.w;
    x8[4]=v1.x; x8[5]=v1.y; x8[6]=v1.z; x8[7]=v1.w;
    unsigned int* xbp = (unsigned int*)&xb;
    #pragma unroll
    for(int k = 0; k < 4; k++) xbp[k] = pk2(x8[2*k], x8[2*k+1]);
  }
  unsigned int hu[8];
  {
    const uint4* hp = (const uint4*)(hpk + (size_t)em*8);
    uint4 u0 = hp[0], u1 = hp[1];
    hu[0]=u0.x; hu[1]=u0.y; hu[2]=u0.z; hu[3]=u0.w;
    hu[4]=u1.x; hu[5]=u1.y; hu[6]=u1.z; hu[7]=u1.w;
  }

  f32x4 acc[NT];
  #pragma unroll
  for(int nt = 0; nt < NT; nt++) acc[nt] = (f32x4){0.f,0.f,0.f,0.f};

  #pragma unroll
  for(int ks = 0; ks < KS; ks++){
    short8 a;
    if(ks < KS-1){
      float hv = (IN == 16) ? bf2f(hu[ks] >> (16*q1))
                            : bf2f(hu[ks >> 1] >> (16*(ks & 1)));
      unsigned int* ap = (unsigned int*)&a;
      #pragma unroll
      for(int k = 0; k < 4; k++) ap[k] = pk2(hv*x8[2*k], hv*x8[2*k+1]);
    } else {
      if(IN == 16) a = (quad < 2) ? xb : (short8){0,0,0,0,0,0,0,0};
      else         a = xb;
    }
    #pragma unroll
    for(int nt = 0; nt < NT; nt++){
      short8 b = *(const short8*)(wpack + (size_t)(nt*16 + m)*KP + ks*32 + quad*8);
      acc[nt] = __builtin_amdgcn_mfma_f32_16x16x32_bf16(a, b, acc[nt], 0, 0, 0);
    }
  }
  #pragma unroll
  for(int nt = 0; nt < NT; nt++)
    #pragma unroll
    for(int r = 0; r < 4; r++)   // C layout: row=(lane>>4)*4+reg (edge), col=lane&15
      msg[(size_t)(ebase + quad*4 + r)*OUT + nt*16 + m] = f2bf(acc[nt][r]);
}

// h1 = relu(x@wr1 + br1 + sum msg rows) -> bf16. 8 threads/node; msg streaming.
__global__ void __launch_bounds__(256) gather1_kernel(
    const float* __restrict__ xf, const unsigned short* __restrict__ msg,
    const int* __restrict__ rowptr,
    const float* __restrict__ wr, const float* __restrict__ br,
    unsigned short* __restrict__ h1b)
{
  __shared__ float s_w[FN*H1C], s_b[H1C];
  for(int i = threadIdx.x; i < FN*H1C; i += 256) s_w[i] = wr[i];
  if(threadIdx.x < H1C) s_b[threadIdx.x] = br[threadIdx.x];
  __syncthreads();
  int g = blockIdx.x*256 + threadIdx.x;
  int n = g >> 3, q = g & 7;
  if(n >= NN) return;
  float a0 = s_b[q*4+0], a1 = s_b[q*4+1], a2 = s_b[q*4+2], a3 = s_b[q*4+3];
  int jb = rowptr[n], je = rowptr[n+1];
  for(int j = jb; j < je; j++){
    const unsigned int* mp = (const unsigned int*)(msg + (size_t)j*H1C + q*4);
    unsigned int u0 = mp[0], u1 = mp[1];
    a0 += bf2f(u0); a1 += bf2f(u0 >> 16); a2 += bf2f(u1); a3 += bf2f(u1 >> 16);
  }
  const float* xr = xf + (size_t)n*FN;
  #pragma unroll
  for(int i = 0; i < FN; i++){
    float xi = xr[i];
    a0 += xi*s_w[i*H1C + q*4+0]; a1 += xi*s_w[i*H1C + q*4+1];
    a2 += xi*s_w[i*H1C + q*4+2]; a3 += xi*s_w[i*H1C + q*4+3];
  }
  a0 = a0>0.f?a0:0.f; a1 = a1>0.f?a1:0.f; a2 = a2>0.f?a2:0.f; a3 = a3>0.f?a3:0.f;
  uint2 hb; hb.x = pk2(a0, a1); hb.y = pk2(a2, a3);
  *(uint2*)(h1b + (size_t)n*H1C + q*4) = hb;
}

// h2 = relu(h1@wr2 + br2 + sum msg2 rows); 4 threads/node; h1 read as bf16
__global__ void __launch_bounds__(256) gather2_kernel(
    const unsigned short* __restrict__ h1b, const unsigned short* __restrict__ msg,
    const int* __restrict__ rowptr,
    const float* __restrict__ wr, const float* __restrict__ br, float* __restrict__ h2)
{
  __shared__ float s_w[H1C*H2C], s_b[H2C];
  for(int i = threadIdx.x; i < H1C*H2C; i += 256) s_w[i] = wr[i];
  if(threadIdx.x < H2C) s_b[threadIdx.x] = br[threadIdx.x];
  __syncthreads();
  int g = blockIdx.x*256 + threadIdx.x;
  int n = g >> 2, q = g & 3;
  if(n >= NN) return;
  float a0 = s_b[q*4+0], a1 = s_b[q*4+1], a2 = s_b[q*4+2], a3 = s_b[q*4+3];
  int jb = rowptr[n], je = rowptr[n+1];
  for(int j = jb; j < je; j++){
    const unsigned int* mp = (const unsigned int*)(msg + (size_t)j*H2C + q*4);
    unsigned int u0 = mp[0], u1 = mp[1];
    a0 += bf2f(u0); a1 += bf2f(u0 >> 16); a2 += bf2f(u1); a3 += bf2f(u1 >> 16);
  }
  const unsigned int* hb = (const unsigned int*)(h1b + (size_t)n*H1C);
  #pragma unroll
  for(int i2 = 0; i2 < H1C/2; i2++){
    unsigned int u = hb[i2];
    float x0 = bf2f(u), x1 = bf2f(u >> 16);
    int i = 2*i2;
    a0 += x0*s_w[i*H2C + q*4+0] + x1*s_w[(i+1)*H2C + q*4+0];
    a1 += x0*s_w[i*H2C + q*4+1] + x1*s_w[(i+1)*H2C + q*4+1];
    a2 += x0*s_w[i*H2C + q*4+2] + x1*s_w[(i+1)*H2C + q*4+2];
    a3 += x0*s_w[i*H2C + q*4+3] + x1*s_w[(i+1)*H2C + q*4+3];
  }
  float4 r; r.x = a0>0.f?a0:0.f; r.y = a1>0.f?a1:0.f; r.z = a2>0.f?a2:0.f; r.w = a3>0.f?a3:0.f;
  *(float4*)(h2 + (size_t)n*H2C + q*4) = r;
}

// one wave per graph: attention pool + mean-pool h2 + head MLP
__global__ void head_kernel(const float* __restrict__ gate, const float* __restrict__ xf,
    const float* __restrict__ h2, const int* __restrict__ batch, const void* __restrict__ xin,
    const float* __restrict__ wl1, const float* __restrict__ bl1,
    const float* __restrict__ wl2, const float* __restrict__ bl2,
    void* __restrict__ out)
{
  __shared__ float sz[H2C + FN];
  int g = blockIdx.x;
  int lane = threadIdx.x;
  bool isbf = detect_isbf(xin);
  int start = lower_bound_i(batch, NN, g);
  int end   = lower_bound_i(batch, NN, g + 1);
  float m = -1e30f;
  for(int n = start + lane; n < end; n += 64) m = fmaxf(m, gate[n]);
  #pragma unroll
  for(int o = 32; o >= 1; o >>= 1) m = fmaxf(m, __shfl_xor(m, o));
  float s = 0.f;
  float acc[FN];
  #pragma unroll
  for(int f = 0; f < FN; f++) acc[f] = 0.f;
  for(int n = start + lane; n < end; n += 64){
    float a = __expf(gate[n] - m);
    s += a;
    const float4* xp = (const float4*)(xf + (size_t)n * FN);
    #pragma unroll
    for(int q = 0; q < 4; q++){
      float4 v = xp[q];
      acc[q*4+0] += a*v.x; acc[q*4+1] += a*v.y; acc[q*4+2] += a*v.z; acc[q*4+3] += a*v.w;
    }
  }
  #pragma unroll
  for(int o = 32; o >= 1; o >>= 1){
    s += __shfl_xor(s, o);
    #pragma unroll
    for(int f = 0; f < FN; f++) acc[f] += __shfl_xor(acc[f], o);
  }
  if(lane < FN) sz[H2C + lane] = (end > start && s > 0.f) ? acc[lane] / s : 0.f;
  #pragma unroll
  for(int f = 0; f < H2C; f++) acc[f] = 0.f;
  for(int n = start + lane; n < end; n += 64){
    const float4* hp = (const float4*)(h2 + (size_t)n*H2C);
    #pragma unroll
    for(int q = 0; q < 4; q++){
      float4 v = hp[q];
      acc[q*4+0] += v.x; acc[q*4+1] += v.y; acc[q*4+2] += v.z; acc[q*4+3] += v.w;
    }
  }
  #pragma unroll
  for(int o = 32; o >= 1; o >>= 1){
    #pragma unroll
    for(int f = 0; f < H2C; f++) acc[f] += __shfl_xor(acc[f], o);
  }
  float inv = 1.f / fmaxf((float)(end - start), 1.f);
  if(lane < H2C) sz[lane] = acc[lane] * inv;
  __syncthreads();
  if(lane == 0){
    float t1[8];
    #pragma unroll
    for(int j = 0; j < 8; j++){
      float t = bl1[j];
      #pragma unroll
      for(int c = 0; c < H2C + FN; c++) t += sz[c] * wl1[c*8 + j];
      t1[j] = t;
    }
    float o = bl2[0];
    #pragma unroll
    for(int j = 0; j < 8; j++) o += t1[j] * wl2[j];
    if(isbf) ((__hip_bfloat16*)out)[g] = __float2bfloat16(o);
    else     ((float*)out)[g] = o;
  }
}

extern "C" void kernel_launch(void* const* d_in, const int* in_sizes, int n_in,
                              void* d_out, int out_size, void* d_ws, size_t ws_size,
                              hipStream_t stream)
{
  const int* ei    = (const int*)d_in[22];
  const int* batch = (const int*)d_in[23];

  float* ws = (float*)d_ws;
  float* xf     = ws;                          // 1,600,000 f
  float* gate   = xf + 1600000;                //   100,000 f
  float* wts    = gate + 100000;               //    19,360 f
  int*   rowptr = (int*)(wts + 19360);         //   100,016 i
  int*   cursor = rowptr + 100016;             //   100,000 i
  int*   deg    = cursor + 100000;             //   100,000 i
  unsigned long long* pub = (unsigned long long*)(deg + 100000);  // 128 ull (256 i)
  int*   srcp   = (int*)(pub + 128);           //   200,000 i
  unsigned int* wpack1 = (unsigned int*)(srcp + 200000);   // 4,736 u32
  unsigned int* wpack2 = wpack1 + 4736;                    // 4,416 u32
  unsigned short* h1b  = (unsigned short*)(wpack2 + 4416); // 3,200,000 u16 (6.4 MB)
  unsigned int* hpk1   = (unsigned int*)h1b;   // alias: [NE][8] u32, dead before gather1
  unsigned short* msg1 = h1b + 3200000;        // 6,400,000 u16 (12.8 MB)
  unsigned short* msg2 = msg1;                 // reuse after gather1
  float* h2     = (float*)(msg1 + 6400000);    // 1,600,000 f
  unsigned int* hpk2   = (unsigned int*)h2;    // alias: dead before gather2
  // total ~35 MB

  WArgs wa;
  for(int i = 0; i < NW; i++) wa.p[i] = d_in[2 + i];

  hipMemsetAsync(deg, 0, (100000 + 256)*sizeof(int), stream);   // deg + pub states
  mega1_kernel<<<MB_E, 256, 0, stream>>>(d_in[0], d_in[1], wa, ei, wts, wpack1, wpack2, gate, xf, deg);
  scan_kernel<<<98, 256, 0, stream>>>(deg, rowptr, cursor, pub);
  fill_edge_kernel<<<(NE + 255)/256, 256, 0, stream>>>(ei, cursor, d_in[1], wts, d_in[0], srcp, hpk1, hpk2);

  conv_mfma_kernel<FN, H1C, false><<<NE/64, 256, 0, stream>>>(
      xf, hpk1, srcp, (const unsigned short*)wpack1, msg1);
  gather1_kernel<<<(NN*8 + 255)/256, 256, 0, stream>>>(xf, msg1, rowptr, wts+OW_R1, wts+OB_R1, h1b);

  conv_mfma_kernel<H1C, H2C, true><<<NE/64, 256, 0, stream>>>(
      h1b, hpk2, srcp, (const unsigned short*)wpack2, msg2);
  gather2_kernel<<<(NN*4 + 255)/256, 256, 0, stream>>>(h1b, msg2, rowptr, wts+OW_R2, wts+OB_R2, h2);

  head_kernel<<<NG, 64, 0, stream>>>(gate, xf, h2, batch, d_in[0],
      wts+OW_L1, wts+OB_L1, wts+OW_L2, wts+OB_L2, d_out);
}

// Round 12
// 212.291 us; speedup vs baseline: 3.3544x; 1.0301x over previous
//
#include <hip/hip_runtime.h>
#include <hip/hip_bf16.h>

#define NN 100000   // nodes
#define NE 200000   // edges
#define NG 2500     // graphs
#define FN 16       // node feats
#define FE 8        // edge feats
#define H1C 32
#define H2C 16
#define KH 16       // edge-MLP hidden

typedef __attribute__((ext_vector_type(8))) short short8;
typedef __attribute__((ext_vector_type(4))) float f32x4;

__device__ __forceinline__ float bf2f(unsigned int u){
  union { unsigned int i; float f; } v; v.i = (u & 0xffffu) << 16; return v.f;
}
__device__ __forceinline__ unsigned short f2bf(float f){
  union { float f; unsigned int i; } u; u.f = f;
  unsigned int r = u.i + 0x7fffu + ((u.i >> 16) & 1u);   // RNE, finite data
  return (unsigned short)(r >> 16);
}
__device__ __forceinline__ unsigned int pk2(float a, float b){
  return (unsigned int)f2bf(a) | ((unsigned int)f2bf(b) << 16);
}
__device__ __forceinline__ float rdf(const void* p, long i, bool isbf){
  return isbf ? bf2f(((const unsigned short*)p)[i]) : ((const float*)p)[i];
}
__device__ __forceinline__ int lower_bound_i(const int* __restrict__ a, int n, int v){
  int lo = 0, hi = n;
  while(lo < hi){ int mid = (lo + hi) >> 1; if(a[mid] < v) lo = mid + 1; else hi = mid; }
  return lo;
}
// inline dtype detection: wave-ballot over 64 sampled halfwords of x (deterministic,
// wave-uniform, identical decision across all kernels).
__device__ __forceinline__ bool detect_isbf(const void* __restrict__ x){
  const unsigned short* u = (const unsigned short*)x;
  int lane = threadIdx.x & 63;
  float f = bf2f(u[2*lane]);
  float a = fabsf(f);
  bool sane = (f == 0.0f) || (a > 1e-4f && a < 1e4f);
  unsigned long long b = __ballot(sane);
  return __popcll(b) >= 32;
}

#define NW 20
struct WArgs { const void* p[NW]; };
enum {
  OW_E1A=0,     OB_E1A=128,   OW_E1B=144,   OB_E1B=8336,  OW_R1=8848,  OB_R1=9360,
  OW_E2A=9392,  OB_E2A=9520,  OW_E2B=9536,  OB_E2B=17728, OW_R2=18240, OB_R2=18752,
  OW_G1=18768,  OB_G1=19024,  OW_G2=19040,  OB_G2=19056,
  OW_L1=19057,  OB_L1=19313,  OW_L2=19321,  OB_L2=19329
};

// ---- mega setup: wts-cvt | wpack1 | wpack2 | gate+cvt | histo (block-segmented) ----
#define MB_A 76               // wts cvt: 19330 elems
#define MB_B (MB_A + 19)      // wpack1: 4736
#define MB_C (MB_B + 18)      // wpack2: 4416
#define MB_D (MB_C + 391)     // gate_cvt: NN
#define MB_E (MB_D + 782)     // histo: NE
__global__ void __launch_bounds__(256) mega1_kernel(
    const void* __restrict__ xin, const void* __restrict__ efin, WArgs w,
    const int* __restrict__ ei,
    float* __restrict__ wts, unsigned int* __restrict__ wpack1, unsigned int* __restrict__ wpack2,
    float* __restrict__ gate, float* __restrict__ xf, int* __restrict__ deg)
{
  int b = blockIdx.x, tid = threadIdx.x;
  if(b < MB_A){
    bool isbf = detect_isbf(xin);
    int i = b*256 + tid;
    if(i >= 19330) return;
    const int sz[NW] = {128,16,8192,512,512,32, 128,16,8192,512,512,16, 256,16,16,1, 256,8,8,1};
    int seg = 0; long base = 0;
    while(i - base >= sz[seg]){ base += sz[seg]; seg++; }
    wts[i] = rdf(w.p[seg], i - base, isbf);
    return;
  }
  if(b < MB_B){   // wpack1: 32 rows x 148 u32 (KP=296), round-7-verified layout
    bool isbf = detect_isbf(xin);
    int j = (b - MB_A)*256 + tid;
    if(j >= 4736) return;
    int n = j / 148; int k = (j % 148) * 2;
    float v0 = 0.f, v1 = 0.f;
    if(k < 256)        v0 = rdf(w.p[2], (long)k*32 + n, isbf);
    else if(k < 272)   v0 = rdf(w.p[3], (long)(k-256)*32 + n, isbf);
    if(k+1 < 256)      v1 = rdf(w.p[2], (long)(k+1)*32 + n, isbf);
    else if(k+1 < 272) v1 = rdf(w.p[3], (long)(k+1-256)*32 + n, isbf);
    wpack1[j] = pk2(v0, v1);
    return;
  }
  if(b < MB_C){   // wpack2: 16 rows x 276 u32 (KP=552)
    bool isbf = detect_isbf(xin);
    int j = (b - MB_B)*256 + tid;
    if(j >= 4416) return;
    int n = j / 276; int k = (j % 276) * 2;
    float v0 = 0.f, v1 = 0.f;
    if(k < 512)        v0 = rdf(w.p[8], (long)k*16 + n, isbf);
    else if(k < 544)   v0 = rdf(w.p[9], (long)(k-512)*16 + n, isbf);
    if(k+1 < 512)      v1 = rdf(w.p[8], (long)(k+1)*16 + n, isbf);
    else if(k+1 < 544) v1 = rdf(w.p[9], (long)(k+1-512)*16 + n, isbf);
    wpack2[j] = pk2(v0, v1);
    return;
  }
  if(b < MB_D){   // gate MLP + x conversion (one pass over raw x)
    __shared__ float s_w1[FN*FN], s_b1[FN], s_w2[FN], s_b2v[1];
    bool isbf = detect_isbf(xin);
    if(tid < FN*FN) s_w1[tid] = rdf(w.p[12], tid, isbf);
    if(tid < FN){ s_b1[tid] = rdf(w.p[13], tid, isbf); s_w2[tid] = rdf(w.p[14], tid, isbf); }
    if(tid == 0) s_b2v[0] = rdf(w.p[15], 0, isbf);
    __syncthreads();
    int n = (b - MB_C)*256 + tid;
    if(n >= NN) return;
    float xv[FN];
    if(isbf){
      uint4 u0 = ((const uint4*)xin)[2*n], u1 = ((const uint4*)xin)[2*n+1];
      xv[0]=bf2f(u0.x); xv[1]=bf2f(u0.x>>16); xv[2]=bf2f(u0.y); xv[3]=bf2f(u0.y>>16);
      xv[4]=bf2f(u0.z); xv[5]=bf2f(u0.z>>16); xv[6]=bf2f(u0.w); xv[7]=bf2f(u0.w>>16);
      xv[8]=bf2f(u1.x); xv[9]=bf2f(u1.x>>16); xv[10]=bf2f(u1.y); xv[11]=bf2f(u1.y>>16);
      xv[12]=bf2f(u1.z); xv[13]=bf2f(u1.z>>16); xv[14]=bf2f(u1.w); xv[15]=bf2f(u1.w>>16);
    } else {
      #pragma unroll
      for(int q = 0; q < 4; q++){
        float4 v = ((const float4*)xin)[4*n + q];
        xv[q*4+0]=v.x; xv[q*4+1]=v.y; xv[q*4+2]=v.z; xv[q*4+3]=v.w;
      }
    }
    float4* xo = (float4*)(xf + (size_t)n*FN);
    #pragma unroll
    for(int q = 0; q < 4; q++) xo[q] = make_float4(xv[q*4+0], xv[q*4+1], xv[q*4+2], xv[q*4+3]);
    float g = s_b2v[0];
    #pragma unroll
    for(int j = 0; j < FN; j++){
      float hj = s_b1[j];
      #pragma unroll
      for(int i = 0; i < FN; i++) hj += xv[i] * s_w1[i*FN + j];
      hj = hj > 0.f ? hj : 0.f;
      g += hj * s_w2[j];
    }
    gate[n] = g;
    return;
  }
  {   // histogram of edge targets (deg pre-zeroed by memset)
    int e = (b - MB_D)*256 + tid;
    if(e < NE) atomicAdd(&deg[ei[NE + e]], 1);
  }
}

// ---- single-launch exclusive scan: publish aggregate, PARALLEL poll (98 co-resident blocks) ----
// pub[b] = (agg<<1)|1 published once per block; every block's threads tid<98 poll one entry
// each in parallel, then one lane sums predecessors from LDS. Critical path: 1 publish + 1 poll.
#define SCAN_NB 98
__global__ void __launch_bounds__(256) scan_kernel(
    const int* __restrict__ deg, int* __restrict__ rowptr, int* __restrict__ cursor,
    unsigned int* __restrict__ pub)
{
  __shared__ int s_thr[256];
  __shared__ int s_agg[SCAN_NB];
  __shared__ int s_bcast;
  int tid = threadIdx.x, bid = blockIdx.x;
  int base = bid*1024 + tid*4;
  int v0=0, v1=0, v2=0, v3=0;
  if(base + 3 < NN){
    int4 t4 = *(const int4*)(deg + base);
    v0=t4.x; v1=t4.y; v2=t4.z; v3=t4.w;
  } else {
    if(base+0 < NN) v0 = deg[base+0];
    if(base+1 < NN) v1 = deg[base+1];
    if(base+2 < NN) v2 = deg[base+2];
  }
  int e1 = v0, e2 = v0+v1, e3 = v0+v1+v2, tot = v0+v1+v2+v3;
  s_thr[tid] = tot;
  __syncthreads();
  for(int off = 1; off < 256; off <<= 1){
    int t = (tid >= off) ? s_thr[tid-off] : 0;
    __syncthreads();
    s_thr[tid] += t;
    __syncthreads();
  }
  int thr_excl = s_thr[tid] - tot;
  int agg = s_thr[255];
  if(tid == 0) atomicExch(&pub[bid], ((unsigned int)agg << 1) | 1u);   // device-scope publish
  if(tid < SCAN_NB){
    unsigned int v;
    do { v = atomicAdd(&pub[tid], 0u); } while((v & 1u) == 0u);        // parallel poll
    s_agg[tid] = (int)(v >> 1);
  }
  __syncthreads();
  if(tid == 0){
    int acc = 0;
    for(int p = 0; p < bid; p++) acc += s_agg[p];
    s_bcast = acc;
  }
  __syncthreads();
  int ex = s_bcast + thr_excl;
  if(base + 3 < NN){
    int4 r = make_int4(ex, ex+e1, ex+e2, ex+e3);
    *(int4*)(rowptr + base) = r;
    *(int4*)(cursor + base) = r;
  } else {
    if(base+0 < NN){ rowptr[base+0]=ex;    cursor[base+0]=ex;    }
    if(base+1 < NN){ rowptr[base+1]=ex+e1; cursor[base+1]=ex+e1; }
    if(base+2 < NN){ rowptr[base+2]=ex+e2; cursor[base+2]=ex+e2; }
  }
  if(bid == 0 && tid == 0) rowptr[NN] = NE;
}

// ---- fill + edge-MLP fused ----
__global__ void __launch_bounds__(256) fill_edge_kernel(
    const int* __restrict__ ei, int* __restrict__ cursor,
    const void* __restrict__ efin, const float* __restrict__ wts, const void* __restrict__ xin,
    int* __restrict__ srcp, unsigned int* __restrict__ hpk1, unsigned int* __restrict__ hpk2)
{
  __shared__ float s_w1[FE*KH], s_b1[KH], s_w2[FE*KH], s_b2[KH];
  int tid = threadIdx.x;
  if(tid < FE*KH){ s_w1[tid] = wts[OW_E1A + tid]; s_w2[tid] = wts[OW_E2A + tid]; }
  if(tid < KH){ s_b1[tid] = wts[OB_E1A + tid]; s_b2[tid] = wts[OB_E2A + tid]; }
  bool isbf = detect_isbf(xin);
  __syncthreads();
  int e = blockIdx.x*256 + tid;
  if(e >= NE) return;
  int pos = atomicAdd(&cursor[ei[NE + e]], 1);
  srcp[pos] = ei[e];
  float ev[FE];
  if(isbf){
    uint4 u = ((const uint4*)efin)[e];
    ev[0]=bf2f(u.x); ev[1]=bf2f(u.x>>16); ev[2]=bf2f(u.y); ev[3]=bf2f(u.y>>16);
    ev[4]=bf2f(u.z); ev[5]=bf2f(u.z>>16); ev[6]=bf2f(u.w); ev[7]=bf2f(u.w>>16);
  } else {
    float4 a = ((const float4*)efin)[2*e], b = ((const float4*)efin)[2*e+1];
    ev[0]=a.x; ev[1]=a.y; ev[2]=a.z; ev[3]=a.w; ev[4]=b.x; ev[5]=b.y; ev[6]=b.z; ev[7]=b.w;
  }
  unsigned int o[8];
  #pragma unroll
  for(int d = 0; d < 8; d++){
    float h0 = s_b1[2*d], h1 = s_b1[2*d+1];
    #pragma unroll
    for(int k = 0; k < FE; k++){
      h0 += ev[k] * s_w1[k*KH + 2*d];
      h1 += ev[k] * s_w1[k*KH + 2*d+1];
    }
    h0 = h0 > 0.f ? h0 : 0.f; h1 = h1 > 0.f ? h1 : 0.f;
    o[d] = pk2(h0, h1);
  }
  uint4* p1 = (uint4*)(hpk1 + (size_t)pos*8);
  p1[0] = make_uint4(o[0],o[1],o[2],o[3]); p1[1] = make_uint4(o[4],o[5],o[6],o[7]);
  #pragma unroll
  for(int d = 0; d < 8; d++){
    float h0 = s_b2[2*d], h1 = s_b2[2*d+1];
    #pragma unroll
    for(int k = 0; k < FE; k++){
      h0 += ev[k] * s_w2[k*KH + 2*d];
      h1 += ev[k] * s_w2[k*KH + 2*d+1];
    }
    h0 = h0 > 0.f ? h0 : 0.f; h1 = h1 > 0.f ? h1 : 0.f;
    o[d] = pk2(h0, h1);
  }
  uint4* p2 = (uint4*)(hpk2 + (size_t)pos*8);
  p2[0] = make_uint4(o[0],o[1],o[2],o[3]); p2[1] = make_uint4(o[4],o[5],o[6],o[7]);
}

// ---- NNConv message GEMM, register-built A-fragments (round-9-verified math) ----
template<int IN, int OUT, bool ABF>
__global__ void __launch_bounds__(256) conv_mfma_kernel(
    const void* __restrict__ nodef, const unsigned int* __restrict__ hpk,
    const int* __restrict__ srcp, const unsigned short* __restrict__ wpack,
    unsigned short* __restrict__ msg)
{
  constexpr int KMF  = ((KH*IN + IN + 31)/32)*32;   // 288 | 544
  constexpr int KP   = KMF + 8;                     // 296 | 552
  constexpr int NT   = OUT/16;                      // 2 | 1
  constexpr int KS   = KMF/32;                      // 9 | 17
  int tid = threadIdx.x;
  int lane = tid & 63, m = lane & 15, quad = lane >> 4;
  int wid = tid >> 6;
  int ebase = blockIdx.x*64 + wid*16;               // grid = NE/64 exactly
  int em = ebase + m;
  int sn = srcp[em];
  int q1 = quad >> 1;
  int xoff = (IN == 16) ? ((quad & 1)*8) : (quad*8);
  float x8[8];
  short8 xb;
  if(ABF){
    uint4 u = *(const uint4*)((const unsigned short*)nodef + (size_t)sn*IN + xoff);
    unsigned int uu[4] = {u.x, u.y, u.z, u.w};
    #pragma unroll
    for(int k = 0; k < 4; k++){ x8[2*k] = bf2f(uu[k]); x8[2*k+1] = bf2f(uu[k] >> 16); }
    xb = *(short8*)&u;
  } else {
    const float4* xp = (const float4*)((const float*)nodef + (size_t)sn*IN + xoff);
    float4 v0 = xp[0], v1 = xp[1];
    x8[0]=v0.x; x8[1]=v0.y; x8[2]=v0.z; x8[3]=v0.w;
    x8[4]=v1.x; x8[5]=v1.y; x8[6]=v1.z; x8[7]=v1.w;
    unsigned int* xbp = (unsigned int*)&xb;
    #pragma unroll
    for(int k = 0; k < 4; k++) xbp[k] = pk2(x8[2*k], x8[2*k+1]);
  }
  unsigned int hu[8];
  {
    const uint4* hp = (const uint4*)(hpk + (size_t)em*8);
    uint4 u0 = hp[0], u1 = hp[1];
    hu[0]=u0.x; hu[1]=u0.y; hu[2]=u0.z; hu[3]=u0.w;
    hu[4]=u1.x; hu[5]=u1.y; hu[6]=u1.z; hu[7]=u1.w;
  }

  f32x4 acc[NT];
  #pragma unroll
  for(int nt = 0; nt < NT; nt++) acc[nt] = (f32x4){0.f,0.f,0.f,0.f};

  #pragma unroll
  for(int ks = 0; ks < KS; ks++){
    short8 a;
    if(ks < KS-1){
      float hv = (IN == 16) ? bf2f(hu[ks] >> (16*q1))
                            : bf2f(hu[ks >> 1] >> (16*(ks & 1)));
      unsigned int* ap = (unsigned int*)&a;
      #pragma unroll
      for(int k = 0; k < 4; k++) ap[k] = pk2(hv*x8[2*k], hv*x8[2*k+1]);
    } else {
      if(IN == 16) a = (quad < 2) ? xb : (short8){0,0,0,0,0,0,0,0};
      else         a = xb;
    }
    #pragma unroll
    for(int nt = 0; nt < NT; nt++){
      short8 b = *(const short8*)(wpack + (size_t)(nt*16 + m)*KP + ks*32 + quad*8);
      acc[nt] = __builtin_amdgcn_mfma_f32_16x16x32_bf16(a, b, acc[nt], 0, 0, 0);
    }
  }
  #pragma unroll
  for(int nt = 0; nt < NT; nt++)
    #pragma unroll
    for(int r = 0; r < 4; r++)   // C layout: row=(lane>>4)*4+reg (edge), col=lane&15
      msg[(size_t)(ebase + quad*4 + r)*OUT + nt*16 + m] = f2bf(acc[nt][r]);
}

// h1 = relu(x@wr1 + br1 + sum msg rows) -> bf16. 8 threads/node; msg streaming.
__global__ void __launch_bounds__(256) gather1_kernel(
    const float* __restrict__ xf, const unsigned short* __restrict__ msg,
    const int* __restrict__ rowptr,
    const float* __restrict__ wr, const float* __restrict__ br,
    unsigned short* __restrict__ h1b)
{
  __shared__ float s_w[FN*H1C], s_b[H1C];
  for(int i = threadIdx.x; i < FN*H1C; i += 256) s_w[i] = wr[i];
  if(threadIdx.x < H1C) s_b[threadIdx.x] = br[threadIdx.x];
  __syncthreads();
  int g = blockIdx.x*256 + threadIdx.x;
  int n = g >> 3, q = g & 7;
  if(n >= NN) return;
  float a0 = s_b[q*4+0], a1 = s_b[q*4+1], a2 = s_b[q*4+2], a3 = s_b[q*4+3];
  int jb = rowptr[n], je = rowptr[n+1];
  for(int j = jb; j < je; j++){
    const unsigned int* mp = (const unsigned int*)(msg + (size_t)j*H1C + q*4);
    unsigned int u0 = mp[0], u1 = mp[1];
    a0 += bf2f(u0); a1 += bf2f(u0 >> 16); a2 += bf2f(u1); a3 += bf2f(u1 >> 16);
  }
  const float* xr = xf + (size_t)n*FN;
  #pragma unroll
  for(int i = 0; i < FN; i++){
    float xi = xr[i];
    a0 += xi*s_w[i*H1C + q*4+0]; a1 += xi*s_w[i*H1C + q*4+1];
    a2 += xi*s_w[i*H1C + q*4+2]; a3 += xi*s_w[i*H1C + q*4+3];
  }
  a0 = a0>0.f?a0:0.f; a1 = a1>0.f?a1:0.f; a2 = a2>0.f?a2:0.f; a3 = a3>0.f?a3:0.f;
  uint2 hb; hb.x = pk2(a0, a1); hb.y = pk2(a2, a3);
  *(uint2*)(h1b + (size_t)n*H1C + q*4) = hb;
}

// h2 = relu(h1@wr2 + br2 + sum msg2 rows); 4 threads/node; h1 read as bf16
__global__ void __launch_bounds__(256) gather2_kernel(
    const unsigned short* __restrict__ h1b, const unsigned short* __restrict__ msg,
    const int* __restrict__ rowptr,
    const float* __restrict__ wr, const float* __restrict__ br, float* __restrict__ h2)
{
  __shared__ float s_w[H1C*H2C], s_b[H2C];
  for(int i = threadIdx.x; i < H1C*H2C; i += 256) s_w[i] = wr[i];
  if(threadIdx.x < H2C) s_b[threadIdx.x] = br[threadIdx.x];
  __syncthreads();
  int g = blockIdx.x*256 + threadIdx.x;
  int n = g >> 2, q = g & 3;
  if(n >= NN) return;
  float a0 = s_b[q*4+0], a1 = s_b[q*4+1], a2 = s_b[q*4+2], a3 = s_b[q*4+3];
  int jb = rowptr[n], je = rowptr[n+1];
  for(int j = jb; j < je; j++){
    const unsigned int* mp = (const unsigned int*)(msg + (size_t)j*H2C + q*4);
    unsigned int u0 = mp[0], u1 = mp[1];
    a0 += bf2f(u0); a1 += bf2f(u0 >> 16); a2 += bf2f(u1); a3 += bf2f(u1 >> 16);
  }
  const unsigned int* hb = (const unsigned int*)(h1b + (size_t)n*H1C);
  #pragma unroll
  for(int i2 = 0; i2 < H1C/2; i2++){
    unsigned int u = hb[i2];
    float x0 = bf2f(u), x1 = bf2f(u >> 16);
    int i = 2*i2;
    a0 += x0*s_w[i*H2C + q*4+0] + x1*s_w[(i+1)*H2C + q*4+0];
    a1 += x0*s_w[i*H2C + q*4+1] + x1*s_w[(i+1)*H2C + q*4+1];
    a2 += x0*s_w[i*H2C + q*4+2] + x1*s_w[(i+1)*H2C + q*4+2];
    a3 += x0*s_w[i*H2C + q*4+3] + x1*s_w[(i+1)*H2C + q*4+3];
  }
  float4 r; r.x = a0>0.f?a0:0.f; r.y = a1>0.f?a1:0.f; r.z = a2>0.f?a2:0.f; r.w = a3>0.f?a3:0.f;
  *(float4*)(h2 + (size_t)n*H2C + q*4) = r;
}

// one wave per graph: attention pool + mean-pool h2 + head MLP
__global__ void head_kernel(const float* __restrict__ gate, const float* __restrict__ xf,
    const float* __restrict__ h2, const int* __restrict__ batch, const void* __restrict__ xin,
    const float* __restrict__ wl1, const float* __restrict__ bl1,
    const float* __restrict__ wl2, const float* __restrict__ bl2,
    void* __restrict__ out)
{
  __shared__ float sz[H2C + FN];
  int g = blockIdx.x;
  int lane = threadIdx.x;
  bool isbf = detect_isbf(xin);
  int start = lower_bound_i(batch, NN, g);
  int end   = lower_bound_i(batch, NN, g + 1);
  float m = -1e30f;
  for(int n = start + lane; n < end; n += 64) m = fmaxf(m, gate[n]);
  #pragma unroll
  for(int o = 32; o >= 1; o >>= 1) m = fmaxf(m, __shfl_xor(m, o));
  float s = 0.f;
  float acc[FN];
  #pragma unroll
  for(int f = 0; f < FN; f++) acc[f] = 0.f;
  for(int n = start + lane; n < end; n += 64){
    float a = __expf(gate[n] - m);
    s += a;
    const float4* xp = (const float4*)(xf + (size_t)n * FN);
    #pragma unroll
    for(int q = 0; q < 4; q++){
      float4 v = xp[q];
      acc[q*4+0] += a*v.x; acc[q*4+1] += a*v.y; acc[q*4+2] += a*v.z; acc[q*4+3] += a*v.w;
    }
  }
  #pragma unroll
  for(int o = 32; o >= 1; o >>= 1){
    s += __shfl_xor(s, o);
    #pragma unroll
    for(int f = 0; f < FN; f++) acc[f] += __shfl_xor(acc[f], o);
  }
  if(lane < FN) sz[H2C + lane] = (end > start && s > 0.f) ? acc[lane] / s : 0.f;
  #pragma unroll
  for(int f = 0; f < H2C; f++) acc[f] = 0.f;
  for(int n = start + lane; n < end; n += 64){
    const float4* hp = (const float4*)(h2 + (size_t)n*H2C);
    #pragma unroll
    for(int q = 0; q < 4; q++){
      float4 v = hp[q];
      acc[q*4+0] += v.x; acc[q*4+1] += v.y; acc[q*4+2] += v.z; acc[q*4+3] += v.w;
    }
  }
  #pragma unroll
  for(int o = 32; o >= 1; o >>= 1){
    #pragma unroll
    for(int f = 0; f < H2C; f++) acc[f] += __shfl_xor(acc[f], o);
  }
  float inv = 1.f / fmaxf((float)(end - start), 1.f);
  if(lane < H2C) sz[lane] = acc[lane] * inv;
  __syncthreads();
  if(lane == 0){
    float t1[8];
    #pragma unroll
    for(int j = 0; j < 8; j++){
      float t = bl1[j];
      #pragma unroll
      for(int c = 0; c < H2C + FN; c++) t += sz[c] * wl1[c*8 + j];
      t1[j] = t;
    }
    float o = bl2[0];
    #pragma unroll
    for(int j = 0; j < 8; j++) o += t1[j] * wl2[j];
    if(isbf) ((__hip_bfloat16*)out)[g] = __float2bfloat16(o);
    else     ((float*)out)[g] = o;
  }
}

extern "C" void kernel_launch(void* const* d_in, const int* in_sizes, int n_in,
                              void* d_out, int out_size, void* d_ws, size_t ws_size,
                              hipStream_t stream)
{
  const int* ei    = (const int*)d_in[22];
  const int* batch = (const int*)d_in[23];

  float* ws = (float*)d_ws;
  float* xf     = ws;                          // 1,600,000 f
  float* gate   = xf + 1600000;                //   100,000 f
  float* wts    = gate + 100000;               //    19,360 f
  int*   rowptr = (int*)(wts + 19360);         //   100,016 i
  int*   cursor = rowptr + 100016;             //   100,000 i
  int*   deg    = cursor + 100000;             //   100,000 i
  unsigned int* pub = (unsigned int*)(deg + 100000);  // 256 u32 (98 used)
  int*   srcp   = (int*)(pub + 256);           //   200,000 i
  unsigned int* wpack1 = (unsigned int*)(srcp + 200000);   // 4,736 u32
  unsigned int* wpack2 = wpack1 + 4736;                    // 4,416 u32
  unsigned short* h1b  = (unsigned short*)(wpack2 + 4416); // 3,200,000 u16 (6.4 MB)
  unsigned int* hpk1   = (unsigned int*)h1b;   // alias: [NE][8] u32, dead before gather1
  unsigned short* msg1 = h1b + 3200000;        // 6,400,000 u16 (12.8 MB)
  unsigned short* msg2 = msg1;                 // reuse after gather1
  float* h2     = (float*)(msg1 + 6400000);    // 1,600,000 f
  unsigned int* hpk2   = (unsigned int*)h2;    // alias: dead before gather2
  // total ~35 MB

  WArgs wa;
  for(int i = 0; i < NW; i++) wa.p[i] = d_in[2 + i];

  hipMemsetAsync(deg, 0, (100000 + 256)*sizeof(int), stream);   // deg + pub states
  mega1_kernel<<<MB_E, 256, 0, stream>>>(d_in[0], d_in[1], wa, ei, wts, wpack1, wpack2, gate, xf, deg);
  scan_kernel<<<SCAN_NB, 256, 0, stream>>>(deg, rowptr, cursor, pub);
  fill_edge_kernel<<<(NE + 255)/256, 256, 0, stream>>>(ei, cursor, d_in[1], wts, d_in[0], srcp, hpk1, hpk2);

  conv_mfma_kernel<FN, H1C, false><<<NE/64, 256, 0, stream>>>(
      xf, hpk1, srcp, (const unsigned short*)wpack1, msg1);
  gather1_kernel<<<(NN*8 + 255)/256, 256, 0, stream>>>(xf, msg1, rowptr, wts+OW_R1, wts+OB_R1, h1b);

  conv_mfma_kernel<H1C, H2C, true><<<NE/64, 256, 0, stream>>>(
      h1b, hpk2, srcp, (const unsigned short*)wpack2, msg2);
  gather2_kernel<<<(NN*4 + 255)/256, 256, 0, stream>>>(h1b, msg2, rowptr, wts+OW_R2, wts+OB_R2, h2);

  head_kernel<<<NG, 64, 0, stream>>>(gate, xf, h2, batch, d_in[0],
      wts+OW_L1, wts+OB_L1, wts+OW_L2, wts+OB_L2, d_out);
}